// Round 1
// baseline (1196.908 us; speedup 1.0000x reference)
//
#include <hip/hip_runtime.h>

#define HIDN 2048
#define NHEAD 16
#define HDIM 128
#define FFDIM 8192
#define SEQLEN 2048

typedef __attribute__((ext_vector_type(8))) __bf16 bf16x8;
typedef __attribute__((ext_vector_type(4))) float f32x4;
typedef __attribute__((ext_vector_type(4))) unsigned short u16x4;

__device__ __forceinline__ unsigned short f2bfu(float f) {
    unsigned int u = __float_as_uint(f);
    unsigned int r = u + 0x7fffu + ((u >> 16) & 1u);
    return (unsigned short)(r >> 16);
}
__device__ __forceinline__ float bfu2f(unsigned short u) {
    return __uint_as_float(((unsigned int)u) << 16);
}

// ---------------- LayerNorm (fp32 in) -> bf16 out ----------------
__global__ __launch_bounds__(256)
void ln_bf16(const float* __restrict__ x, const float* __restrict__ w,
             const float* __restrict__ b, unsigned short* __restrict__ out) {
    const int row = blockIdx.x;
    const int tid = threadIdx.x;
    const float* xr = x + (size_t)row * HIDN;
    float4 v0 = ((const float4*)xr)[tid];
    float4 v1 = ((const float4*)xr)[tid + 256];
    float s = v0.x + v0.y + v0.z + v0.w + v1.x + v1.y + v1.z + v1.w;
    float q = v0.x*v0.x + v0.y*v0.y + v0.z*v0.z + v0.w*v0.w
            + v1.x*v1.x + v1.y*v1.y + v1.z*v1.z + v1.w*v1.w;
    for (int o = 32; o > 0; o >>= 1) {
        s += __shfl_down(s, o, 64);
        q += __shfl_down(q, o, 64);
    }
    __shared__ float red[8];
    const int wid = tid >> 6;
    if ((tid & 63) == 0) { red[wid] = s; red[4 + wid] = q; }
    __syncthreads();
    float st = red[0] + red[1] + red[2] + red[3];
    float qt = red[4] + red[5] + red[6] + red[7];
    float mu = st * (1.0f / HIDN);
    float var = qt * (1.0f / HIDN) - mu * mu;
    float rs = rsqrtf(var + 1e-5f);
    unsigned short* orow = out + (size_t)row * HIDN;
    int i0 = tid * 4, i1 = (tid + 256) * 4;
    orow[i0 + 0] = f2bfu((v0.x - mu) * rs * w[i0 + 0] + b[i0 + 0]);
    orow[i0 + 1] = f2bfu((v0.y - mu) * rs * w[i0 + 1] + b[i0 + 1]);
    orow[i0 + 2] = f2bfu((v0.z - mu) * rs * w[i0 + 2] + b[i0 + 2]);
    orow[i0 + 3] = f2bfu((v0.w - mu) * rs * w[i0 + 3] + b[i0 + 3]);
    orow[i1 + 0] = f2bfu((v1.x - mu) * rs * w[i1 + 0] + b[i1 + 0]);
    orow[i1 + 1] = f2bfu((v1.y - mu) * rs * w[i1 + 1] + b[i1 + 1]);
    orow[i1 + 2] = f2bfu((v1.z - mu) * rs * w[i1 + 2] + b[i1 + 2]);
    orow[i1 + 3] = f2bfu((v1.w - mu) * rs * w[i1 + 3] + b[i1 + 3]);
}

// ---------------- RoPE, in-place on bf16 (S, NH, HD) ----------------
__global__ __launch_bounds__(256)
void rope_kernel(unsigned short* __restrict__ x, const int* __restrict__ tsl) {
    int idx = blockIdx.x * 256 + threadIdx.x;   // S*NH*64 total
    int p  = idx & 63;
    int sh = idx >> 6;          // s*NH + h
    int s  = sh >> 4;
    int off = tsl[0] - SEQLEN;
    float inv = powf(10000.0f, -(float)(2 * p) * (1.0f / 128.0f));
    float ang = (float)(s + off) * inv;
    float c = cosf(ang), sn = sinf(ang);
    size_t base = (size_t)sh * 128 + p;
    float x1 = bfu2f(x[base]);
    float x2 = bfu2f(x[base + 64]);
    x[base]      = f2bfu(x1 * c - x2 * sn);
    x[base + 64] = f2bfu(x2 * c + x1 * sn);
}

// ---------------- GEMM: C[M,N] = A[M,K](bf16) * B[N,K]^T(fp32->bf16) ----------------
// EPI 0: outB = bf16(acc + bias)
// EPI 1: outF = resid + acc + bias          (fp32 out)
// EPI 2: outB = bf16( silu(outB_in) * acc ) (in-place gate->gu)
template<int EPI>
__global__ __launch_bounds__(256)
void gemm_bt(const unsigned short* __restrict__ A, const float* __restrict__ B,
             const float* __restrict__ bias, const float* __restrict__ resid,
             unsigned short* __restrict__ outB, float* __restrict__ outF,
             int M, int N, int K) {
    __shared__ __align__(16) unsigned short As[128 * 40];
    __shared__ __align__(16) unsigned short Bs[128 * 40];
    const int tid = threadIdx.x;
    const int brow = blockIdx.y * 128, bcol = blockIdx.x * 128;
    const int wid = tid >> 6, lane = tid & 63;
    const int wr = wid >> 1, wc = wid & 1;
    const int lr = lane & 15, lg = lane >> 4;

    f32x4 acc[4][4];
#pragma unroll
    for (int m = 0; m < 4; ++m)
#pragma unroll
        for (int n = 0; n < 4; ++n) acc[m][n] = (f32x4){0.f, 0.f, 0.f, 0.f};

    const int arow = tid >> 2;        // 0..63
    const int akb  = (tid & 3) * 8;   // 0,8,16,24
    const int bn   = tid >> 3;        // 0..31
    const int bkb  = (tid & 7) * 4;   // 0..28

    for (int k0 = 0; k0 < K; k0 += 32) {
#pragma unroll
        for (int i = 0; i < 2; ++i) {
            int r = arow + i * 64;
            bf16x8 av = *(const bf16x8*)(A + (size_t)(brow + r) * K + k0 + akb);
            *(bf16x8*)&As[r * 40 + akb] = av;
        }
#pragma unroll
        for (int i = 0; i < 4; ++i) {
            int n = bn + i * 32;
            float4 bv = *(const float4*)(B + (size_t)(bcol + n) * K + k0 + bkb);
            u16x4 cv;
            cv[0] = f2bfu(bv.x); cv[1] = f2bfu(bv.y);
            cv[2] = f2bfu(bv.z); cv[3] = f2bfu(bv.w);
            *(u16x4*)&Bs[n * 40 + bkb] = cv;
        }
        __syncthreads();
        bf16x8 aF[4], bF[4];
#pragma unroll
        for (int m = 0; m < 4; ++m)
            aF[m] = *(const bf16x8*)&As[(wr * 64 + m * 16 + lr) * 40 + lg * 8];
#pragma unroll
        for (int n = 0; n < 4; ++n)
            bF[n] = *(const bf16x8*)&Bs[(wc * 64 + n * 16 + lr) * 40 + lg * 8];
#pragma unroll
        for (int m = 0; m < 4; ++m)
#pragma unroll
            for (int n = 0; n < 4; ++n)
                acc[m][n] = __builtin_amdgcn_mfma_f32_16x16x32_bf16(aF[m], bF[n], acc[m][n], 0, 0, 0);
        __syncthreads();
    }

#pragma unroll
    for (int n = 0; n < 4; ++n) {
        int col = bcol + wc * 64 + n * 16 + lr;
        float bv = bias ? bias[col] : 0.f;
#pragma unroll
        for (int m = 0; m < 4; ++m) {
            int row0 = brow + wr * 64 + m * 16 + lg * 4;
#pragma unroll
            for (int j = 0; j < 4; ++j) {
                size_t idx = (size_t)(row0 + j) * N + col;
                float v = acc[m][n][j] + bv;
                if (EPI == 0) {
                    outB[idx] = f2bfu(v);
                } else if (EPI == 1) {
                    outF[idx] = resid[idx] + v;
                } else {
                    float g = bfu2f(outB[idx]);
                    float sg = g / (1.0f + expf(-g));
                    outB[idx] = f2bfu(sg * v);
                }
            }
        }
    }
}

// ---------------- Flash attention: 1 wave per (head, 16 q-rows) ----------------
__global__ __launch_bounds__(64)
void attn_kernel(const unsigned short* __restrict__ Q, const unsigned short* __restrict__ K,
                 const unsigned short* __restrict__ V, unsigned short* __restrict__ O) {
    __shared__ __align__(16) unsigned short vt[128 * 40];  // [d][t] transposed V tile
    __shared__ __align__(16) unsigned short pl[16 * 40];   // [q][t] P tile
    const int lane = threadIdx.x;
    const int h = blockIdx.y;
    const int q0 = blockIdx.x * 16;
    const int lr = lane & 15, lg = lane >> 4;

    // Q fragments: A[row=q(lr)][k=d], 4 chunks of 32 d
    bf16x8 qa[4];
#pragma unroll
    for (int c = 0; c < 4; ++c)
        qa[c] = *(const bf16x8*)(Q + (size_t)(q0 + lr) * HIDN + h * HDIM + c * 32 + lg * 8);

    f32x4 acc[8];
#pragma unroll
    for (int dt = 0; dt < 8; ++dt) acc[dt] = (f32x4){0.f, 0.f, 0.f, 0.f};
    float mrow[4] = {-INFINITY, -INFINITY, -INFINITY, -INFINITY};
    float lrow[4] = {0.f, 0.f, 0.f, 0.f};

    const float sc = 0.08838834764831845f;  // 1/sqrt(128)
    const int ntile = (q0 + 15) / 32 + 1;

    for (int tt = 0; tt < ntile; ++tt) {
        const int t0 = tt * 32;
        // stage transposed V tile
        {
            int tl = lane >> 1;
            int dh = (lane & 1) * 64;
            const unsigned short* vp = V + (size_t)(t0 + tl) * HIDN + h * HDIM + dh;
#pragma unroll
            for (int c = 0; c < 8; ++c) {
                bf16x8 vv = *(const bf16x8*)(vp + c * 8);
#pragma unroll
                for (int e = 0; e < 8; ++e)
                    vt[(dh + c * 8 + e) * 40 + tl] = ((const unsigned short*)&vv)[e];
            }
        }
        // scores S[16q x 32t]
        f32x4 s[2];
        s[0] = (f32x4){0.f, 0.f, 0.f, 0.f};
        s[1] = (f32x4){0.f, 0.f, 0.f, 0.f};
#pragma unroll
        for (int th = 0; th < 2; ++th)
#pragma unroll
            for (int c = 0; c < 4; ++c) {
                bf16x8 kb = *(const bf16x8*)(K + (size_t)(t0 + th * 16 + lr) * HIDN + h * HDIM + c * 32 + lg * 8);
                s[th] = __builtin_amdgcn_mfma_f32_16x16x32_bf16(qa[c], kb, s[th], 0, 0, 0);
            }
        // scale + causal mask
#pragma unroll
        for (int th = 0; th < 2; ++th) {
            int tg = t0 + th * 16 + lr;
#pragma unroll
            for (int j = 0; j < 4; ++j) {
                int qg = q0 + lg * 4 + j;
                s[th][j] = s[th][j] * sc + (tg <= qg ? 0.f : -1e9f);
            }
        }
        // row max
        float mt[4];
#pragma unroll
        for (int j = 0; j < 4; ++j) mt[j] = fmaxf(s[0][j], s[1][j]);
#pragma unroll
        for (int o = 8; o > 0; o >>= 1)
#pragma unroll
            for (int j = 0; j < 4; ++j) mt[j] = fmaxf(mt[j], __shfl_xor(mt[j], o, 16));
        float alpha[4];
#pragma unroll
        for (int j = 0; j < 4; ++j) {
            float mn = fmaxf(mrow[j], mt[j]);
            alpha[j] = expf(mrow[j] - mn);
            mrow[j] = mn;
        }
        // p = exp(s - m), row sum
        float ps[4] = {0.f, 0.f, 0.f, 0.f};
#pragma unroll
        for (int th = 0; th < 2; ++th)
#pragma unroll
            for (int j = 0; j < 4; ++j) {
                float p = expf(s[th][j] - mrow[j]);
                s[th][j] = p;
                ps[j] += p;
            }
#pragma unroll
        for (int o = 8; o > 0; o >>= 1)
#pragma unroll
            for (int j = 0; j < 4; ++j) ps[j] += __shfl_xor(ps[j], o, 16);
#pragma unroll
        for (int j = 0; j < 4; ++j) lrow[j] = lrow[j] * alpha[j] + ps[j];
        // rescale O
#pragma unroll
        for (int dt = 0; dt < 8; ++dt)
#pragma unroll
            for (int j = 0; j < 4; ++j) acc[dt][j] *= alpha[j];
        // write P tile
#pragma unroll
        for (int th = 0; th < 2; ++th)
#pragma unroll
            for (int j = 0; j < 4; ++j)
                pl[(lg * 4 + j) * 40 + th * 16 + lr] = f2bfu(s[th][j]);
        __syncthreads();
        // PV
        bf16x8 pa = *(const bf16x8*)&pl[lr * 40 + lg * 8];
#pragma unroll
        for (int dt = 0; dt < 8; ++dt) {
            bf16x8 vb = *(const bf16x8*)&vt[(dt * 16 + lr) * 40 + lg * 8];
            acc[dt] = __builtin_amdgcn_mfma_f32_16x16x32_bf16(pa, vb, acc[dt], 0, 0, 0);
        }
        __syncthreads();
    }
    // epilogue: O / l
    float invl[4];
#pragma unroll
    for (int j = 0; j < 4; ++j) invl[j] = 1.0f / lrow[j];
#pragma unroll
    for (int dt = 0; dt < 8; ++dt)
#pragma unroll
        for (int j = 0; j < 4; ++j)
            O[(size_t)(q0 + lg * 4 + j) * HIDN + h * HDIM + dt * 16 + lr] = f2bfu(acc[dt][j] * invl[j]);
}

extern "C" void kernel_launch(void* const* d_in, const int* in_sizes, int n_in,
                              void* d_out, int out_size, void* d_ws, size_t ws_size,
                              hipStream_t stream) {
    const float* hidden = (const float*)d_in[0];
    const float* ln1w = (const float*)d_in[2];
    const float* ln1b = (const float*)d_in[3];
    const float* ln2w = (const float*)d_in[4];
    const float* ln2b = (const float*)d_in[5];
    const float* wq = (const float*)d_in[6];
    const float* bq = (const float*)d_in[7];
    const float* wk = (const float*)d_in[8];
    const float* bk = (const float*)d_in[9];
    const float* wv = (const float*)d_in[10];
    const float* bv = (const float*)d_in[11];
    const float* wo = (const float*)d_in[12];
    const float* bo = (const float*)d_in[13];
    const float* wg = (const float*)d_in[14];
    const float* wu = (const float*)d_in[15];
    const float* wd = (const float*)d_in[16];
    const int* tsl = (const int*)d_in[17];
    float* out = (float*)d_out;

    char* ws = (char*)d_ws;
    const size_t MB = 1024 * 1024;
    unsigned short* x_bf = (unsigned short*)(ws);              // 8MB; attn output reuses
    unsigned short* q_bf = (unsigned short*)(ws + 8 * MB);     // 8MB; y reuses
    unsigned short* k_bf = (unsigned short*)(ws + 16 * MB);    // 8MB
    unsigned short* v_bf = (unsigned short*)(ws + 24 * MB);    // 8MB
    unsigned short* g_bf = (unsigned short*)(ws + 32 * MB);    // 32MB; gu in-place

    ln_bf16<<<SEQLEN, 256, 0, stream>>>(hidden, ln1w, ln1b, x_bf);

    dim3 g16(HIDN / 128, SEQLEN / 128);
    gemm_bt<0><<<g16, 256, 0, stream>>>(x_bf, wq, bq, nullptr, q_bf, nullptr, SEQLEN, HIDN, HIDN);
    gemm_bt<0><<<g16, 256, 0, stream>>>(x_bf, wk, bk, nullptr, k_bf, nullptr, SEQLEN, HIDN, HIDN);
    gemm_bt<0><<<g16, 256, 0, stream>>>(x_bf, wv, bv, nullptr, v_bf, nullptr, SEQLEN, HIDN, HIDN);

    int rope_blocks = SEQLEN * NHEAD * 64 / 256;
    rope_kernel<<<rope_blocks, 256, 0, stream>>>(q_bf, tsl);
    rope_kernel<<<rope_blocks, 256, 0, stream>>>(k_bf, tsl);

    attn_kernel<<<dim3(SEQLEN / 16, NHEAD), 64, 0, stream>>>(q_bf, k_bf, v_bf, x_bf);

    gemm_bt<1><<<g16, 256, 0, stream>>>(x_bf, wo, bo, hidden, nullptr, out, SEQLEN, HIDN, HIDN);

    ln_bf16<<<SEQLEN, 256, 0, stream>>>(out, ln2w, ln2b, q_bf);

    dim3 gff(FFDIM / 128, SEQLEN / 128);
    gemm_bt<0><<<gff, 256, 0, stream>>>(q_bf, wg, nullptr, nullptr, g_bf, nullptr, SEQLEN, FFDIM, HIDN);
    gemm_bt<2><<<gff, 256, 0, stream>>>(q_bf, wu, nullptr, nullptr, g_bf, nullptr, SEQLEN, FFDIM, HIDN);

    gemm_bt<1><<<g16, 256, 0, stream>>>(g_bf, wd, nullptr, out, nullptr, out, SEQLEN, HIDN, FFDIM);
}

// Round 2
// 892.970 us; speedup vs baseline: 1.3404x; 1.3404x over previous
//
#include <hip/hip_runtime.h>

#define HIDN 2048
#define NHEAD 16
#define HDIM 128
#define FFDIM 8192
#define SEQLEN 2048

typedef __attribute__((ext_vector_type(8))) __bf16 bf16x8;
typedef __attribute__((ext_vector_type(4))) float f32x4;
typedef __attribute__((ext_vector_type(4))) unsigned short u16x4;
typedef __attribute__((ext_vector_type(8))) unsigned short u16x8;

__device__ __forceinline__ unsigned short f2bfu(float f) {
    unsigned int u = __float_as_uint(f);
    unsigned int r = u + 0x7fffu + ((u >> 16) & 1u);
    return (unsigned short)(r >> 16);
}
__device__ __forceinline__ float bfu2f(unsigned short u) {
    return __uint_as_float(((unsigned int)u) << 16);
}

__device__ __forceinline__ void gload16(const void* g, void* l) {
    __builtin_amdgcn_global_load_lds(
        (const __attribute__((address_space(1))) unsigned int*)g,
        (__attribute__((address_space(3))) unsigned int*)l,
        16, 0, 0);
}

// ---------------- fp32 -> bf16 weight conversion ----------------
__global__ __launch_bounds__(256)
void conv_f32_bf16(const float* __restrict__ src, unsigned short* __restrict__ dst) {
    int i = blockIdx.x * 256 + threadIdx.x;      // one thread = 8 elems
    float4 a = ((const float4*)src)[i * 2];
    float4 b = ((const float4*)src)[i * 2 + 1];
    u16x8 v;
    v[0] = f2bfu(a.x); v[1] = f2bfu(a.y); v[2] = f2bfu(a.z); v[3] = f2bfu(a.w);
    v[4] = f2bfu(b.x); v[5] = f2bfu(b.y); v[6] = f2bfu(b.z); v[7] = f2bfu(b.w);
    *(u16x8*)(dst + (size_t)i * 8) = v;
}

// ---------------- LayerNorm (fp32 in) -> bf16 out ----------------
__global__ __launch_bounds__(256)
void ln_bf16(const float* __restrict__ x, const float* __restrict__ w,
             const float* __restrict__ b, unsigned short* __restrict__ out) {
    const int row = blockIdx.x;
    const int tid = threadIdx.x;
    const float* xr = x + (size_t)row * HIDN;
    float4 v0 = ((const float4*)xr)[tid];
    float4 v1 = ((const float4*)xr)[tid + 256];
    float s = v0.x + v0.y + v0.z + v0.w + v1.x + v1.y + v1.z + v1.w;
    float q = v0.x*v0.x + v0.y*v0.y + v0.z*v0.z + v0.w*v0.w
            + v1.x*v1.x + v1.y*v1.y + v1.z*v1.z + v1.w*v1.w;
    for (int o = 32; o > 0; o >>= 1) {
        s += __shfl_down(s, o, 64);
        q += __shfl_down(q, o, 64);
    }
    __shared__ float red[8];
    const int wid = tid >> 6;
    if ((tid & 63) == 0) { red[wid] = s; red[4 + wid] = q; }
    __syncthreads();
    float st = red[0] + red[1] + red[2] + red[3];
    float qt = red[4] + red[5] + red[6] + red[7];
    float mu = st * (1.0f / HIDN);
    float var = qt * (1.0f / HIDN) - mu * mu;
    float rs = rsqrtf(var + 1e-5f);
    unsigned short* orow = out + (size_t)row * HIDN;
    int i0 = tid * 4, i1 = (tid + 256) * 4;
    orow[i0 + 0] = f2bfu((v0.x - mu) * rs * w[i0 + 0] + b[i0 + 0]);
    orow[i0 + 1] = f2bfu((v0.y - mu) * rs * w[i0 + 1] + b[i0 + 1]);
    orow[i0 + 2] = f2bfu((v0.z - mu) * rs * w[i0 + 2] + b[i0 + 2]);
    orow[i0 + 3] = f2bfu((v0.w - mu) * rs * w[i0 + 3] + b[i0 + 3]);
    orow[i1 + 0] = f2bfu((v1.x - mu) * rs * w[i1 + 0] + b[i1 + 0]);
    orow[i1 + 1] = f2bfu((v1.y - mu) * rs * w[i1 + 1] + b[i1 + 1]);
    orow[i1 + 2] = f2bfu((v1.z - mu) * rs * w[i1 + 2] + b[i1 + 2]);
    orow[i1 + 3] = f2bfu((v1.w - mu) * rs * w[i1 + 3] + b[i1 + 3]);
}

// ---------------- RoPE in-place on qk buffer [S][4096] (q cols 0-2047, k cols 2048-4095) ----
__global__ __launch_bounds__(256)
void rope_kernel(unsigned short* __restrict__ qk, const int* __restrict__ tsl) {
    int id = blockIdx.x * 256 + threadIdx.x;   // S * 32 * 64
    int p  = id & 63;
    int hh = (id >> 6) & 31;      // 0-15: q heads, 16-31: k heads
    int s  = id >> 11;
    int off = tsl[0] - SEQLEN;
    // 10000^(-p/64) = 2^(-p * log2(10000)/64)
    float inv = exp2f((float)p * -0.20762050593f);
    float ang = (float)(s + off) * inv;
    float c, sn;
    __sincosf(ang, &sn, &c);
    size_t base = (size_t)s * 4096 + hh * 128 + p;
    float x1 = bfu2f(qk[base]);
    float x2 = bfu2f(qk[base + 64]);
    qk[base]      = f2bfu(x1 * c - x2 * sn);
    qk[base + 64] = f2bfu(x2 * c + x1 * sn);
}

// ---------------- GEMM: C[M,N] = A[M,K](bf16) * B[N,K]^T(bf16), m97 structure ----------------
// EPI 0 (QKV):  col<4096 -> qk[row*4096+col] bf16(+bias q/k); else vt[(col-4096)*SEQ+row] bf16(+bias v)
// EPI 1 (BF):   outB[row*N+col] = bf16(acc + bias0)
// EPI 2 (RESID):outF[row*N+col] = resid + acc + bias0     (fp32)
// EPI 3 (SILU): outB[row*N+col] = bf16(silu(outB_prev) * acc)   (in-place gate->gu)
template<int EPI>
__global__ __launch_bounds__(256)
void gemm_bt(const unsigned short* __restrict__ A, const unsigned short* __restrict__ B,
             const float* __restrict__ bias0, const float* __restrict__ bias1,
             const float* __restrict__ bias2, const float* __restrict__ resid,
             unsigned short* __restrict__ outB, unsigned short* __restrict__ outV,
             float* __restrict__ outF, int M, int N, int K) {
    __shared__ __align__(16) unsigned short As[128 * 32];
    __shared__ __align__(16) unsigned short Bs[128 * 32];
    const int tid = threadIdx.x;
    const int brow = blockIdx.y * 128, bcol = blockIdx.x * 128;
    const int wid = tid >> 6, lane = tid & 63;
    const int wr = wid >> 1, wc = wid & 1;
    const int lr = lane & 15, lg = lane >> 4;

    f32x4 acc[4][4];
#pragma unroll
    for (int m = 0; m < 4; ++m)
#pragma unroll
        for (int n = 0; n < 4; ++n) acc[m][n] = (f32x4){0.f, 0.f, 0.f, 0.f};

    const int r0 = tid >> 2;            // 0..63
    const int c0 = (tid & 3) * 8;       // elem col in k-tile
    char* ldsA = (char*)As + wid * 1024;
    char* ldsB = (char*)Bs + wid * 1024;
    const unsigned short* gA = A + (size_t)brow * K;
    const unsigned short* gB = B + (size_t)bcol * K;

    for (int k0 = 0; k0 < K; k0 += 32) {
        gload16(gA + (size_t)r0 * K + k0 + c0, ldsA);
        gload16(gA + (size_t)(r0 + 64) * K + k0 + c0, ldsA + 4096);
        gload16(gB + (size_t)r0 * K + k0 + c0, ldsB);
        gload16(gB + (size_t)(r0 + 64) * K + k0 + c0, ldsB + 4096);
        __syncthreads();
        bf16x8 aF[4], bF[4];
#pragma unroll
        for (int m = 0; m < 4; ++m)
            aF[m] = *(const bf16x8*)&As[(wr * 64 + m * 16 + lr) * 32 + lg * 8];
#pragma unroll
        for (int n = 0; n < 4; ++n)
            bF[n] = *(const bf16x8*)&Bs[(wc * 64 + n * 16 + lr) * 32 + lg * 8];
#pragma unroll
        for (int m = 0; m < 4; ++m)
#pragma unroll
            for (int n = 0; n < 4; ++n)
                acc[m][n] = __builtin_amdgcn_mfma_f32_16x16x32_bf16(aF[m], bF[n], acc[m][n], 0, 0, 0);
        __syncthreads();
    }

#pragma unroll
    for (int n = 0; n < 4; ++n) {
        int col = bcol + wc * 64 + n * 16 + lr;
        float bv;
        if (EPI == 0) {
            bv = (col < 2048) ? bias0[col] : (col < 4096) ? bias1[col - 2048] : bias2[col - 4096];
        } else {
            bv = bias0 ? bias0[col] : 0.f;
        }
#pragma unroll
        for (int m = 0; m < 4; ++m) {
            int row0 = brow + wr * 64 + m * 16 + lg * 4;
#pragma unroll
            for (int j = 0; j < 4; ++j) {
                int row = row0 + j;
                float v = acc[m][n][j] + bv;
                if (EPI == 0) {
                    if (col < 4096) outB[(size_t)row * 4096 + col] = f2bfu(v);
                    else            outV[(size_t)(col - 4096) * SEQLEN + row] = f2bfu(v);
                } else if (EPI == 1) {
                    outB[(size_t)row * N + col] = f2bfu(v);
                } else if (EPI == 2) {
                    size_t idx = (size_t)row * N + col;
                    outF[idx] = resid[idx] + v;
                } else {
                    size_t idx = (size_t)row * N + col;
                    float g = bfu2f(outB[idx]);
                    float sg = g / (1.0f + expf(-g));
                    outB[idx] = f2bfu(sg * v);
                }
            }
        }
    }
}

// ---------------- Flash attention: 1 wave per (head, 16 q-rows), V^T direct from global ----
__global__ __launch_bounds__(64)
void attn_kernel(const unsigned short* __restrict__ QK, const unsigned short* __restrict__ VT,
                 unsigned short* __restrict__ O) {
    __shared__ __align__(16) unsigned short pl[16 * 40];   // [q][t] P tile
    const int lane = threadIdx.x;
    const int h = blockIdx.y;
    const int q0 = blockIdx.x * 16;
    const int lr = lane & 15, lg = lane >> 4;

    const unsigned short* Qb = QK + (size_t)q0 * 4096 + h * 128;
    const unsigned short* Kb = QK + 2048 + h * 128;
    const unsigned short* Vb = VT + (size_t)(h * 128) * SEQLEN;

    bf16x8 qa[4];
#pragma unroll
    for (int c = 0; c < 4; ++c)
        qa[c] = *(const bf16x8*)(Qb + (size_t)lr * 4096 + c * 32 + lg * 8);

    f32x4 acc[8];
#pragma unroll
    for (int dt = 0; dt < 8; ++dt) acc[dt] = (f32x4){0.f, 0.f, 0.f, 0.f};
    float mrow[4] = {-INFINITY, -INFINITY, -INFINITY, -INFINITY};
    float lrow[4] = {0.f, 0.f, 0.f, 0.f};

    const float sc = 0.08838834764831845f;  // 1/sqrt(128)
    const int ntile = (q0 + 15) / 32 + 1;

    for (int tt = 0; tt < ntile; ++tt) {
        const int t0 = tt * 32;
        f32x4 s[2];
        s[0] = (f32x4){0.f, 0.f, 0.f, 0.f};
        s[1] = (f32x4){0.f, 0.f, 0.f, 0.f};
#pragma unroll
        for (int th = 0; th < 2; ++th)
#pragma unroll
            for (int c = 0; c < 4; ++c) {
                bf16x8 kb = *(const bf16x8*)(Kb + (size_t)(t0 + th * 16 + lr) * 4096 + c * 32 + lg * 8);
                s[th] = __builtin_amdgcn_mfma_f32_16x16x32_bf16(qa[c], kb, s[th], 0, 0, 0);
            }
#pragma unroll
        for (int th = 0; th < 2; ++th) {
            int tg = t0 + th * 16 + lr;
#pragma unroll
            for (int j = 0; j < 4; ++j) {
                int qg = q0 + lg * 4 + j;
                s[th][j] = s[th][j] * sc + (tg <= qg ? 0.f : -1e9f);
            }
        }
        float mt[4];
#pragma unroll
        for (int j = 0; j < 4; ++j) mt[j] = fmaxf(s[0][j], s[1][j]);
#pragma unroll
        for (int o = 8; o > 0; o >>= 1)
#pragma unroll
            for (int j = 0; j < 4; ++j) mt[j] = fmaxf(mt[j], __shfl_xor(mt[j], o, 16));
        float alpha[4];
#pragma unroll
        for (int j = 0; j < 4; ++j) {
            float mn = fmaxf(mrow[j], mt[j]);
            alpha[j] = expf(mrow[j] - mn);
            mrow[j] = mn;
        }
        float ps[4] = {0.f, 0.f, 0.f, 0.f};
#pragma unroll
        for (int th = 0; th < 2; ++th)
#pragma unroll
            for (int j = 0; j < 4; ++j) {
                float p = expf(s[th][j] - mrow[j]);
                s[th][j] = p;
                ps[j] += p;
            }
#pragma unroll
        for (int o = 8; o > 0; o >>= 1)
#pragma unroll
            for (int j = 0; j < 4; ++j) ps[j] += __shfl_xor(ps[j], o, 16);
#pragma unroll
        for (int j = 0; j < 4; ++j) lrow[j] = lrow[j] * alpha[j] + ps[j];
#pragma unroll
        for (int dt = 0; dt < 8; ++dt)
#pragma unroll
            for (int j = 0; j < 4; ++j) acc[dt][j] *= alpha[j];
#pragma unroll
        for (int th = 0; th < 2; ++th)
#pragma unroll
            for (int j = 0; j < 4; ++j)
                pl[(lg * 4 + j) * 40 + th * 16 + lr] = f2bfu(s[th][j]);
        __syncthreads();
        bf16x8 pa = *(const bf16x8*)&pl[lr * 40 + lg * 8];
#pragma unroll
        for (int dt = 0; dt < 8; ++dt) {
            bf16x8 vb = *(const bf16x8*)(Vb + (size_t)(dt * 16 + lr) * SEQLEN + t0 + lg * 8);
            acc[dt] = __builtin_amdgcn_mfma_f32_16x16x32_bf16(pa, vb, acc[dt], 0, 0, 0);
        }
        __syncthreads();
    }
    float invl[4];
#pragma unroll
    for (int j = 0; j < 4; ++j) invl[j] = 1.0f / lrow[j];
#pragma unroll
    for (int dt = 0; dt < 8; ++dt)
#pragma unroll
        for (int j = 0; j < 4; ++j)
            O[(size_t)(q0 + lg * 4 + j) * HIDN + h * HDIM + dt * 16 + lr] = f2bfu(acc[dt][j] * invl[j]);
}

extern "C" void kernel_launch(void* const* d_in, const int* in_sizes, int n_in,
                              void* d_out, int out_size, void* d_ws, size_t ws_size,
                              hipStream_t stream) {
    const float* hidden = (const float*)d_in[0];
    const float* ln1w = (const float*)d_in[2];
    const float* ln1b = (const float*)d_in[3];
    const float* ln2w = (const float*)d_in[4];
    const float* ln2b = (const float*)d_in[5];
    const float* wq = (const float*)d_in[6];
    const float* bq = (const float*)d_in[7];
    const float* wk = (const float*)d_in[8];
    const float* bk = (const float*)d_in[9];
    const float* wv = (const float*)d_in[10];
    const float* bv = (const float*)d_in[11];
    const float* wo = (const float*)d_in[12];
    const float* bo = (const float*)d_in[13];
    const float* wg = (const float*)d_in[14];
    const float* wu = (const float*)d_in[15];
    const float* wd = (const float*)d_in[16];
    const int* tsl = (const int*)d_in[17];
    float* out = (float*)d_out;

    char* ws = (char*)d_ws;
    const size_t MB = 1024 * 1024;
    unsigned short* Wbuf = (unsigned short*)(ws);            // 32 MiB weight staging
    unsigned short* qk   = (unsigned short*)(ws + 32 * MB);  // [2048][4096] 16 MiB; y reuses
    unsigned short* vt   = (unsigned short*)(ws + 48 * MB);  // [2048 d][2048 t] 8 MiB
    unsigned short* x_bf = (unsigned short*)(ws + 56 * MB);  // 8 MiB; attn out reuses
    unsigned short* g_bf = (unsigned short*)(ws + 64 * MB);  // [2048][8192] 32 MiB
    unsigned short* y_bf = qk;                               // reuse after attn

    const int HID2 = HIDN * HIDN;            // 4194304
    const int CONV_HID = HID2 / 8 / 256;     // 2048 blocks
    const int CONV_FF  = FFDIM * HIDN / 8 / 256;  // 8192 blocks

    // ---- QKV ----
    conv_f32_bf16<<<CONV_HID, 256, 0, stream>>>(wq, Wbuf);
    conv_f32_bf16<<<CONV_HID, 256, 0, stream>>>(wk, Wbuf + HID2);
    conv_f32_bf16<<<CONV_HID, 256, 0, stream>>>(wv, Wbuf + 2 * (size_t)HID2);
    ln_bf16<<<SEQLEN, 256, 0, stream>>>(hidden, ln1w, ln1b, x_bf);
    gemm_bt<0><<<dim3(48, 16), 256, 0, stream>>>(x_bf, Wbuf, bq, bk, bv, nullptr,
                                                 qk, vt, nullptr, SEQLEN, 3 * HIDN, HIDN);
    rope_kernel<<<SEQLEN * 32 * 64 / 256, 256, 0, stream>>>(qk, tsl);
    attn_kernel<<<dim3(SEQLEN / 16, NHEAD), 64, 0, stream>>>(qk, vt, x_bf);

    // ---- WO + residual ----
    conv_f32_bf16<<<CONV_HID, 256, 0, stream>>>(wo, Wbuf);
    gemm_bt<2><<<dim3(16, 16), 256, 0, stream>>>(x_bf, Wbuf, bo, nullptr, nullptr, hidden,
                                                 nullptr, nullptr, out, SEQLEN, HIDN, HIDN);

    // ---- FFN ----
    ln_bf16<<<SEQLEN, 256, 0, stream>>>(out, ln2w, ln2b, y_bf);
    conv_f32_bf16<<<CONV_FF, 256, 0, stream>>>(wg, Wbuf);
    gemm_bt<1><<<dim3(64, 16), 256, 0, stream>>>(y_bf, Wbuf, nullptr, nullptr, nullptr, nullptr,
                                                 g_bf, nullptr, nullptr, SEQLEN, FFDIM, HIDN);
    conv_f32_bf16<<<CONV_FF, 256, 0, stream>>>(wu, Wbuf);
    gemm_bt<3><<<dim3(64, 16), 256, 0, stream>>>(y_bf, Wbuf, nullptr, nullptr, nullptr, nullptr,
                                                 g_bf, nullptr, nullptr, SEQLEN, FFDIM, HIDN);
    conv_f32_bf16<<<CONV_FF, 256, 0, stream>>>(wd, Wbuf);
    gemm_bt<2><<<dim3(16, 16), 256, 0, stream>>>(g_bf, Wbuf, nullptr, nullptr, nullptr, out,
                                                 nullptr, nullptr, out, SEQLEN, HIDN, FFDIM);
}

// Round 3
// 726.924 us; speedup vs baseline: 1.6465x; 1.2284x over previous
//
#include <hip/hip_runtime.h>

#define HIDN 2048
#define NHEAD 16
#define HDIM 128
#define FFDIM 8192
#define SEQLEN 2048

typedef __attribute__((ext_vector_type(8))) __bf16 bf16x8;
typedef __attribute__((ext_vector_type(4))) float f32x4;
typedef __attribute__((ext_vector_type(4))) unsigned short u16x4;
typedef __attribute__((ext_vector_type(8))) unsigned short u16x8;

__device__ __forceinline__ unsigned short f2bfu(float f) {
    unsigned int u = __float_as_uint(f);
    unsigned int r = u + 0x7fffu + ((u >> 16) & 1u);
    return (unsigned short)(r >> 16);
}
__device__ __forceinline__ float bfu2f(unsigned short u) {
    return __uint_as_float(((unsigned int)u) << 16);
}

__device__ __forceinline__ void gload16(const void* g, void* l) {
    __builtin_amdgcn_global_load_lds(
        (const __attribute__((address_space(1))) unsigned int*)g,
        (__attribute__((address_space(3))) unsigned int*)l,
        16, 0, 0);
}

// ---------------- fp32 -> bf16 weight conversion ----------------
__global__ __launch_bounds__(256)
void conv_f32_bf16(const float* __restrict__ src, unsigned short* __restrict__ dst) {
    int i = blockIdx.x * 256 + threadIdx.x;      // one thread = 8 elems
    float4 a = ((const float4*)src)[i * 2];
    float4 b = ((const float4*)src)[i * 2 + 1];
    u16x8 v;
    v[0] = f2bfu(a.x); v[1] = f2bfu(a.y); v[2] = f2bfu(a.z); v[3] = f2bfu(a.w);
    v[4] = f2bfu(b.x); v[5] = f2bfu(b.y); v[6] = f2bfu(b.z); v[7] = f2bfu(b.w);
    *(u16x8*)(dst + (size_t)i * 8) = v;
}

// ---------------- LayerNorm (fp32 in) -> bf16 out ----------------
__global__ __launch_bounds__(256)
void ln_bf16(const float* __restrict__ x, const float* __restrict__ w,
             const float* __restrict__ b, unsigned short* __restrict__ out) {
    const int row = blockIdx.x;
    const int tid = threadIdx.x;
    const float* xr = x + (size_t)row * HIDN;
    float4 v0 = ((const float4*)xr)[tid];
    float4 v1 = ((const float4*)xr)[tid + 256];
    float s = v0.x + v0.y + v0.z + v0.w + v1.x + v1.y + v1.z + v1.w;
    float q = v0.x*v0.x + v0.y*v0.y + v0.z*v0.z + v0.w*v0.w
            + v1.x*v1.x + v1.y*v1.y + v1.z*v1.z + v1.w*v1.w;
    for (int o = 32; o > 0; o >>= 1) {
        s += __shfl_down(s, o, 64);
        q += __shfl_down(q, o, 64);
    }
    __shared__ float red[8];
    const int wid = tid >> 6;
    if ((tid & 63) == 0) { red[wid] = s; red[4 + wid] = q; }
    __syncthreads();
    float st = red[0] + red[1] + red[2] + red[3];
    float qt = red[4] + red[5] + red[6] + red[7];
    float mu = st * (1.0f / HIDN);
    float var = qt * (1.0f / HIDN) - mu * mu;
    float rs = rsqrtf(var + 1e-5f);
    unsigned short* orow = out + (size_t)row * HIDN;
    int i0 = tid * 4, i1 = (tid + 256) * 4;
    orow[i0 + 0] = f2bfu((v0.x - mu) * rs * w[i0 + 0] + b[i0 + 0]);
    orow[i0 + 1] = f2bfu((v0.y - mu) * rs * w[i0 + 1] + b[i0 + 1]);
    orow[i0 + 2] = f2bfu((v0.z - mu) * rs * w[i0 + 2] + b[i0 + 2]);
    orow[i0 + 3] = f2bfu((v0.w - mu) * rs * w[i0 + 3] + b[i0 + 3]);
    orow[i1 + 0] = f2bfu((v1.x - mu) * rs * w[i1 + 0] + b[i1 + 0]);
    orow[i1 + 1] = f2bfu((v1.y - mu) * rs * w[i1 + 1] + b[i1 + 1]);
    orow[i1 + 2] = f2bfu((v1.z - mu) * rs * w[i1 + 2] + b[i1 + 2]);
    orow[i1 + 3] = f2bfu((v1.w - mu) * rs * w[i1 + 3] + b[i1 + 3]);
}

// ---------------- RoPE in-place on qk buffer [S][4096] ----------------
__global__ __launch_bounds__(256)
void rope_kernel(unsigned short* __restrict__ qk, const int* __restrict__ tsl) {
    int id = blockIdx.x * 256 + threadIdx.x;   // S * 32 * 64
    int p  = id & 63;
    int hh = (id >> 6) & 31;      // 0-15: q heads, 16-31: k heads
    int s  = id >> 11;
    int off = tsl[0] - SEQLEN;
    float inv = exp2f((float)p * -0.20762050593f);
    float ang = (float)(s + off) * inv;
    float c, sn;
    __sincosf(ang, &sn, &c);
    size_t base = (size_t)s * 4096 + hh * 128 + p;
    float x1 = bfu2f(qk[base]);
    float x2 = bfu2f(qk[base + 64]);
    qk[base]      = f2bfu(x1 * c - x2 * sn);
    qk[base + 64] = f2bfu(x2 * c + x1 * sn);
}

// ---------------- GEMM: C[M,N] = A[M,K](bf16) * B[N,K]^T(bf16), m97 structure ----------------
template<int EPI>
__global__ __launch_bounds__(256)
void gemm_bt(const unsigned short* __restrict__ A, const unsigned short* __restrict__ B,
             const float* __restrict__ bias0, const float* __restrict__ bias1,
             const float* __restrict__ bias2, const float* __restrict__ resid,
             unsigned short* __restrict__ outB, unsigned short* __restrict__ outV,
             float* __restrict__ outF, int M, int N, int K) {
    __shared__ __align__(16) unsigned short As[128 * 32];
    __shared__ __align__(16) unsigned short Bs[128 * 32];
    const int tid = threadIdx.x;
    const int brow = blockIdx.y * 128, bcol = blockIdx.x * 128;
    const int wid = tid >> 6, lane = tid & 63;
    const int wr = wid >> 1, wc = wid & 1;
    const int lr = lane & 15, lg = lane >> 4;

    f32x4 acc[4][4];
#pragma unroll
    for (int m = 0; m < 4; ++m)
#pragma unroll
        for (int n = 0; n < 4; ++n) acc[m][n] = (f32x4){0.f, 0.f, 0.f, 0.f};

    const int r0 = tid >> 2;            // 0..63
    const int c0 = (tid & 3) * 8;       // elem col in k-tile
    char* ldsA = (char*)As + wid * 1024;
    char* ldsB = (char*)Bs + wid * 1024;
    const unsigned short* gA = A + (size_t)brow * K;
    const unsigned short* gB = B + (size_t)bcol * K;

    for (int k0 = 0; k0 < K; k0 += 32) {
        gload16(gA + (size_t)r0 * K + k0 + c0, ldsA);
        gload16(gA + (size_t)(r0 + 64) * K + k0 + c0, ldsA + 4096);
        gload16(gB + (size_t)r0 * K + k0 + c0, ldsB);
        gload16(gB + (size_t)(r0 + 64) * K + k0 + c0, ldsB + 4096);
        __syncthreads();
        bf16x8 aF[4], bF[4];
#pragma unroll
        for (int m = 0; m < 4; ++m)
            aF[m] = *(const bf16x8*)&As[(wr * 64 + m * 16 + lr) * 32 + lg * 8];
#pragma unroll
        for (int n = 0; n < 4; ++n)
            bF[n] = *(const bf16x8*)&Bs[(wc * 64 + n * 16 + lr) * 32 + lg * 8];
#pragma unroll
        for (int m = 0; m < 4; ++m)
#pragma unroll
            for (int n = 0; n < 4; ++n)
                acc[m][n] = __builtin_amdgcn_mfma_f32_16x16x32_bf16(aF[m], bF[n], acc[m][n], 0, 0, 0);
        __syncthreads();
    }

#pragma unroll
    for (int n = 0; n < 4; ++n) {
        int col = bcol + wc * 64 + n * 16 + lr;
        float bv;
        if (EPI == 0) {
            bv = (col < 2048) ? bias0[col] : (col < 4096) ? bias1[col - 2048] : bias2[col - 4096];
        } else {
            bv = bias0 ? bias0[col] : 0.f;
        }
#pragma unroll
        for (int m = 0; m < 4; ++m) {
            int row0 = brow + wr * 64 + m * 16 + lg * 4;
#pragma unroll
            for (int j = 0; j < 4; ++j) {
                int row = row0 + j;
                float v = acc[m][n][j] + bv;
                if (EPI == 0) {
                    if (col < 4096) outB[(size_t)row * 4096 + col] = f2bfu(v);
                    else            outV[(size_t)(col - 4096) * SEQLEN + row] = f2bfu(v);
                } else if (EPI == 1) {
                    outB[(size_t)row * N + col] = f2bfu(v);
                } else if (EPI == 2) {
                    size_t idx = (size_t)row * N + col;
                    outF[idx] = resid[idx] + v;
                } else {
                    size_t idx = (size_t)row * N + col;
                    float g = bfu2f(outB[idx]);
                    float sg = g / (1.0f + expf(-g));
                    outB[idx] = f2bfu(sg * v);
                }
            }
        }
    }
}

// ---------------- Flash attention: 4 waves/block, QBLK=64, KVBLK=32 ----------------
// K tile [32][128] and V^T tile [128][32] staged via global_load_lds into
// double-buffered, XOR-swizzled LDS shared by all 4 waves.
__global__ __launch_bounds__(256)
void attn_kernel(const unsigned short* __restrict__ QK, const unsigned short* __restrict__ VT,
                 unsigned short* __restrict__ O) {
    __shared__ __align__(16) unsigned short Ks[2][4096];  // [32][128] swizzled ^((row&7)<<4)
    __shared__ __align__(16) unsigned short Vs[2][4096];  // [128][32] swizzled ^((d&3)<<4)
    __shared__ __align__(16) unsigned short Ps[4][16 * 40];
    const int tid = threadIdx.x;
    const int lane = tid & 63;
    const int w = tid >> 6;
    const int lr = lane & 15, lg = lane >> 4;

    // XCD-pair mapping: XCD k handles heads 2k,2k+1; longest q-blocks dispatch first
    const int id = blockIdx.x;
    const int pair = id & 7;
    const int j = id >> 3;
    const int h = pair * 2 + (j & 1);
    const int qb = 31 - (j >> 1);
    const int q0 = qb * 64;
    const int qw = q0 + w * 16;

    const unsigned short* Qb = QK + (size_t)qw * 4096 + h * 128;
    const unsigned short* Kb = QK + 2048 + h * 128;
    const unsigned short* Vb = VT + (size_t)(h * 128) * SEQLEN;

    bf16x8 qa[4];
#pragma unroll
    for (int c = 0; c < 4; ++c)
        qa[c] = *(const bf16x8*)(Qb + (size_t)lr * 4096 + c * 32 + lg * 8);

    // per-lane staging geometry (chunks 2w, 2w+1 of each tile)
    const int kc[2] = {2 * w, 2 * w + 1};
    int krow[2], kcolB[2], vd[2], vtB[2];
#pragma unroll
    for (int i = 0; i < 2; ++i) {
        krow[i]  = kc[i] * 4 + (lane >> 4);
        kcolB[i] = ((lane & 15) * 16) ^ ((krow[i] & 7) << 4);
        vd[i]    = kc[i] * 16 + (lane >> 2);
        vtB[i]   = ((lane & 3) * 16) ^ ((vd[i] & 3) << 4);
    }

    f32x4 acc[8];
#pragma unroll
    for (int dt = 0; dt < 8; ++dt) acc[dt] = (f32x4){0.f, 0.f, 0.f, 0.f};
    float mrow[4] = {-INFINITY, -INFINITY, -INFINITY, -INFINITY};
    float lrow[4] = {0.f, 0.f, 0.f, 0.f};

    const float sc = 0.08838834764831845f;  // 1/sqrt(128)
    const int ntile = 2 * qb + 2;

    // prologue: stage tile 0 into buffer 0
#pragma unroll
    for (int i = 0; i < 2; ++i) {
        gload16(Kb + (size_t)krow[i] * 4096 + (kcolB[i] >> 1), (char*)&Ks[0][0] + kc[i] * 1024);
        gload16(Vb + (size_t)vd[i] * SEQLEN + (vtB[i] >> 1),   (char*)&Vs[0][0] + kc[i] * 1024);
    }
    __syncthreads();

    for (int tt = 0; tt < ntile; ++tt) {
        const int cur = tt & 1;
        const int t0 = tt * 32;
        if (tt + 1 < ntile) {
            const int t1 = t0 + 32;
#pragma unroll
            for (int i = 0; i < 2; ++i) {
                gload16(Kb + (size_t)(t1 + krow[i]) * 4096 + (kcolB[i] >> 1),
                        (char*)&Ks[cur ^ 1][0] + kc[i] * 1024);
                gload16(Vb + (size_t)vd[i] * SEQLEN + t1 + (vtB[i] >> 1),
                        (char*)&Vs[cur ^ 1][0] + kc[i] * 1024);
            }
        }
        // QK^T for this wave's 16 q-rows x 32 kv
        f32x4 s[2];
        s[0] = (f32x4){0.f, 0.f, 0.f, 0.f};
        s[1] = (f32x4){0.f, 0.f, 0.f, 0.f};
#pragma unroll
        for (int th = 0; th < 2; ++th) {
            const int row = th * 16 + lr;
#pragma unroll
            for (int c = 0; c < 4; ++c) {
                bf16x8 kb = *(const bf16x8*)((char*)&Ks[cur][0] + row * 256 +
                                             (((c * 64) + lg * 16) ^ ((lr & 7) << 4)));
                s[th] = __builtin_amdgcn_mfma_f32_16x16x32_bf16(qa[c], kb, s[th], 0, 0, 0);
            }
        }
        // scale + causal mask
#pragma unroll
        for (int th = 0; th < 2; ++th) {
            int tg = t0 + th * 16 + lr;
#pragma unroll
            for (int jj = 0; jj < 4; ++jj) {
                int qg = qw + lg * 4 + jj;
                s[th][jj] = s[th][jj] * sc + (tg <= qg ? 0.f : -1e9f);
            }
        }
        // row max over 16 lanes
        float mt[4];
#pragma unroll
        for (int jj = 0; jj < 4; ++jj) mt[jj] = fmaxf(s[0][jj], s[1][jj]);
#pragma unroll
        for (int o = 8; o > 0; o >>= 1)
#pragma unroll
            for (int jj = 0; jj < 4; ++jj) mt[jj] = fmaxf(mt[jj], __shfl_xor(mt[jj], o, 16));
        float alpha[4];
#pragma unroll
        for (int jj = 0; jj < 4; ++jj) {
            float mn = fmaxf(mrow[jj], mt[jj]);
            alpha[jj] = __expf(mrow[jj] - mn);
            mrow[jj] = mn;
        }
        float ps[4] = {0.f, 0.f, 0.f, 0.f};
#pragma unroll
        for (int th = 0; th < 2; ++th)
#pragma unroll
            for (int jj = 0; jj < 4; ++jj) {
                float p = __expf(s[th][jj] - mrow[jj]);
                s[th][jj] = p;
                ps[jj] += p;
            }
#pragma unroll
        for (int o = 8; o > 0; o >>= 1)
#pragma unroll
            for (int jj = 0; jj < 4; ++jj) ps[jj] += __shfl_xor(ps[jj], o, 16);
#pragma unroll
        for (int jj = 0; jj < 4; ++jj) lrow[jj] = lrow[jj] * alpha[jj] + ps[jj];
#pragma unroll
        for (int dt = 0; dt < 8; ++dt)
#pragma unroll
            for (int jj = 0; jj < 4; ++jj) acc[dt][jj] *= alpha[jj];
        // P tile to per-wave LDS slice
#pragma unroll
        for (int th = 0; th < 2; ++th)
#pragma unroll
            for (int jj = 0; jj < 4; ++jj)
                Ps[w][(lg * 4 + jj) * 40 + th * 16 + lr] = f2bfu(s[th][jj]);
        // PV
        bf16x8 pa = *(const bf16x8*)&Ps[w][lr * 40 + lg * 8];
#pragma unroll
        for (int dt = 0; dt < 8; ++dt) {
            const int d = dt * 16 + lr;
            bf16x8 vb = *(const bf16x8*)((char*)&Vs[cur][0] + d * 64 +
                                         ((lg * 16) ^ ((lr & 3) << 4)));
            acc[dt] = __builtin_amdgcn_mfma_f32_16x16x32_bf16(pa, vb, acc[dt], 0, 0, 0);
        }
        __syncthreads();
    }
    float invl[4];
#pragma unroll
    for (int jj = 0; jj < 4; ++jj) invl[jj] = 1.0f / lrow[jj];
#pragma unroll
    for (int dt = 0; dt < 8; ++dt)
#pragma unroll
        for (int jj = 0; jj < 4; ++jj)
            O[(size_t)(qw + lg * 4 + jj) * HIDN + h * HDIM + dt * 16 + lr] = f2bfu(acc[dt][jj] * invl[jj]);
}

extern "C" void kernel_launch(void* const* d_in, const int* in_sizes, int n_in,
                              void* d_out, int out_size, void* d_ws, size_t ws_size,
                              hipStream_t stream) {
    const float* hidden = (const float*)d_in[0];
    const float* ln1w = (const float*)d_in[2];
    const float* ln1b = (const float*)d_in[3];
    const float* ln2w = (const float*)d_in[4];
    const float* ln2b = (const float*)d_in[5];
    const float* wq = (const float*)d_in[6];
    const float* bq = (const float*)d_in[7];
    const float* wk = (const float*)d_in[8];
    const float* bk = (const float*)d_in[9];
    const float* wv = (const float*)d_in[10];
    const float* bv = (const float*)d_in[11];
    const float* wo = (const float*)d_in[12];
    const float* bo = (const float*)d_in[13];
    const float* wg = (const float*)d_in[14];
    const float* wu = (const float*)d_in[15];
    const float* wd = (const float*)d_in[16];
    const int* tsl = (const int*)d_in[17];
    float* out = (float*)d_out;

    char* ws = (char*)d_ws;
    const size_t MB = 1024 * 1024;
    unsigned short* Wbuf = (unsigned short*)(ws);            // 32 MiB weight staging
    unsigned short* qk   = (unsigned short*)(ws + 32 * MB);  // [2048][4096] 16 MiB; y reuses
    unsigned short* vt   = (unsigned short*)(ws + 48 * MB);  // [2048 d][2048 t] 8 MiB
    unsigned short* x_bf = (unsigned short*)(ws + 56 * MB);  // 8 MiB; attn out reuses
    unsigned short* g_bf = (unsigned short*)(ws + 64 * MB);  // [2048][8192] 32 MiB
    unsigned short* y_bf = qk;                               // reuse after attn

    const int HID2 = HIDN * HIDN;            // 4194304
    const int CONV_HID = HID2 / 8 / 256;     // 2048 blocks
    const int CONV_FF  = FFDIM * HIDN / 8 / 256;  // 8192 blocks

    // ---- QKV ----
    conv_f32_bf16<<<CONV_HID, 256, 0, stream>>>(wq, Wbuf);
    conv_f32_bf16<<<CONV_HID, 256, 0, stream>>>(wk, Wbuf + HID2);
    conv_f32_bf16<<<CONV_HID, 256, 0, stream>>>(wv, Wbuf + 2 * (size_t)HID2);
    ln_bf16<<<SEQLEN, 256, 0, stream>>>(hidden, ln1w, ln1b, x_bf);
    gemm_bt<0><<<dim3(48, 16), 256, 0, stream>>>(x_bf, Wbuf, bq, bk, bv, nullptr,
                                                 qk, vt, nullptr, SEQLEN, 3 * HIDN, HIDN);
    rope_kernel<<<SEQLEN * 32 * 64 / 256, 256, 0, stream>>>(qk, tsl);
    attn_kernel<<<512, 256, 0, stream>>>(qk, vt, x_bf);

    // ---- WO + residual ----
    conv_f32_bf16<<<CONV_HID, 256, 0, stream>>>(wo, Wbuf);
    gemm_bt<2><<<dim3(16, 16), 256, 0, stream>>>(x_bf, Wbuf, bo, nullptr, nullptr, hidden,
                                                 nullptr, nullptr, out, SEQLEN, HIDN, HIDN);

    // ---- FFN ----
    ln_bf16<<<SEQLEN, 256, 0, stream>>>(out, ln2w, ln2b, y_bf);
    conv_f32_bf16<<<CONV_FF, 256, 0, stream>>>(wg, Wbuf);
    gemm_bt<1><<<dim3(64, 16), 256, 0, stream>>>(y_bf, Wbuf, nullptr, nullptr, nullptr, nullptr,
                                                 g_bf, nullptr, nullptr, SEQLEN, FFDIM, HIDN);
    conv_f32_bf16<<<CONV_FF, 256, 0, stream>>>(wu, Wbuf);
    gemm_bt<3><<<dim3(64, 16), 256, 0, stream>>>(y_bf, Wbuf, nullptr, nullptr, nullptr, nullptr,
                                                 g_bf, nullptr, nullptr, SEQLEN, FFDIM, HIDN);
    conv_f32_bf16<<<CONV_FF, 256, 0, stream>>>(wd, Wbuf);
    gemm_bt<2><<<dim3(16, 16), 256, 0, stream>>>(g_bf, Wbuf, nullptr, nullptr, nullptr, out,
                                                 nullptr, nullptr, out, SEQLEN, HIDN, FFDIM);
}

// Round 4
// 557.405 us; speedup vs baseline: 2.1473x; 1.3041x over previous
//
#include <hip/hip_runtime.h>

#define HIDN 2048
#define NHEAD 16
#define HDIM 128
#define FFDIM 8192
#define SEQLEN 2048

typedef __attribute__((ext_vector_type(8))) __bf16 bf16x8;
typedef __attribute__((ext_vector_type(4))) float f32x4;
typedef __attribute__((ext_vector_type(4))) unsigned short u16x4;
typedef __attribute__((ext_vector_type(8))) unsigned short u16x8;

__device__ __forceinline__ unsigned short f2bfu(float f) {
    unsigned int u = __float_as_uint(f);
    unsigned int r = u + 0x7fffu + ((u >> 16) & 1u);
    return (unsigned short)(r >> 16);
}
__device__ __forceinline__ float bfu2f(unsigned short u) {
    return __uint_as_float(((unsigned int)u) << 16);
}

__device__ __forceinline__ void gload16(const void* g, void* l) {
    __builtin_amdgcn_global_load_lds(
        (const __attribute__((address_space(1))) unsigned int*)g,
        (__attribute__((address_space(3))) unsigned int*)l,
        16, 0, 0);
}

// ---------------- fp32 -> bf16 weight conversion ----------------
__global__ __launch_bounds__(256)
void conv_f32_bf16(const float* __restrict__ src, unsigned short* __restrict__ dst) {
    int i = blockIdx.x * 256 + threadIdx.x;
    float4 a = ((const float4*)src)[i * 2];
    float4 b = ((const float4*)src)[i * 2 + 1];
    u16x8 v;
    v[0] = f2bfu(a.x); v[1] = f2bfu(a.y); v[2] = f2bfu(a.z); v[3] = f2bfu(a.w);
    v[4] = f2bfu(b.x); v[5] = f2bfu(b.y); v[6] = f2bfu(b.z); v[7] = f2bfu(b.w);
    *(u16x8*)(dst + (size_t)i * 8) = v;
}

// ---------------- LayerNorm (fp32 in) -> bf16 out ----------------
__global__ __launch_bounds__(256)
void ln_bf16(const float* __restrict__ x, const float* __restrict__ w,
             const float* __restrict__ b, unsigned short* __restrict__ out) {
    const int row = blockIdx.x;
    const int tid = threadIdx.x;
    const float* xr = x + (size_t)row * HIDN;
    float4 v0 = ((const float4*)xr)[tid];
    float4 v1 = ((const float4*)xr)[tid + 256];
    float s = v0.x + v0.y + v0.z + v0.w + v1.x + v1.y + v1.z + v1.w;
    float q = v0.x*v0.x + v0.y*v0.y + v0.z*v0.z + v0.w*v0.w
            + v1.x*v1.x + v1.y*v1.y + v1.z*v1.z + v1.w*v1.w;
    for (int o = 32; o > 0; o >>= 1) {
        s += __shfl_down(s, o, 64);
        q += __shfl_down(q, o, 64);
    }
    __shared__ float red[8];
    const int wid = tid >> 6;
    if ((tid & 63) == 0) { red[wid] = s; red[4 + wid] = q; }
    __syncthreads();
    float st = red[0] + red[1] + red[2] + red[3];
    float qt = red[4] + red[5] + red[6] + red[7];
    float mu = st * (1.0f / HIDN);
    float var = qt * (1.0f / HIDN) - mu * mu;
    float rs = rsqrtf(var + 1e-5f);
    unsigned short* orow = out + (size_t)row * HIDN;
    int i0 = tid * 4, i1 = (tid + 256) * 4;
    orow[i0 + 0] = f2bfu((v0.x - mu) * rs * w[i0 + 0] + b[i0 + 0]);
    orow[i0 + 1] = f2bfu((v0.y - mu) * rs * w[i0 + 1] + b[i0 + 1]);
    orow[i0 + 2] = f2bfu((v0.z - mu) * rs * w[i0 + 2] + b[i0 + 2]);
    orow[i0 + 3] = f2bfu((v0.w - mu) * rs * w[i0 + 3] + b[i0 + 3]);
    orow[i1 + 0] = f2bfu((v1.x - mu) * rs * w[i1 + 0] + b[i1 + 0]);
    orow[i1 + 1] = f2bfu((v1.y - mu) * rs * w[i1 + 1] + b[i1 + 1]);
    orow[i1 + 2] = f2bfu((v1.z - mu) * rs * w[i1 + 2] + b[i1 + 2]);
    orow[i1 + 3] = f2bfu((v1.w - mu) * rs * w[i1 + 3] + b[i1 + 3]);
}

// ---------------- RoPE in-place on qk buffer [S][4096] ----------------
__global__ __launch_bounds__(256)
void rope_kernel(unsigned short* __restrict__ qk, const int* __restrict__ tsl) {
    int id = blockIdx.x * 256 + threadIdx.x;
    int p  = id & 63;
    int hh = (id >> 6) & 31;
    int s  = id >> 11;
    int off = tsl[0] - SEQLEN;
    float inv = exp2f((float)p * -0.20762050593f);
    float ang = (float)(s + off) * inv;
    float c, sn;
    __sincosf(ang, &sn, &c);
    size_t base = (size_t)s * 4096 + hh * 128 + p;
    float x1 = bfu2f(qk[base]);
    float x2 = bfu2f(qk[base + 64]);
    qk[base]      = f2bfu(x1 * c - x2 * sn);
    qk[base + 64] = f2bfu(x2 * c + x1 * sn);
}

// ================= 256x256 8-phase GEMM: C = A(bf16) * B^T(bf16) =================
// EPI 0 (QKV):  col<4096 -> qk[row*4096+col]+bias; else vt[(col-4096)*SEQ+row]+bv
// EPI 1 (BF):   outB[row*ldc+col] = bf16(acc)
// EPI 3 (SILU): outB[row*ldc+col] = bf16(silu(prev)*acc) in-place
// EPI 4 (PART): outB[sk*2048*2048 + row*2048+col] = bf16(acc)   (split-K partial)
#define BAR __builtin_amdgcn_s_barrier()
#define VM4 asm volatile("s_waitcnt vmcnt(4)" ::: "memory")
#define VM0 asm volatile("s_waitcnt vmcnt(0)" ::: "memory")

#define STAGE_A(tile, h) { const int k0_ = k_start + (tile) * 64;                      \
  _Pragma("unroll") for (int i_ = 0; i_ < 2; ++i_) {                                   \
    int d_ = (h) * 16384 + i_ * 8192 + tid * 16;                                       \
    int r_ = d_ >> 7;                                                                  \
    int cb_ = (d_ & 127) ^ ((r_ & 7) << 4);                                            \
    gload16((const char*)Ab + ((size_t)(brow + r_) * lda + k0_) * 2 + cb_,             \
            smem + ((tile) & 1) * 65536 + (h) * 16384 + i_ * 8192 + w * 1024); } }

#define STAGE_B(tile, h) { const int k0_ = k_start + (tile) * 64;                      \
  _Pragma("unroll") for (int i_ = 0; i_ < 2; ++i_) {                                   \
    int d_ = (h) * 16384 + i_ * 8192 + tid * 16;                                       \
    int r_ = d_ >> 7;                                                                  \
    int cb_ = (d_ & 127) ^ ((r_ & 7) << 4);                                            \
    gload16((const char*)Bb + ((size_t)(bcol + r_) * ldb + k0_) * 2 + cb_,             \
            smem + ((tile) & 1) * 65536 + 32768 + (h) * 16384 + i_ * 8192 + w * 1024); } }

#define LDB(BO)                                                                        \
  _Pragma("unroll") for (int n_ = 0; n_ < 4; ++n_)                                     \
  _Pragma("unroll") for (int kk_ = 0; kk_ < 2; ++kk_)                                  \
    bF[n_][kk_] = *(const bf16x8*)(smem + (BO) + bbase + n_ * 2048 + colb[kk_]);

#define LDA2(BO, MP)                                                                   \
  _Pragma("unroll") for (int dm_ = 0; dm_ < 2; ++dm_)                                  \
  _Pragma("unroll") for (int kk_ = 0; kk_ < 2; ++kk_)                                  \
    aF[dm_][kk_] = *(const bf16x8*)(smem + (BO) + abase + ((MP) * 2 + dm_) * 2048 + colb[kk_]);

#define MM(MP)                                                                         \
  __builtin_amdgcn_s_setprio(1);                                                       \
  _Pragma("unroll") for (int dm_ = 0; dm_ < 2; ++dm_)                                  \
  _Pragma("unroll") for (int n_ = 0; n_ < 4; ++n_)                                     \
  _Pragma("unroll") for (int kk_ = 0; kk_ < 2; ++kk_)                                  \
    acc[(MP) * 2 + dm_][n_] = __builtin_amdgcn_mfma_f32_16x16x32_bf16(                 \
        aF[dm_][kk_], bF[n_][kk_], acc[(MP) * 2 + dm_][n_], 0, 0, 0);                  \
  __builtin_amdgcn_s_setprio(0);

template<int EPI>
__global__ __launch_bounds__(512, 1)
void gemm256(const unsigned short* __restrict__ Ab, int lda,
             const unsigned short* __restrict__ Bb, int ldb,
             int k_len, int nbx, int ldc,
             const float* __restrict__ bias0, const float* __restrict__ bias1,
             const float* __restrict__ bias2,
             unsigned short* __restrict__ outB, unsigned short* __restrict__ outV) {
    extern __shared__ char smem[];   // 131072 bytes: 2 bufs x (A 32KB + B 32KB)
    const int tid = threadIdx.x;
    const int w = tid >> 6, lane = tid & 63;
    const int lr = lane & 15, lg = lane >> 4;
    const int wrow = (w >> 2) * 128;   // wave M offset
    const int wc = w & 3;              // wave N quarter

    // XCD-aware bijective swizzle (gridDim.x % 8 == 0 for all our grids)
    const int nwg = gridDim.x;
    const int wg = blockIdx.x;
    const int swz = (wg & 7) * (nwg >> 3) + (wg >> 3);
    const int bx = swz % nbx, by = swz / nbx;
    const int brow = by * 256, bcol = bx * 256;
    const int k_start = blockIdx.y * k_len;

    const int xorv = (lr & 7) << 4;
    int colb[2];
    colb[0] = (lg * 16) ^ xorv;
    colb[1] = (64 + lg * 16) ^ xorv;
    const int abase = (wrow + lr) * 128;
    const int bbase = 32768 + (wc * 64 + lr) * 128;

    f32x4 acc[8][4];
#pragma unroll
    for (int m = 0; m < 8; ++m)
#pragma unroll
        for (int n = 0; n < 4; ++n) acc[m][n] = (f32x4){0.f, 0.f, 0.f, 0.f};

    bf16x8 bF[4][2], aF[2][2];

    const int NT = k_len >> 6;    // 64-wide K tiles (even; >= 4)
    const int NIT = NT >> 1;

    // prologue: tile0 (buf0) fully, tile1 B halves (buf1)
    STAGE_A(0, 0); STAGE_A(0, 1); STAGE_B(0, 0); STAGE_B(0, 1);
    STAGE_B(1, 0); STAGE_B(1, 1);
    VM4; BAR;

    for (int it = 0; it < NIT; ++it) {
        const int T = 2 * it;
        const bool s2 = (T + 2) < NT, s3 = (T + 3) < NT;
        // ---- tile T (buf0) ----
        LDB(0); LDA2(0, 0); STAGE_A(T + 1, 0); MM(0); BAR;
        LDA2(0, 1); STAGE_A(T + 1, 1); MM(1); BAR;
        LDA2(0, 2); if (s2) STAGE_B(T + 2, 0); MM(2); BAR;
        LDA2(0, 3); if (s2) STAGE_B(T + 2, 1); MM(3);
        if (s2) { VM4; } else { VM0; }
        BAR;
        // ---- tile T+1 (buf1) ----
        LDB(65536); LDA2(65536, 0); if (s2) STAGE_A(T + 2, 0); MM(0); BAR;
        LDA2(65536, 1); if (s2) STAGE_A(T + 2, 1); MM(1); BAR;
        LDA2(65536, 2); if (s3) STAGE_B(T + 3, 0); MM(2); BAR;
        LDA2(65536, 3); if (s3) STAGE_B(T + 3, 1); MM(3);
        if (s3) { VM4; } else { VM0; }
        BAR;
    }

    // ---- epilogue ----
#pragma unroll
    for (int n = 0; n < 4; ++n) {
        const int col = bcol + wc * 64 + n * 16 + lr;
        float bv = 0.f;
        if (EPI == 0)
            bv = (col < 2048) ? bias0[col] : (col < 4096) ? bias1[col - 2048] : bias2[col - 4096];
#pragma unroll
        for (int m = 0; m < 8; ++m) {
#pragma unroll
            for (int j = 0; j < 4; ++j) {
                const int row = brow + wrow + m * 16 + lg * 4 + j;
                float v = acc[m][n][j] + bv;
                if (EPI == 0) {
                    if (col < 4096) outB[(size_t)row * 4096 + col] = f2bfu(v);
                    else            outV[(size_t)(col - 4096) * SEQLEN + row] = f2bfu(v);
                } else if (EPI == 1) {
                    outB[(size_t)row * ldc + col] = f2bfu(v);
                } else if (EPI == 3) {
                    size_t idx = (size_t)row * ldc + col;
                    float g = bfu2f(outB[idx]);
                    float sg = g / (1.0f + expf(-g));
                    outB[idx] = f2bfu(sg * v);
                } else {
                    outB[(size_t)blockIdx.y * 4194304 + (size_t)row * 2048 + col] = f2bfu(v);
                }
            }
        }
    }
}

// ---------------- split-K reduce: out += sum of 4 bf16 partials ----------------
__global__ __launch_bounds__(256)
void reduce4_add(const unsigned short* __restrict__ part, float* __restrict__ out) {
    int i = blockIdx.x * 256 + threadIdx.x;    // float4 index
    float4 o = ((const float4*)out)[i];
#pragma unroll
    for (int sk = 0; sk < 4; ++sk) {
        u16x4 p = ((const u16x4*)(part + (size_t)sk * 4194304))[i];
        o.x += bfu2f(p[0]); o.y += bfu2f(p[1]); o.z += bfu2f(p[2]); o.w += bfu2f(p[3]);
    }
    ((float4*)out)[i] = o;
}

// ---------------- 128x128 GEMM (m97 structure), kept for WO ----------------
template<int EPI>
__global__ __launch_bounds__(256)
void gemm_bt(const unsigned short* __restrict__ A, const unsigned short* __restrict__ B,
             const float* __restrict__ bias0, const float* __restrict__ resid,
             float* __restrict__ outF, int M, int N, int K) {
    __shared__ __align__(16) unsigned short As[128 * 32];
    __shared__ __align__(16) unsigned short Bs[128 * 32];
    const int tid = threadIdx.x;
    const int brow = blockIdx.y * 128, bcol = blockIdx.x * 128;
    const int wid = tid >> 6, lane = tid & 63;
    const int wr = wid >> 1, wc = wid & 1;
    const int lr = lane & 15, lg = lane >> 4;

    f32x4 acc[4][4];
#pragma unroll
    for (int m = 0; m < 4; ++m)
#pragma unroll
        for (int n = 0; n < 4; ++n) acc[m][n] = (f32x4){0.f, 0.f, 0.f, 0.f};

    const int r0 = tid >> 2;
    const int c0 = (tid & 3) * 8;
    char* ldsA = (char*)As + wid * 1024;
    char* ldsB = (char*)Bs + wid * 1024;
    const unsigned short* gA = A + (size_t)brow * K;
    const unsigned short* gB = B + (size_t)bcol * K;

    for (int k0 = 0; k0 < K; k0 += 32) {
        gload16(gA + (size_t)r0 * K + k0 + c0, ldsA);
        gload16(gA + (size_t)(r0 + 64) * K + k0 + c0, ldsA + 4096);
        gload16(gB + (size_t)r0 * K + k0 + c0, ldsB);
        gload16(gB + (size_t)(r0 + 64) * K + k0 + c0, ldsB + 4096);
        __syncthreads();
        bf16x8 aFr[4], bFr[4];
#pragma unroll
        for (int m = 0; m < 4; ++m)
            aFr[m] = *(const bf16x8*)&As[(wr * 64 + m * 16 + lr) * 32 + lg * 8];
#pragma unroll
        for (int n = 0; n < 4; ++n)
            bFr[n] = *(const bf16x8*)&Bs[(wc * 64 + n * 16 + lr) * 32 + lg * 8];
#pragma unroll
        for (int m = 0; m < 4; ++m)
#pragma unroll
            for (int n = 0; n < 4; ++n)
                acc[m][n] = __builtin_amdgcn_mfma_f32_16x16x32_bf16(aFr[m], bFr[n], acc[m][n], 0, 0, 0);
        __syncthreads();
    }

#pragma unroll
    for (int n = 0; n < 4; ++n) {
        int col = bcol + wc * 64 + n * 16 + lr;
        float bv = bias0 ? bias0[col] : 0.f;
#pragma unroll
        for (int m = 0; m < 4; ++m) {
            int row0 = brow + wr * 64 + m * 16 + lg * 4;
#pragma unroll
            for (int j = 0; j < 4; ++j) {
                size_t idx = (size_t)(row0 + j) * N + col;
                outF[idx] = resid[idx] + acc[m][n][j] + bv;
            }
        }
    }
}

// ---------------- Flash attention: 4 waves/block, QBLK=64, KVBLK=32 ----------------
__global__ __launch_bounds__(256)
void attn_kernel(const unsigned short* __restrict__ QK, const unsigned short* __restrict__ VT,
                 unsigned short* __restrict__ O) {
    __shared__ __align__(16) unsigned short Ks[2][4096];
    __shared__ __align__(16) unsigned short Vs[2][4096];
    __shared__ __align__(16) unsigned short Ps[4][16 * 40];
    const int tid = threadIdx.x;
    const int lane = tid & 63;
    const int w = tid >> 6;
    const int lr = lane & 15, lg = lane >> 4;

    const int id = blockIdx.x;
    const int pair = id & 7;
    const int j = id >> 3;
    const int h = pair * 2 + (j & 1);
    const int qb = 31 - (j >> 1);
    const int q0 = qb * 64;
    const int qw = q0 + w * 16;

    const unsigned short* Qb = QK + (size_t)qw * 4096 + h * 128;
    const unsigned short* Kb = QK + 2048 + h * 128;
    const unsigned short* Vb = VT + (size_t)(h * 128) * SEQLEN;

    bf16x8 qa[4];
#pragma unroll
    for (int c = 0; c < 4; ++c)
        qa[c] = *(const bf16x8*)(Qb + (size_t)lr * 4096 + c * 32 + lg * 8);

    const int kc[2] = {2 * w, 2 * w + 1};
    int krow[2], kcolB[2], vd[2], vtB[2];
#pragma unroll
    for (int i = 0; i < 2; ++i) {
        krow[i]  = kc[i] * 4 + (lane >> 4);
        kcolB[i] = ((lane & 15) * 16) ^ ((krow[i] & 7) << 4);
        vd[i]    = kc[i] * 16 + (lane >> 2);
        vtB[i]   = ((lane & 3) * 16) ^ ((vd[i] & 3) << 4);
    }

    f32x4 acc[8];
#pragma unroll
    for (int dt = 0; dt < 8; ++dt) acc[dt] = (f32x4){0.f, 0.f, 0.f, 0.f};
    float mrow[4] = {-INFINITY, -INFINITY, -INFINITY, -INFINITY};
    float lrow[4] = {0.f, 0.f, 0.f, 0.f};

    const float sc = 0.08838834764831845f;
    const int ntile = 2 * qb + 2;

#pragma unroll
    for (int i = 0; i < 2; ++i) {
        gload16(Kb + (size_t)krow[i] * 4096 + (kcolB[i] >> 1), (char*)&Ks[0][0] + kc[i] * 1024);
        gload16(Vb + (size_t)vd[i] * SEQLEN + (vtB[i] >> 1),   (char*)&Vs[0][0] + kc[i] * 1024);
    }
    __syncthreads();

    for (int tt = 0; tt < ntile; ++tt) {
        const int cur = tt & 1;
        const int t0 = tt * 32;
        if (tt + 1 < ntile) {
            const int t1 = t0 + 32;
#pragma unroll
            for (int i = 0; i < 2; ++i) {
                gload16(Kb + (size_t)(t1 + krow[i]) * 4096 + (kcolB[i] >> 1),
                        (char*)&Ks[cur ^ 1][0] + kc[i] * 1024);
                gload16(Vb + (size_t)vd[i] * SEQLEN + t1 + (vtB[i] >> 1),
                        (char*)&Vs[cur ^ 1][0] + kc[i] * 1024);
            }
        }
        f32x4 s[2];
        s[0] = (f32x4){0.f, 0.f, 0.f, 0.f};
        s[1] = (f32x4){0.f, 0.f, 0.f, 0.f};
#pragma unroll
        for (int th = 0; th < 2; ++th) {
            const int row = th * 16 + lr;
#pragma unroll
            for (int c = 0; c < 4; ++c) {
                bf16x8 kb = *(const bf16x8*)((char*)&Ks[cur][0] + row * 256 +
                                             (((c * 64) + lg * 16) ^ ((lr & 7) << 4)));
                s[th] = __builtin_amdgcn_mfma_f32_16x16x32_bf16(qa[c], kb, s[th], 0, 0, 0);
            }
        }
#pragma unroll
        for (int th = 0; th < 2; ++th) {
            int tg = t0 + th * 16 + lr;
#pragma unroll
            for (int jj = 0; jj < 4; ++jj) {
                int qg = qw + lg * 4 + jj;
                s[th][jj] = s[th][jj] * sc + (tg <= qg ? 0.f : -1e9f);
            }
        }
        float mt[4];
#pragma unroll
        for (int jj = 0; jj < 4; ++jj) mt[jj] = fmaxf(s[0][jj], s[1][jj]);
#pragma unroll
        for (int o = 8; o > 0; o >>= 1)
#pragma unroll
            for (int jj = 0; jj < 4; ++jj) mt[jj] = fmaxf(mt[jj], __shfl_xor(mt[jj], o, 16));
        float alpha[4];
#pragma unroll
        for (int jj = 0; jj < 4; ++jj) {
            float mn = fmaxf(mrow[jj], mt[jj]);
            alpha[jj] = __expf(mrow[jj] - mn);
            mrow[jj] = mn;
        }
        float ps[4] = {0.f, 0.f, 0.f, 0.f};
#pragma unroll
        for (int th = 0; th < 2; ++th)
#pragma unroll
            for (int jj = 0; jj < 4; ++jj) {
                float p = __expf(s[th][jj] - mrow[jj]);
                s[th][jj] = p;
                ps[jj] += p;
            }
#pragma unroll
        for (int o = 8; o > 0; o >>= 1)
#pragma unroll
            for (int jj = 0; jj < 4; ++jj) ps[jj] += __shfl_xor(ps[jj], o, 16);
#pragma unroll
        for (int jj = 0; jj < 4; ++jj) lrow[jj] = lrow[jj] * alpha[jj] + ps[jj];
#pragma unroll
        for (int dt = 0; dt < 8; ++dt)
#pragma unroll
            for (int jj = 0; jj < 4; ++jj) acc[dt][jj] *= alpha[jj];
#pragma unroll
        for (int th = 0; th < 2; ++th)
#pragma unroll
            for (int jj = 0; jj < 4; ++jj)
                Ps[w][(lg * 4 + jj) * 40 + th * 16 + lr] = f2bfu(s[th][jj]);
        bf16x8 pa = *(const bf16x8*)&Ps[w][lr * 40 + lg * 8];
#pragma unroll
        for (int dt = 0; dt < 8; ++dt) {
            const int d = dt * 16 + lr;
            bf16x8 vb = *(const bf16x8*)((char*)&Vs[cur][0] + d * 64 +
                                         ((lg * 16) ^ ((lr & 3) << 4)));
            acc[dt] = __builtin_amdgcn_mfma_f32_16x16x32_bf16(pa, vb, acc[dt], 0, 0, 0);
        }
        __syncthreads();
    }
    float invl[4];
#pragma unroll
    for (int jj = 0; jj < 4; ++jj) invl[jj] = 1.0f / lrow[jj];
#pragma unroll
    for (int dt = 0; dt < 8; ++dt)
#pragma unroll
        for (int jj = 0; jj < 4; ++jj)
            O[(size_t)(qw + lg * 4 + jj) * HIDN + h * HDIM + dt * 16 + lr] = f2bfu(acc[dt][jj] * invl[jj]);
}

extern "C" void kernel_launch(void* const* d_in, const int* in_sizes, int n_in,
                              void* d_out, int out_size, void* d_ws, size_t ws_size,
                              hipStream_t stream) {
    const float* hidden = (const float*)d_in[0];
    const float* ln1w = (const float*)d_in[2];
    const float* ln1b = (const float*)d_in[3];
    const float* ln2w = (const float*)d_in[4];
    const float* ln2b = (const float*)d_in[5];
    const float* wq = (const float*)d_in[6];
    const float* bq = (const float*)d_in[7];
    const float* wk = (const float*)d_in[8];
    const float* bk = (const float*)d_in[9];
    const float* wv = (const float*)d_in[10];
    const float* bv = (const float*)d_in[11];
    const float* wo = (const float*)d_in[12];
    const float* bo = (const float*)d_in[13];
    const float* wg = (const float*)d_in[14];
    const float* wu = (const float*)d_in[15];
    const float* wd = (const float*)d_in[16];
    const int* tsl = (const int*)d_in[17];
    float* out = (float*)d_out;

    char* ws = (char*)d_ws;
    const size_t MB = 1024 * 1024;
    unsigned short* Wbuf = (unsigned short*)(ws);            // 32 MiB weight staging
    unsigned short* qk   = (unsigned short*)(ws + 32 * MB);  // 16 MiB [2048][4096]; part reuses
    unsigned short* vt   = (unsigned short*)(ws + 48 * MB);  // 8 MiB
    unsigned short* x_bf = (unsigned short*)(ws + 56 * MB);  // 8 MiB; attn out reuses
    unsigned short* g_bf = (unsigned short*)(ws + 64 * MB);  // 32 MiB [2048][8192]
    unsigned short* part = qk;                               // 32 MiB (qk..x_bf) free post-attn... (qk+vt+x_bf = 32 MiB)
    unsigned short* y_bf = vt;                               // ln2 out: reuse vt (free post-attn), 8 MiB

    const int HID2 = HIDN * HIDN;
    const int CONV_HID = HID2 / 8 / 256;
    const int CONV_FF  = FFDIM * HIDN / 8 / 256;
    const size_t LDSZ = 131072;

    // ---- QKV ----
    conv_f32_bf16<<<CONV_HID, 256, 0, stream>>>(wq, Wbuf);
    conv_f32_bf16<<<CONV_HID, 256, 0, stream>>>(wk, Wbuf + HID2);
    conv_f32_bf16<<<CONV_HID, 256, 0, stream>>>(wv, Wbuf + 2 * (size_t)HID2);
    ln_bf16<<<SEQLEN, 256, 0, stream>>>(hidden, ln1w, ln1b, x_bf);
    gemm256<0><<<dim3(192, 1), 512, LDSZ, stream>>>(x_bf, HIDN, Wbuf, HIDN, HIDN, 24, 0,
                                                    bq, bk, bv, qk, vt);
    rope_kernel<<<SEQLEN * 32 * 64 / 256, 256, 0, stream>>>(qk, tsl);
    attn_kernel<<<512, 256, 0, stream>>>(qk, vt, x_bf);

    // ---- WO + residual ----
    conv_f32_bf16<<<CONV_HID, 256, 0, stream>>>(wo, Wbuf);
    gemm_bt<2><<<dim3(16, 16), 256, 0, stream>>>(x_bf, Wbuf, bo, hidden, out, SEQLEN, HIDN, HIDN);

    // ---- FFN ----
    ln_bf16<<<SEQLEN, 256, 0, stream>>>(out, ln2w, ln2b, y_bf);
    conv_f32_bf16<<<CONV_FF, 256, 0, stream>>>(wg, Wbuf);
    gemm256<1><<<dim3(256, 1), 512, LDSZ, stream>>>(y_bf, HIDN, Wbuf, HIDN, HIDN, 32, FFDIM,
                                                    nullptr, nullptr, nullptr, g_bf, nullptr);
    conv_f32_bf16<<<CONV_FF, 256, 0, stream>>>(wu, Wbuf);
    gemm256<3><<<dim3(256, 1), 512, LDSZ, stream>>>(y_bf, HIDN, Wbuf, HIDN, HIDN, 32, FFDIM,
                                                    nullptr, nullptr, nullptr, g_bf, nullptr);
    conv_f32_bf16<<<CONV_FF, 256, 0, stream>>>(wd, Wbuf);
    gemm256<4><<<dim3(64, 4), 512, LDSZ, stream>>>(g_bf, FFDIM, Wbuf, FFDIM, 2048, 8, HIDN,
                                                   nullptr, nullptr, nullptr, part, nullptr);
    reduce4_add<<<4096, 256, 0, stream>>>(part, out);
}

// Round 5
// 517.825 us; speedup vs baseline: 2.3114x; 1.0764x over previous
//
#include <hip/hip_runtime.h>

#define HIDN 2048
#define NHEAD 16
#define HDIM 128
#define FFDIM 8192
#define SEQLEN 2048

typedef __attribute__((ext_vector_type(8))) __bf16 bf16x8;
typedef __attribute__((ext_vector_type(4))) float f32x4;
typedef __attribute__((ext_vector_type(4))) unsigned short u16x4;
typedef __attribute__((ext_vector_type(8))) unsigned short u16x8;

__device__ __forceinline__ unsigned short f2bfu(float f) {
    unsigned int u = __float_as_uint(f);
    unsigned int r = u + 0x7fffu + ((u >> 16) & 1u);
    return (unsigned short)(r >> 16);
}
__device__ __forceinline__ float bfu2f(unsigned short u) {
    return __uint_as_float(((unsigned int)u) << 16);
}

__device__ __forceinline__ void gload16(const void* g, void* l) {
    __builtin_amdgcn_global_load_lds(
        (const __attribute__((address_space(1))) unsigned int*)g,
        (__attribute__((address_space(3))) unsigned int*)l,
        16, 0, 0);
}

// ---------------- fp32 -> bf16 weight conversion ----------------
__global__ __launch_bounds__(256)
void conv_f32_bf16(const float* __restrict__ src, unsigned short* __restrict__ dst) {
    int i = blockIdx.x * 256 + threadIdx.x;
    float4 a = ((const float4*)src)[i * 2];
    float4 b = ((const float4*)src)[i * 2 + 1];
    u16x8 v;
    v[0] = f2bfu(a.x); v[1] = f2bfu(a.y); v[2] = f2bfu(a.z); v[3] = f2bfu(a.w);
    v[4] = f2bfu(b.x); v[5] = f2bfu(b.y); v[6] = f2bfu(b.z); v[7] = f2bfu(b.w);
    *(u16x8*)(dst + (size_t)i * 8) = v;
}

// ---------------- LayerNorm (fp32 in) -> bf16 out ----------------
__global__ __launch_bounds__(256)
void ln_bf16(const float* __restrict__ x, const float* __restrict__ w,
             const float* __restrict__ b, unsigned short* __restrict__ out) {
    const int row = blockIdx.x;
    const int tid = threadIdx.x;
    const float* xr = x + (size_t)row * HIDN;
    float4 v0 = ((const float4*)xr)[tid];
    float4 v1 = ((const float4*)xr)[tid + 256];
    float s = v0.x + v0.y + v0.z + v0.w + v1.x + v1.y + v1.z + v1.w;
    float q = v0.x*v0.x + v0.y*v0.y + v0.z*v0.z + v0.w*v0.w
            + v1.x*v1.x + v1.y*v1.y + v1.z*v1.z + v1.w*v1.w;
    for (int o = 32; o > 0; o >>= 1) {
        s += __shfl_down(s, o, 64);
        q += __shfl_down(q, o, 64);
    }
    __shared__ float red[8];
    const int wid = tid >> 6;
    if ((tid & 63) == 0) { red[wid] = s; red[4 + wid] = q; }
    __syncthreads();
    float st = red[0] + red[1] + red[2] + red[3];
    float qt = red[4] + red[5] + red[6] + red[7];
    float mu = st * (1.0f / HIDN);
    float var = qt * (1.0f / HIDN) - mu * mu;
    float rs = rsqrtf(var + 1e-5f);
    unsigned short* orow = out + (size_t)row * HIDN;
    int i0 = tid * 4, i1 = (tid + 256) * 4;
    orow[i0 + 0] = f2bfu((v0.x - mu) * rs * w[i0 + 0] + b[i0 + 0]);
    orow[i0 + 1] = f2bfu((v0.y - mu) * rs * w[i0 + 1] + b[i0 + 1]);
    orow[i0 + 2] = f2bfu((v0.z - mu) * rs * w[i0 + 2] + b[i0 + 2]);
    orow[i0 + 3] = f2bfu((v0.w - mu) * rs * w[i0 + 3] + b[i0 + 3]);
    orow[i1 + 0] = f2bfu((v1.x - mu) * rs * w[i1 + 0] + b[i1 + 0]);
    orow[i1 + 1] = f2bfu((v1.y - mu) * rs * w[i1 + 1] + b[i1 + 1]);
    orow[i1 + 2] = f2bfu((v1.z - mu) * rs * w[i1 + 2] + b[i1 + 2]);
    orow[i1 + 3] = f2bfu((v1.w - mu) * rs * w[i1 + 3] + b[i1 + 3]);
}

// ---------------- RoPE in-place on qk buffer [S][4096] ----------------
__global__ __launch_bounds__(256)
void rope_kernel(unsigned short* __restrict__ qk, const int* __restrict__ tsl) {
    int id = blockIdx.x * 256 + threadIdx.x;
    int p  = id & 63;
    int hh = (id >> 6) & 31;
    int s  = id >> 11;
    int off = tsl[0] - SEQLEN;
    float inv = exp2f((float)p * -0.20762050593f);
    float ang = (float)(s + off) * inv;
    float c, sn;
    __sincosf(ang, &sn, &c);
    size_t base = (size_t)s * 4096 + hh * 128 + p;
    float x1 = bfu2f(qk[base]);
    float x2 = bfu2f(qk[base + 64]);
    qk[base]      = f2bfu(x1 * c - x2 * sn);
    qk[base + 64] = f2bfu(x2 * c + x1 * sn);
}

// ================= 256x256 8-phase GEMM: C = A(bf16) * B^T(bf16) =================
#define BAR __builtin_amdgcn_s_barrier()
#define VM4 asm volatile("s_waitcnt vmcnt(4)" ::: "memory")
#define VM0 asm volatile("s_waitcnt vmcnt(0)" ::: "memory")

#define STAGE_A(tile, h) { const int k0_ = k_start + (tile) * 64;                      \
  _Pragma("unroll") for (int i_ = 0; i_ < 2; ++i_) {                                   \
    int d_ = (h) * 16384 + i_ * 8192 + tid * 16;                                       \
    int r_ = d_ >> 7;                                                                  \
    int cb_ = (d_ & 127) ^ ((r_ & 7) << 4);                                            \
    gload16((const char*)Ab + ((size_t)(brow + r_) * lda + k0_) * 2 + cb_,             \
            smem + ((tile) & 1) * 65536 + (h) * 16384 + i_ * 8192 + w * 1024); } }

#define STAGE_B(tile, h) { const int k0_ = k_start + (tile) * 64;                      \
  _Pragma("unroll") for (int i_ = 0; i_ < 2; ++i_) {                                   \
    int d_ = (h) * 16384 + i_ * 8192 + tid * 16;                                       \
    int r_ = d_ >> 7;                                                                  \
    int cb_ = (d_ & 127) ^ ((r_ & 7) << 4);                                            \
    gload16((const char*)Bb + ((size_t)(bcol + r_) * ldb + k0_) * 2 + cb_,             \
            smem + ((tile) & 1) * 65536 + 32768 + (h) * 16384 + i_ * 8192 + w * 1024); } }

#define LDB(BO)                                                                        \
  _Pragma("unroll") for (int n_ = 0; n_ < 4; ++n_)                                     \
  _Pragma("unroll") for (int kk_ = 0; kk_ < 2; ++kk_)                                  \
    bF[n_][kk_] = *(const bf16x8*)(smem + (BO) + bbase + n_ * 2048 + colb[kk_]);

#define LDA2(BO, MP)                                                                   \
  _Pragma("unroll") for (int dm_ = 0; dm_ < 2; ++dm_)                                  \
  _Pragma("unroll") for (int kk_ = 0; kk_ < 2; ++kk_)                                  \
    aF[dm_][kk_] = *(const bf16x8*)(smem + (BO) + abase + ((MP) * 2 + dm_) * 2048 + colb[kk_]);

#define MM(MP)                                                                         \
  __builtin_amdgcn_s_setprio(1);                                                       \
  _Pragma("unroll") for (int dm_ = 0; dm_ < 2; ++dm_)                                  \
  _Pragma("unroll") for (int n_ = 0; n_ < 4; ++n_)                                     \
  _Pragma("unroll") for (int kk_ = 0; kk_ < 2; ++kk_)                                  \
    acc[(MP) * 2 + dm_][n_] = __builtin_amdgcn_mfma_f32_16x16x32_bf16(                 \
        aF[dm_][kk_], bF[n_][kk_], acc[(MP) * 2 + dm_][n_], 0, 0, 0);                  \
  __builtin_amdgcn_s_setprio(0);

template<int EPI>
__global__ __launch_bounds__(512, 1)
void gemm256(const unsigned short* __restrict__ Ab, int lda,
             const unsigned short* __restrict__ Bb, int ldb,
             int k_len, int nbx, int ldc,
             const float* __restrict__ bias0, const float* __restrict__ bias1,
             const float* __restrict__ bias2,
             unsigned short* __restrict__ outB, unsigned short* __restrict__ outV) {
    extern __shared__ char smem[];   // 131072 bytes
    const int tid = threadIdx.x;
    const int w = tid >> 6, lane = tid & 63;
    const int lr = lane & 15, lg = lane >> 4;
    const int wrow = (w >> 2) * 128;
    const int wc = w & 3;

    const int nwg = gridDim.x;
    const int wg = blockIdx.x;
    const int swz = (wg & 7) * (nwg >> 3) + (wg >> 3);
    const int bx = swz % nbx, by = swz / nbx;
    const int brow = by * 256, bcol = bx * 256;
    const int k_start = blockIdx.y * k_len;

    const int xorv = (lr & 7) << 4;
    int colb[2];
    colb[0] = (lg * 16) ^ xorv;
    colb[1] = (64 + lg * 16) ^ xorv;
    const int abase = (wrow + lr) * 128;
    const int bbase = 32768 + (wc * 64 + lr) * 128;

    f32x4 acc[8][4];
#pragma unroll
    for (int m = 0; m < 8; ++m)
#pragma unroll
        for (int n = 0; n < 4; ++n) acc[m][n] = (f32x4){0.f, 0.f, 0.f, 0.f};

    bf16x8 bF[4][2], aF[2][2];

    const int NT = k_len >> 6;
    const int NIT = NT >> 1;

    STAGE_A(0, 0); STAGE_A(0, 1); STAGE_B(0, 0); STAGE_B(0, 1);
    STAGE_B(1, 0); STAGE_B(1, 1);
    VM4; BAR;

    for (int it = 0; it < NIT; ++it) {
        const int T = 2 * it;
        const bool s2 = (T + 2) < NT, s3 = (T + 3) < NT;
        LDB(0); LDA2(0, 0); STAGE_A(T + 1, 0); MM(0); BAR;
        LDA2(0, 1); STAGE_A(T + 1, 1); MM(1); BAR;
        LDA2(0, 2); if (s2) STAGE_B(T + 2, 0); MM(2); BAR;
        LDA2(0, 3); if (s2) STAGE_B(T + 2, 1); MM(3);
        if (s2) { VM4; } else { VM0; }
        BAR;
        LDB(65536); LDA2(65536, 0); if (s2) STAGE_A(T + 2, 0); MM(0); BAR;
        LDA2(65536, 1); if (s2) STAGE_A(T + 2, 1); MM(1); BAR;
        LDA2(65536, 2); if (s3) STAGE_B(T + 3, 0); MM(2); BAR;
        LDA2(65536, 3); if (s3) STAGE_B(T + 3, 1); MM(3);
        if (s3) { VM4; } else { VM0; }
        BAR;
    }

#pragma unroll
    for (int n = 0; n < 4; ++n) {
        const int col = bcol + wc * 64 + n * 16 + lr;
        float bv = 0.f;
        if (EPI == 0)
            bv = (col < 2048) ? bias0[col] : (col < 4096) ? bias1[col - 2048] : bias2[col - 4096];
#pragma unroll
        for (int m = 0; m < 8; ++m) {
#pragma unroll
            for (int j = 0; j < 4; ++j) {
                const int row = brow + wrow + m * 16 + lg * 4 + j;
                float v = acc[m][n][j] + bv;
                if (EPI == 0) {
                    if (col < 4096) outB[(size_t)row * 4096 + col] = f2bfu(v);
                    else            outV[(size_t)(col - 4096) * SEQLEN + row] = f2bfu(v);
                } else if (EPI == 1) {
                    outB[(size_t)row * ldc + col] = f2bfu(v);
                } else if (EPI == 3) {
                    size_t idx = (size_t)row * ldc + col;
                    float g = bfu2f(outB[idx]);
                    float sg = g / (1.0f + expf(-g));
                    outB[idx] = f2bfu(sg * v);
                } else {
                    outB[(size_t)blockIdx.y * 4194304 + (size_t)row * 2048 + col] = f2bfu(v);
                }
            }
        }
    }
}

// ---------------- split-K reduce: out += sum of 4 bf16 partials ----------------
__global__ __launch_bounds__(256)
void reduce4_add(const unsigned short* __restrict__ part, float* __restrict__ out) {
    int i = blockIdx.x * 256 + threadIdx.x;
    float4 o = ((const float4*)out)[i];
#pragma unroll
    for (int sk = 0; sk < 4; ++sk) {
        u16x4 p = ((const u16x4*)(part + (size_t)sk * 4194304))[i];
        o.x += bfu2f(p[0]); o.y += bfu2f(p[1]); o.z += bfu2f(p[2]); o.w += bfu2f(p[3]);
    }
    ((float4*)out)[i] = o;
}

// ---------------- WO reduce: out = hidden + bias + sum of 4 partials ----------------
__global__ __launch_bounds__(256)
void reduce4_wo(const unsigned short* __restrict__ part, const float* __restrict__ h,
                const float* __restrict__ bias, float* __restrict__ out) {
    int i = blockIdx.x * 256 + threadIdx.x;
    float4 o = ((const float4*)h)[i];
    int col = (i & 511) * 4;
    o.x += bias[col]; o.y += bias[col + 1]; o.z += bias[col + 2]; o.w += bias[col + 3];
#pragma unroll
    for (int sk = 0; sk < 4; ++sk) {
        u16x4 p = ((const u16x4*)(part + (size_t)sk * 4194304))[i];
        o.x += bfu2f(p[0]); o.y += bfu2f(p[1]); o.z += bfu2f(p[2]); o.w += bfu2f(p[3]);
    }
    ((float4*)out)[i] = o;
}

// ---------------- Flash attention: 4 waves/block, QBLK=64, KVBLK=64, defer-max ----------------
#define PST 72
__global__ __launch_bounds__(256)
void attn_kernel(const unsigned short* __restrict__ QK, const unsigned short* __restrict__ VT,
                 unsigned short* __restrict__ O) {
    __shared__ __align__(16) unsigned short Ks[2][64 * 128];   // swz ^((row&7)<<4)
    __shared__ __align__(16) unsigned short Vs[2][128 * 64];   // swz ^((d&7)<<4)
    __shared__ __align__(16) unsigned short Ps[4][16 * PST];
    const int tid = threadIdx.x;
    const int lane = tid & 63;
    const int w = tid >> 6;
    const int lr = lane & 15, lg = lane >> 4;

    const int id = blockIdx.x;
    const int pair = id & 7;
    const int j0 = id >> 3;
    const int h = pair * 2 + (j0 & 1);
    const int qb = 31 - (j0 >> 1);
    const int q0 = qb * 64;
    const int qw = q0 + w * 16;

    const unsigned short* Qb = QK + (size_t)qw * 4096 + h * 128;
    const unsigned short* Kb = QK + 2048 + h * 128;
    const unsigned short* Vb = VT + (size_t)(h * 128) * SEQLEN;

    bf16x8 qa[4];
#pragma unroll
    for (int c = 0; c < 4; ++c)
        qa[c] = *(const bf16x8*)(Qb + (size_t)lr * 4096 + c * 32 + lg * 8);

    // staging geometry: 4 chunks of 4KB each for K and V tiles (16KB each)
    int krow[4], kcb[4], vrow[4], vcb[4];
#pragma unroll
    for (int ch = 0; ch < 4; ++ch) {
        int d = ch * 4096 + w * 1024 + lane * 16;
        krow[ch] = d >> 8;
        kcb[ch]  = (d & 255) ^ ((krow[ch] & 7) << 4);
        vrow[ch] = d >> 7;
        vcb[ch]  = (d & 127) ^ ((vrow[ch] & 7) << 4);
    }

    f32x4 acc[8];
#pragma unroll
    for (int dt = 0; dt < 8; ++dt) acc[dt] = (f32x4){0.f, 0.f, 0.f, 0.f};
    float mrow[4] = {-INFINITY, -INFINITY, -INFINITY, -INFINITY};
    float lrow[4] = {0.f, 0.f, 0.f, 0.f};

    const float sc = 0.08838834764831845f;
    const int ntile = qb + 1;

    // prologue: stage tile 0 into buffer 0
#pragma unroll
    for (int ch = 0; ch < 4; ++ch) {
        gload16(Kb + (size_t)krow[ch] * 4096 + (kcb[ch] >> 1),
                (char*)&Ks[0][0] + ch * 4096 + w * 1024);
        gload16(Vb + (size_t)vrow[ch] * SEQLEN + (vcb[ch] >> 1),
                (char*)&Vs[0][0] + ch * 4096 + w * 1024);
    }
    __syncthreads();

    for (int tt = 0; tt < ntile; ++tt) {
        const int cur = tt & 1;
        const int t0 = tt * 64;
        if (tt + 1 < ntile) {
            const int t1 = t0 + 64;
#pragma unroll
            for (int ch = 0; ch < 4; ++ch) {
                gload16(Kb + (size_t)(t1 + krow[ch]) * 4096 + (kcb[ch] >> 1),
                        (char*)&Ks[cur ^ 1][0] + ch * 4096 + w * 1024);
                gload16(Vb + (size_t)vrow[ch] * SEQLEN + t1 + (vcb[ch] >> 1),
                        (char*)&Vs[cur ^ 1][0] + ch * 4096 + w * 1024);
            }
        }
        // QK^T : 16 q-rows x 64 kv
        f32x4 s[4];
#pragma unroll
        for (int th = 0; th < 4; ++th) s[th] = (f32x4){0.f, 0.f, 0.f, 0.f};
        __builtin_amdgcn_s_setprio(1);
#pragma unroll
        for (int th = 0; th < 4; ++th) {
            const int row = th * 16 + lr;
#pragma unroll
            for (int c = 0; c < 4; ++c) {
                bf16x8 kb = *(const bf16x8*)((char*)&Ks[cur][0] + row * 256 +
                                             ((c * 64 + lg * 16) ^ ((lr & 7) << 4)));
                s[th] = __builtin_amdgcn_mfma_f32_16x16x32_bf16(qa[c], kb, s[th], 0, 0, 0);
            }
        }
        __builtin_amdgcn_s_setprio(0);
        // scale + causal mask
#pragma unroll
        for (int th = 0; th < 4; ++th) {
            int tg = t0 + th * 16 + lr;
#pragma unroll
            for (int jj = 0; jj < 4; ++jj) {
                int qg = qw + lg * 4 + jj;
                s[th][jj] = s[th][jj] * sc + (tg <= qg ? 0.f : -1e9f);
            }
        }
        // row max over 64 kv
        float mt[4];
#pragma unroll
        for (int jj = 0; jj < 4; ++jj)
            mt[jj] = fmaxf(fmaxf(s[0][jj], s[1][jj]), fmaxf(s[2][jj], s[3][jj]));
#pragma unroll
        for (int o = 8; o > 0; o >>= 1)
#pragma unroll
            for (int jj = 0; jj < 4; ++jj) mt[jj] = fmaxf(mt[jj], __shfl_xor(mt[jj], o, 16));
        // defer-max: only rescale when max grows past threshold
        bool need = false;
#pragma unroll
        for (int jj = 0; jj < 4; ++jj) need = need || (mt[jj] > mrow[jj] + 4.0f);
        if (__any(need)) {
#pragma unroll
            for (int jj = 0; jj < 4; ++jj) {
                float mn = fmaxf(mrow[jj], mt[jj]);
                float a = __expf(mrow[jj] - mn);
                mrow[jj] = mn;
                lrow[jj] *= a;
#pragma unroll
                for (int dt = 0; dt < 8; ++dt) acc[dt][jj] *= a;
            }
        }
        // p = exp(s - m), row sum
        float ps[4] = {0.f, 0.f, 0.f, 0.f};
#pragma unroll
        for (int th = 0; th < 4; ++th)
#pragma unroll
            for (int jj = 0; jj < 4; ++jj) {
                float p = __expf(s[th][jj] - mrow[jj]);
                s[th][jj] = p;
                ps[jj] += p;
            }
#pragma unroll
        for (int o = 8; o > 0; o >>= 1)
#pragma unroll
            for (int jj = 0; jj < 4; ++jj) ps[jj] += __shfl_xor(ps[jj], o, 16);
#pragma unroll
        for (int jj = 0; jj < 4; ++jj) lrow[jj] += ps[jj];
        // P tile to per-wave LDS slice [16 q][64 t]
#pragma unroll
        for (int th = 0; th < 4; ++th)
#pragma unroll
            for (int jj = 0; jj < 4; ++jj)
                Ps[w][(lg * 4 + jj) * PST + th * 16 + lr] = f2bfu(s[th][jj]);
        // PV
        bf16x8 pa[2];
#pragma unroll
        for (int ks = 0; ks < 2; ++ks)
            pa[ks] = *(const bf16x8*)&Ps[w][lr * PST + ks * 32 + lg * 8];
        __builtin_amdgcn_s_setprio(1);
#pragma unroll
        for (int dt = 0; dt < 8; ++dt) {
            const int d = dt * 16 + lr;
#pragma unroll
            for (int ks = 0; ks < 2; ++ks) {
                bf16x8 vb = *(const bf16x8*)((char*)&Vs[cur][0] + d * 128 +
                                             ((ks * 64 + lg * 16) ^ ((lr & 7) << 4)));
                acc[dt] = __builtin_amdgcn_mfma_f32_16x16x32_bf16(pa[ks], vb, acc[dt], 0, 0, 0);
            }
        }
        __builtin_amdgcn_s_setprio(0);
        __syncthreads();
    }
    float invl[4];
#pragma unroll
    for (int jj = 0; jj < 4; ++jj) invl[jj] = 1.0f / lrow[jj];
#pragma unroll
    for (int dt = 0; dt < 8; ++dt)
#pragma unroll
        for (int jj = 0; jj < 4; ++jj)
            O[(size_t)(qw + lg * 4 + jj) * HIDN + h * HDIM + dt * 16 + lr] = f2bfu(acc[dt][jj] * invl[jj]);
}

extern "C" void kernel_launch(void* const* d_in, const int* in_sizes, int n_in,
                              void* d_out, int out_size, void* d_ws, size_t ws_size,
                              hipStream_t stream) {
    const float* hidden = (const float*)d_in[0];
    const float* ln1w = (const float*)d_in[2];
    const float* ln1b = (const float*)d_in[3];
    const float* ln2w = (const float*)d_in[4];
    const float* ln2b = (const float*)d_in[5];
    const float* wq = (const float*)d_in[6];
    const float* bq = (const float*)d_in[7];
    const float* wk = (const float*)d_in[8];
    const float* bk = (const float*)d_in[9];
    const float* wv = (const float*)d_in[10];
    const float* bv = (const float*)d_in[11];
    const float* wo = (const float*)d_in[12];
    const float* bo = (const float*)d_in[13];
    const float* wg = (const float*)d_in[14];
    const float* wu = (const float*)d_in[15];
    const float* wd = (const float*)d_in[16];
    const int* tsl = (const int*)d_in[17];
    float* out = (float*)d_out;

    char* ws = (char*)d_ws;
    const size_t MB = 1024 * 1024;
    unsigned short* Wbuf = (unsigned short*)(ws);            // 32 MiB weight staging
    unsigned short* qk   = (unsigned short*)(ws + 32 * MB);  // 16 MiB [2048][4096]
    unsigned short* vt   = (unsigned short*)(ws + 48 * MB);  // 8 MiB [2048 d][2048 t]
    unsigned short* x_bf = (unsigned short*)(ws + 56 * MB);  // 8 MiB; attn out reuses
    unsigned short* g_bf = (unsigned short*)(ws + 64 * MB);  // 32 MiB; WO partials reuse
    unsigned short* part = qk;                               // 32 MiB (qk..x_bf) for down partials
    unsigned short* y_bf = vt;                               // ln2 out reuses vt

    const int HID2 = HIDN * HIDN;
    const int CONV_HID = HID2 / 8 / 256;
    const int CONV_FF  = FFDIM * HIDN / 8 / 256;
    const size_t LDSZ = 131072;

    // ---- QKV ----
    conv_f32_bf16<<<CONV_HID, 256, 0, stream>>>(wq, Wbuf);
    conv_f32_bf16<<<CONV_HID, 256, 0, stream>>>(wk, Wbuf + HID2);
    conv_f32_bf16<<<CONV_HID, 256, 0, stream>>>(wv, Wbuf + 2 * (size_t)HID2);
    ln_bf16<<<SEQLEN, 256, 0, stream>>>(hidden, ln1w, ln1b, x_bf);
    gemm256<0><<<dim3(192, 1), 512, LDSZ, stream>>>(x_bf, HIDN, Wbuf, HIDN, HIDN, 24, 0,
                                                    bq, bk, bv, qk, vt);
    rope_kernel<<<SEQLEN * 32 * 64 / 256, 256, 0, stream>>>(qk, tsl);
    attn_kernel<<<512, 256, 0, stream>>>(qk, vt, x_bf);

    // ---- WO + residual (split-K=4, partials in g_bf) ----
    conv_f32_bf16<<<CONV_HID, 256, 0, stream>>>(wo, Wbuf);
    gemm256<4><<<dim3(64, 4), 512, LDSZ, stream>>>(x_bf, HIDN, Wbuf, HIDN, 512, 8, HIDN,
                                                   nullptr, nullptr, nullptr, g_bf, nullptr);
    reduce4_wo<<<4096, 256, 0, stream>>>(g_bf, hidden, bo, out);

    // ---- FFN ----
    ln_bf16<<<SEQLEN, 256, 0, stream>>>(out, ln2w, ln2b, y_bf);
    conv_f32_bf16<<<CONV_FF, 256, 0, stream>>>(wg, Wbuf);
    gemm256<1><<<dim3(256, 1), 512, LDSZ, stream>>>(y_bf, HIDN, Wbuf, HIDN, HIDN, 32, FFDIM,
                                                    nullptr, nullptr, nullptr, g_bf, nullptr);
    conv_f32_bf16<<<CONV_FF, 256, 0, stream>>>(wu, Wbuf);
    gemm256<3><<<dim3(256, 1), 512, LDSZ, stream>>>(y_bf, HIDN, Wbuf, HIDN, HIDN, 32, FFDIM,
                                                    nullptr, nullptr, nullptr, g_bf, nullptr);
    conv_f32_bf16<<<CONV_FF, 256, 0, stream>>>(wd, Wbuf);
    gemm256<4><<<dim3(64, 4), 512, LDSZ, stream>>>(g_bf, FFDIM, Wbuf, FFDIM, 2048, 8, HIDN,
                                                   nullptr, nullptr, nullptr, part, nullptr);
    reduce4_add<<<4096, 256, 0, stream>>>(part, out);
}

// Round 6
// 450.661 us; speedup vs baseline: 2.6559x; 1.1490x over previous
//
#include <hip/hip_runtime.h>

#define HIDN 2048
#define NHEAD 16
#define HDIM 128
#define FFDIM 8192
#define SEQLEN 2048

typedef __attribute__((ext_vector_type(8))) __bf16 bf16x8;
typedef __attribute__((ext_vector_type(4))) float f32x4;
typedef __attribute__((ext_vector_type(4))) unsigned short u16x4;
typedef __attribute__((ext_vector_type(8))) unsigned short u16x8;

__device__ __forceinline__ unsigned short f2bfu(float f) {
    unsigned int u = __float_as_uint(f);
    unsigned int r = u + 0x7fffu + ((u >> 16) & 1u);
    return (unsigned short)(r >> 16);
}
__device__ __forceinline__ float bfu2f(unsigned short u) {
    return __uint_as_float(((unsigned int)u) << 16);
}

__device__ __forceinline__ void gload16(const void* g, void* l) {
    __builtin_amdgcn_global_load_lds(
        (const __attribute__((address_space(1))) unsigned int*)g,
        (__attribute__((address_space(3))) unsigned int*)l,
        16, 0, 0);
}

// ---------------- fp32 -> bf16 weight conversion ----------------
__global__ __launch_bounds__(256)
void conv_f32_bf16(const float* __restrict__ src, unsigned short* __restrict__ dst) {
    int i = blockIdx.x * 256 + threadIdx.x;
    float4 a = ((const float4*)src)[i * 2];
    float4 b = ((const float4*)src)[i * 2 + 1];
    u16x8 v;
    v[0] = f2bfu(a.x); v[1] = f2bfu(a.y); v[2] = f2bfu(a.z); v[3] = f2bfu(a.w);
    v[4] = f2bfu(b.x); v[5] = f2bfu(b.y); v[6] = f2bfu(b.z); v[7] = f2bfu(b.w);
    *(u16x8*)(dst + (size_t)i * 8) = v;
}

// 3 HIDNxHIDN matrices in one launch (each 1<<19 x8 elems)
__global__ __launch_bounds__(256)
void conv3_f32_bf16(const float* __restrict__ s0, const float* __restrict__ s1,
                    const float* __restrict__ s2, unsigned short* __restrict__ dst) {
    int i = blockIdx.x * 256 + threadIdx.x;
    int m = i >> 19;
    int li = i & ((1 << 19) - 1);
    const float* s = (m == 0) ? s0 : (m == 1) ? s1 : s2;
    float4 a = ((const float4*)s)[li * 2];
    float4 b = ((const float4*)s)[li * 2 + 1];
    u16x8 v;
    v[0] = f2bfu(a.x); v[1] = f2bfu(a.y); v[2] = f2bfu(a.z); v[3] = f2bfu(a.w);
    v[4] = f2bfu(b.x); v[5] = f2bfu(b.y); v[6] = f2bfu(b.z); v[7] = f2bfu(b.w);
    *(u16x8*)(dst + (size_t)i * 8) = v;
}

// ---------------- LayerNorm (fp32 in) -> bf16 out ----------------
__global__ __launch_bounds__(256)
void ln_bf16(const float* __restrict__ x, const float* __restrict__ w,
             const float* __restrict__ b, unsigned short* __restrict__ out) {
    const int row = blockIdx.x;
    const int tid = threadIdx.x;
    const float* xr = x + (size_t)row * HIDN;
    float4 v0 = ((const float4*)xr)[tid];
    float4 v1 = ((const float4*)xr)[tid + 256];
    float s = v0.x + v0.y + v0.z + v0.w + v1.x + v1.y + v1.z + v1.w;
    float q = v0.x*v0.x + v0.y*v0.y + v0.z*v0.z + v0.w*v0.w
            + v1.x*v1.x + v1.y*v1.y + v1.z*v1.z + v1.w*v1.w;
    for (int o = 32; o > 0; o >>= 1) {
        s += __shfl_down(s, o, 64);
        q += __shfl_down(q, o, 64);
    }
    __shared__ float red[8];
    const int wid = tid >> 6;
    if ((tid & 63) == 0) { red[wid] = s; red[4 + wid] = q; }
    __syncthreads();
    float st = red[0] + red[1] + red[2] + red[3];
    float qt = red[4] + red[5] + red[6] + red[7];
    float mu = st * (1.0f / HIDN);
    float var = qt * (1.0f / HIDN) - mu * mu;
    float rs = rsqrtf(var + 1e-5f);
    unsigned short* orow = out + (size_t)row * HIDN;
    int i0 = tid * 4, i1 = (tid + 256) * 4;
    orow[i0 + 0] = f2bfu((v0.x - mu) * rs * w[i0 + 0] + b[i0 + 0]);
    orow[i0 + 1] = f2bfu((v0.y - mu) * rs * w[i0 + 1] + b[i0 + 1]);
    orow[i0 + 2] = f2bfu((v0.z - mu) * rs * w[i0 + 2] + b[i0 + 2]);
    orow[i0 + 3] = f2bfu((v0.w - mu) * rs * w[i0 + 3] + b[i0 + 3]);
    orow[i1 + 0] = f2bfu((v1.x - mu) * rs * w[i1 + 0] + b[i1 + 0]);
    orow[i1 + 1] = f2bfu((v1.y - mu) * rs * w[i1 + 1] + b[i1 + 1]);
    orow[i1 + 2] = f2bfu((v1.z - mu) * rs * w[i1 + 2] + b[i1 + 2]);
    orow[i1 + 3] = f2bfu((v1.w - mu) * rs * w[i1 + 3] + b[i1 + 3]);
}

// ---------------- RoPE in-place on qk buffer [S][4096] ----------------
__global__ __launch_bounds__(256)
void rope_kernel(unsigned short* __restrict__ qk, const int* __restrict__ tsl) {
    int id = blockIdx.x * 256 + threadIdx.x;
    int p  = id & 63;
    int hh = (id >> 6) & 31;
    int s  = id >> 11;
    int off = tsl[0] - SEQLEN;
    float inv = exp2f((float)p * -0.20762050593f);
    float ang = (float)(s + off) * inv;
    float c, sn;
    __sincosf(ang, &sn, &c);
    size_t base = (size_t)s * 4096 + hh * 128 + p;
    float x1 = bfu2f(qk[base]);
    float x2 = bfu2f(qk[base + 64]);
    qk[base]      = f2bfu(x1 * c - x2 * sn);
    qk[base + 64] = f2bfu(x2 * c + x1 * sn);
}

// ================= 256x256 8-phase GEMM: C = A(bf16) * B^T(bf16) =================
// EPI 0 (QKV):  col<4096 -> qk[row*4096+col]+bias; else vt[(col-4096)*SEQ+row]+bv
// EPI 1 (BF):   outB[row*ldc+col] = bf16(acc)
// EPI 3 (SILU): outB[row*ldc+col] = bf16(silu(prev)*acc) in-place
// EPI 4 (PART): outB[ky*2048*2048 + row*ldc+col] = bf16(acc)   (split-K partial)
#define BAR __builtin_amdgcn_s_barrier()
#define VM4 asm volatile("s_waitcnt vmcnt(4)" ::: "memory")
#define VM0 asm volatile("s_waitcnt vmcnt(0)" ::: "memory")

#define STAGE_A(tile, h) { const int k0_ = k_start + (tile) * 64;                      \
  _Pragma("unroll") for (int i_ = 0; i_ < 2; ++i_) {                                   \
    int d_ = (h) * 16384 + i_ * 8192 + tid * 16;                                       \
    int r_ = d_ >> 7;                                                                  \
    int cb_ = (d_ & 127) ^ ((r_ & 7) << 4);                                            \
    gload16((const char*)Ab + ((size_t)(brow + r_) * lda + k0_) * 2 + cb_,             \
            smem + ((tile) & 1) * 65536 + (h) * 16384 + i_ * 8192 + w * 1024); } }

#define STAGE_B(tile, h) { const int k0_ = k_start + (tile) * 64;                      \
  _Pragma("unroll") for (int i_ = 0; i_ < 2; ++i_) {                                   \
    int d_ = (h) * 16384 + i_ * 8192 + tid * 16;                                       \
    int r_ = d_ >> 7;                                                                  \
    int cb_ = (d_ & 127) ^ ((r_ & 7) << 4);                                            \
    gload16((const char*)Bb + ((size_t)(bcol + r_) * ldb + k0_) * 2 + cb_,             \
            smem + ((tile) & 1) * 65536 + 32768 + (h) * 16384 + i_ * 8192 + w * 1024); } }

#define LDB(BO)                                                                        \
  _Pragma("unroll") for (int n_ = 0; n_ < 4; ++n_)                                     \
  _Pragma("unroll") for (int kk_ = 0; kk_ < 2; ++kk_)                                  \
    bF[n_][kk_] = *(const bf16x8*)(smem + (BO) + bbase + n_ * 2048 + colb[kk_]);

#define LDA2(BO, MP)                                                                   \
  _Pragma("unroll") for (int dm_ = 0; dm_ < 2; ++dm_)                                  \
  _Pragma("unroll") for (int kk_ = 0; kk_ < 2; ++kk_)                                  \
    aF[dm_][kk_] = *(const bf16x8*)(smem + (BO) + abase + ((MP) * 2 + dm_) * 2048 + colb[kk_]);

#define MM(MP)                                                                         \
  __builtin_amdgcn_s_setprio(1);                                                       \
  _Pragma("unroll") for (int dm_ = 0; dm_ < 2; ++dm_)                                  \
  _Pragma("unroll") for (int n_ = 0; n_ < 4; ++n_)                                     \
  _Pragma("unroll") for (int kk_ = 0; kk_ < 2; ++kk_)                                  \
    acc[(MP) * 2 + dm_][n_] = __builtin_amdgcn_mfma_f32_16x16x32_bf16(                 \
        aF[dm_][kk_], bF[n_][kk_], acc[(MP) * 2 + dm_][n_], 0, 0, 0);                  \
  __builtin_amdgcn_s_setprio(0);

template<int EPI>
__global__ __launch_bounds__(512, 1)
void gemm256(const unsigned short* __restrict__ Ab, int lda,
             const unsigned short* __restrict__ Bb, int ldb,
             int k_len, int nbx, int ldc,
             const float* __restrict__ bias0, const float* __restrict__ bias1,
             const float* __restrict__ bias2,
             unsigned short* __restrict__ outB, unsigned short* __restrict__ outV) {
    extern __shared__ char smem[];   // 131072 bytes
    const int tid = threadIdx.x;
    const int w = tid >> 6, lane = tid & 63;
    const int lr = lane & 15, lg = lane >> 4;
    const int wrow = (w >> 2) * 128;
    const int wc = w & 3;

    // XCD column-stripe chunking: per-XCD B footprint = (nbx/8)*256 N-rows (L2-resident)
    const int cpx = nbx >> 3;
    const int xcd = blockIdx.x & 7;
    const int loc = blockIdx.x >> 3;
    const int bx = xcd * cpx + loc % cpx;
    const int by = loc / cpx;
    const int brow = by * 256, bcol = bx * 256;
    const int k_start = blockIdx.y * k_len;

    const int xorv = (lr & 7) << 4;
    int colb[2];
    colb[0] = (lg * 16) ^ xorv;
    colb[1] = (64 + lg * 16) ^ xorv;
    const int abase = (wrow + lr) * 128;
    const int bbase = 32768 + (wc * 64 + lr) * 128;

    f32x4 acc[8][4];
#pragma unroll
    for (int m = 0; m < 8; ++m)
#pragma unroll
        for (int n = 0; n < 4; ++n) acc[m][n] = (f32x4){0.f, 0.f, 0.f, 0.f};

    bf16x8 bF[4][2], aF[2][2];

    const int NT = k_len >> 6;
    const int NIT = NT >> 1;

    STAGE_A(0, 0); STAGE_A(0, 1); STAGE_B(0, 0); STAGE_B(0, 1);
    STAGE_B(1, 0); STAGE_B(1, 1);
    VM4; BAR;

    for (int it = 0; it < NIT; ++it) {
        const int T = 2 * it;
        const bool s2 = (T + 2) < NT, s3 = (T + 3) < NT;
        LDB(0); LDA2(0, 0); STAGE_A(T + 1, 0); MM(0); BAR;
        LDA2(0, 1); STAGE_A(T + 1, 1); MM(1); BAR;
        LDA2(0, 2); if (s2) STAGE_B(T + 2, 0); MM(2); BAR;
        LDA2(0, 3); if (s2) STAGE_B(T + 2, 1); MM(3);
        if (s2) { VM4; } else { VM0; }
        BAR;
        LDB(65536); LDA2(65536, 0); if (s2) STAGE_A(T + 2, 0); MM(0); BAR;
        LDA2(65536, 1); if (s2) STAGE_A(T + 2, 1); MM(1); BAR;
        LDA2(65536, 2); if (s3) STAGE_B(T + 3, 0); MM(2); BAR;
        LDA2(65536, 3); if (s3) STAGE_B(T + 3, 1); MM(3);
        if (s3) { VM4; } else { VM0; }
        BAR;
    }

    // ======== LDS-staged epilogue (per-wave 16KB slice; all barriers passed) ========
    char* sw = smem + w * 16384;
    const bool vblk = (EPI == 0) && (bcol >= 4096);

    if (!vblk) {
        // stage row-major [128 r][64 c] bf16, byte-swizzled ^((r&7)<<4)
#pragma unroll
        for (int n = 0; n < 4; ++n) {
            const int col = bcol + wc * 64 + n * 16 + lr;
            float bv = 0.f;
            if (EPI == 0) bv = (col < 2048) ? bias0[col] : bias1[col - 2048];
#pragma unroll
            for (int m = 0; m < 8; ++m)
#pragma unroll
                for (int j = 0; j < 4; ++j) {
                    const int r = m * 16 + lg * 4 + j;
                    const int cb = ((n * 16 + lr) * 2) ^ ((r & 7) << 4);
                    *(unsigned short*)(sw + r * 128 + cb) = f2bfu(acc[m][n][j] + bv);
                }
        }
        // readback: 16 iters x (8 rows x 8 lanes x 16B)
        const int rl = lane >> 3, cl = lane & 7;
#pragma unroll
        for (int it2 = 0; it2 < 16; ++it2) {
            const int r = it2 * 8 + rl;
            const int cb = (cl * 16) ^ ((r & 7) << 4);
            u16x8 val = *(const u16x8*)(sw + r * 128 + cb);
            const int gr = brow + wrow + r;
            const int gcol = bcol + wc * 64 + cl * 8;
            if (EPI == 0) {
                *(u16x8*)(outB + (size_t)gr * 4096 + gcol) = val;
            } else if (EPI == 1) {
                *(u16x8*)(outB + (size_t)gr * ldc + gcol) = val;
            } else if (EPI == 3) {
                unsigned short* gp = outB + (size_t)gr * ldc + gcol;
                u16x8 gv = *(const u16x8*)gp;
                u16x8 ov;
#pragma unroll
                for (int e = 0; e < 8; ++e) {
                    float g = bfu2f(gv[e]);
                    float uu = bfu2f(val[e]);
                    ov[e] = f2bfu(g / (1.0f + __expf(-g)) * uu);
                }
                *(u16x8*)gp = ov;
            } else {
                *(u16x8*)(outB + (size_t)blockIdx.y * 4194304 + (size_t)gr * ldc + gcol) = val;
            }
        }
    } else {
        // V block: stage TRANSPOSED [64 c][128 r] bf16, byte-swizzled ^((c&7)<<4)
#pragma unroll
        for (int n = 0; n < 4; ++n) {
            const int c = n * 16 + lr;
            const float bv = bias2[bcol - 4096 + wc * 64 + c];
            const int cx = (c & 7) << 4;
#pragma unroll
            for (int m = 0; m < 8; ++m) {
                const int r0 = m * 16 + lg * 4;
                u16x4 pk;
#pragma unroll
                for (int j = 0; j < 4; ++j) pk[j] = f2bfu(acc[m][n][j] + bv);
                *(u16x4*)(sw + c * 256 + ((r0 * 2) ^ cx)) = pk;
            }
        }
        // readback: 16 iters x (4 cols x 16 lanes x 16B)
        const int cg = lane >> 4, rl2 = lane & 15;
#pragma unroll
        for (int it2 = 0; it2 < 16; ++it2) {
            const int c = it2 * 4 + cg;
            const int rb = (rl2 * 16) ^ ((c & 7) << 4);
            u16x8 val = *(const u16x8*)(sw + c * 256 + rb);
            const int d = bcol - 4096 + wc * 64 + c;
            *(u16x8*)(outV + (size_t)d * SEQLEN + brow + wrow + rl2 * 8) = val;
        }
    }
}

// ---------------- split-K reduce: out += sum of 4 bf16 partials ----------------
__global__ __launch_bounds__(256)
void reduce4_add(const unsigned short* __restrict__ part, float* __restrict__ out) {
    int i = blockIdx.x * 256 + threadIdx.x;
    float4 o = ((const float4*)out)[i];
#pragma unroll
    for (int sk = 0; sk < 4; ++sk) {
        u16x4 p = ((const u16x4*)(part + (size_t)sk * 4194304))[i];
        o.x += bfu2f(p[0]); o.y += bfu2f(p[1]); o.z += bfu2f(p[2]); o.w += bfu2f(p[3]);
    }
    ((float4*)out)[i] = o;
}

// ---------------- WO reduce: out = hidden + bias + sum of 4 partials ----------------
__global__ __launch_bounds__(256)
void reduce4_wo(const unsigned short* __restrict__ part, const float* __restrict__ h,
                const float* __restrict__ bias, float* __restrict__ out) {
    int i = blockIdx.x * 256 + threadIdx.x;
    float4 o = ((const float4*)h)[i];
    int col = (i & 511) * 4;
    o.x += bias[col]; o.y += bias[col + 1]; o.z += bias[col + 2]; o.w += bias[col + 3];
#pragma unroll
    for (int sk = 0; sk < 4; ++sk) {
        u16x4 p = ((const u16x4*)(part + (size_t)sk * 4194304))[i];
        o.x += bfu2f(p[0]); o.y += bfu2f(p[1]); o.z += bfu2f(p[2]); o.w += bfu2f(p[3]);
    }
    ((float4*)out)[i] = o;
}

// ---------------- Flash attention: 4 waves/block, QBLK=64, KVBLK=64, defer-max ----------------
#define PST 72
__global__ __launch_bounds__(256)
void attn_kernel(const unsigned short* __restrict__ QK, const unsigned short* __restrict__ VT,
                 unsigned short* __restrict__ O) {
    __shared__ __align__(16) unsigned short Ks[2][64 * 128];   // swz ^((row&7)<<4)
    __shared__ __align__(16) unsigned short Vs[2][128 * 64];   // swz ^((d&7)<<4)
    __shared__ __align__(16) unsigned short Ps[4][16 * PST];
    const int tid = threadIdx.x;
    const int lane = tid & 63;
    const int w = tid >> 6;
    const int lr = lane & 15, lg = lane >> 4;

    const int id = blockIdx.x;
    const int pair = id & 7;
    const int j0 = id >> 3;
    const int h = pair * 2 + (j0 & 1);
    const int qb = 31 - (j0 >> 1);
    const int q0 = qb * 64;
    const int qw = q0 + w * 16;

    const unsigned short* Qb = QK + (size_t)qw * 4096 + h * 128;
    const unsigned short* Kb = QK + 2048 + h * 128;
    const unsigned short* Vb = VT + (size_t)(h * 128) * SEQLEN;

    bf16x8 qa[4];
#pragma unroll
    for (int c = 0; c < 4; ++c)
        qa[c] = *(const bf16x8*)(Qb + (size_t)lr * 4096 + c * 32 + lg * 8);

    int krow[4], kcb[4], vrow[4], vcb[4];
#pragma unroll
    for (int ch = 0; ch < 4; ++ch) {
        int d = ch * 4096 + w * 1024 + lane * 16;
        krow[ch] = d >> 8;
        kcb[ch]  = (d & 255) ^ ((krow[ch] & 7) << 4);
        vrow[ch] = d >> 7;
        vcb[ch]  = (d & 127) ^ ((vrow[ch] & 7) << 4);
    }

    f32x4 acc[8];
#pragma unroll
    for (int dt = 0; dt < 8; ++dt) acc[dt] = (f32x4){0.f, 0.f, 0.f, 0.f};
    float mrow[4] = {-INFINITY, -INFINITY, -INFINITY, -INFINITY};
    float lrow[4] = {0.f, 0.f, 0.f, 0.f};

    const float sc = 0.08838834764831845f;
    const int ntile = qb + 1;

#pragma unroll
    for (int ch = 0; ch < 4; ++ch) {
        gload16(Kb + (size_t)krow[ch] * 4096 + (kcb[ch] >> 1),
                (char*)&Ks[0][0] + ch * 4096 + w * 1024);
        gload16(Vb + (size_t)vrow[ch] * SEQLEN + (vcb[ch] >> 1),
                (char*)&Vs[0][0] + ch * 4096 + w * 1024);
    }
    __syncthreads();

    for (int tt = 0; tt < ntile; ++tt) {
        const int cur = tt & 1;
        const int t0 = tt * 64;
        if (tt + 1 < ntile) {
            const int t1 = t0 + 64;
#pragma unroll
            for (int ch = 0; ch < 4; ++ch) {
                gload16(Kb + (size_t)(t1 + krow[ch]) * 4096 + (kcb[ch] >> 1),
                        (char*)&Ks[cur ^ 1][0] + ch * 4096 + w * 1024);
                gload16(Vb + (size_t)vrow[ch] * SEQLEN + t1 + (vcb[ch] >> 1),
                        (char*)&Vs[cur ^ 1][0] + ch * 4096 + w * 1024);
            }
        }
        f32x4 s[4];
#pragma unroll
        for (int th = 0; th < 4; ++th) s[th] = (f32x4){0.f, 0.f, 0.f, 0.f};
        __builtin_amdgcn_s_setprio(1);
#pragma unroll
        for (int th = 0; th < 4; ++th) {
            const int row = th * 16 + lr;
#pragma unroll
            for (int c = 0; c < 4; ++c) {
                bf16x8 kb = *(const bf16x8*)((char*)&Ks[cur][0] + row * 256 +
                                             ((c * 64 + lg * 16) ^ ((lr & 7) << 4)));
                s[th] = __builtin_amdgcn_mfma_f32_16x16x32_bf16(qa[c], kb, s[th], 0, 0, 0);
            }
        }
        __builtin_amdgcn_s_setprio(0);
#pragma unroll
        for (int th = 0; th < 4; ++th) {
            int tg = t0 + th * 16 + lr;
#pragma unroll
            for (int jj = 0; jj < 4; ++jj) {
                int qg = qw + lg * 4 + jj;
                s[th][jj] = s[th][jj] * sc + (tg <= qg ? 0.f : -1e9f);
            }
        }
        float mt[4];
#pragma unroll
        for (int jj = 0; jj < 4; ++jj)
            mt[jj] = fmaxf(fmaxf(s[0][jj], s[1][jj]), fmaxf(s[2][jj], s[3][jj]));
#pragma unroll
        for (int o = 8; o > 0; o >>= 1)
#pragma unroll
            for (int jj = 0; jj < 4; ++jj) mt[jj] = fmaxf(mt[jj], __shfl_xor(mt[jj], o, 16));
        bool need = false;
#pragma unroll
        for (int jj = 0; jj < 4; ++jj) need = need || (mt[jj] > mrow[jj] + 4.0f);
        if (__any(need)) {
#pragma unroll
            for (int jj = 0; jj < 4; ++jj) {
                float mn = fmaxf(mrow[jj], mt[jj]);
                float a = __expf(mrow[jj] - mn);
                mrow[jj] = mn;
                lrow[jj] *= a;
#pragma unroll
                for (int dt = 0; dt < 8; ++dt) acc[dt][jj] *= a;
            }
        }
        float ps[4] = {0.f, 0.f, 0.f, 0.f};
#pragma unroll
        for (int th = 0; th < 4; ++th)
#pragma unroll
            for (int jj = 0; jj < 4; ++jj) {
                float p = __expf(s[th][jj] - mrow[jj]);
                s[th][jj] = p;
                ps[jj] += p;
            }
#pragma unroll
        for (int o = 8; o > 0; o >>= 1)
#pragma unroll
            for (int jj = 0; jj < 4; ++jj) ps[jj] += __shfl_xor(ps[jj], o, 16);
#pragma unroll
        for (int jj = 0; jj < 4; ++jj) lrow[jj] += ps[jj];
#pragma unroll
        for (int th = 0; th < 4; ++th)
#pragma unroll
            for (int jj = 0; jj < 4; ++jj)
                Ps[w][(lg * 4 + jj) * PST + th * 16 + lr] = f2bfu(s[th][jj]);
        bf16x8 pa[2];
#pragma unroll
        for (int ks = 0; ks < 2; ++ks)
            pa[ks] = *(const bf16x8*)&Ps[w][lr * PST + ks * 32 + lg * 8];
        __builtin_amdgcn_s_setprio(1);
#pragma unroll
        for (int dt = 0; dt < 8; ++dt) {
            const int d = dt * 16 + lr;
#pragma unroll
            for (int ks = 0; ks < 2; ++ks) {
                bf16x8 vb = *(const bf16x8*)((char*)&Vs[cur][0] + d * 128 +
                                             ((ks * 64 + lg * 16) ^ ((lr & 7) << 4)));
                acc[dt] = __builtin_amdgcn_mfma_f32_16x16x32_bf16(pa[ks], vb, acc[dt], 0, 0, 0);
            }
        }
        __builtin_amdgcn_s_setprio(0);
        __syncthreads();
    }
    float invl[4];
#pragma unroll
    for (int jj = 0; jj < 4; ++jj) invl[jj] = 1.0f / lrow[jj];
#pragma unroll
    for (int dt = 0; dt < 8; ++dt)
#pragma unroll
        for (int jj = 0; jj < 4; ++jj)
            O[(size_t)(qw + lg * 4 + jj) * HIDN + h * HDIM + dt * 16 + lr] = f2bfu(acc[dt][jj] * invl[jj]);
}

extern "C" void kernel_launch(void* const* d_in, const int* in_sizes, int n_in,
                              void* d_out, int out_size, void* d_ws, size_t ws_size,
                              hipStream_t stream) {
    const float* hidden = (const float*)d_in[0];
    const float* ln1w = (const float*)d_in[2];
    const float* ln1b = (const float*)d_in[3];
    const float* ln2w = (const float*)d_in[4];
    const float* ln2b = (const float*)d_in[5];
    const float* wq = (const float*)d_in[6];
    const float* bq = (const float*)d_in[7];
    const float* wk = (const float*)d_in[8];
    const float* bk = (const float*)d_in[9];
    const float* wv = (const float*)d_in[10];
    const float* bv = (const float*)d_in[11];
    const float* wo = (const float*)d_in[12];
    const float* bo = (const float*)d_in[13];
    const float* wg = (const float*)d_in[14];
    const float* wu = (const float*)d_in[15];
    const float* wd = (const float*)d_in[16];
    const int* tsl = (const int*)d_in[17];
    float* out = (float*)d_out;

    char* ws = (char*)d_ws;
    const size_t MB = 1024 * 1024;
    unsigned short* Wbuf = (unsigned short*)(ws);            // 32 MiB weight staging
    unsigned short* qk   = (unsigned short*)(ws + 32 * MB);  // 16 MiB [2048][4096]
    unsigned short* vt   = (unsigned short*)(ws + 48 * MB);  // 8 MiB [2048 d][2048 t]
    unsigned short* x_bf = (unsigned short*)(ws + 56 * MB);  // 8 MiB; attn out reuses
    unsigned short* g_bf = (unsigned short*)(ws + 64 * MB);  // 32 MiB; WO partials reuse
    unsigned short* part = qk;                               // 32 MiB for down partials
    unsigned short* y_bf = vt;                               // ln2 out reuses vt

    const int HID2 = HIDN * HIDN;
    const int CONV_HID = HID2 / 8 / 256;
    const int CONV_FF  = FFDIM * HIDN / 8 / 256;
    const size_t LDSZ = 131072;

    // ---- QKV ----
    conv3_f32_bf16<<<3 * CONV_HID, 256, 0, stream>>>(wq, wk, wv, Wbuf);
    ln_bf16<<<SEQLEN, 256, 0, stream>>>(hidden, ln1w, ln1b, x_bf);
    gemm256<0><<<dim3(192, 1), 512, LDSZ, stream>>>(x_bf, HIDN, Wbuf, HIDN, HIDN, 24, 0,
                                                    bq, bk, bv, qk, vt);
    rope_kernel<<<SEQLEN * 32 * 64 / 256, 256, 0, stream>>>(qk, tsl);
    attn_kernel<<<512, 256, 0, stream>>>(qk, vt, x_bf);

    // ---- WO + residual (split-K=4, partials in g_bf) ----
    conv_f32_bf16<<<CONV_HID, 256, 0, stream>>>(wo, Wbuf);
    gemm256<4><<<dim3(64, 4), 512, LDSZ, stream>>>(x_bf, HIDN, Wbuf, HIDN, 512, 8, HIDN,
                                                   nullptr, nullptr, nullptr, g_bf, nullptr);
    reduce4_wo<<<4096, 256, 0, stream>>>(g_bf, hidden, bo, out);

    // ---- FFN ----
    ln_bf16<<<SEQLEN, 256, 0, stream>>>(out, ln2w, ln2b, y_bf);
    conv_f32_bf16<<<CONV_FF, 256, 0, stream>>>(wg, Wbuf);
    gemm256<1><<<dim3(256, 1), 512, LDSZ, stream>>>(y_bf, HIDN, Wbuf, HIDN, HIDN, 32, FFDIM,
                                                    nullptr, nullptr, nullptr, g_bf, nullptr);
    conv_f32_bf16<<<CONV_FF, 256, 0, stream>>>(wu, Wbuf);
    gemm256<3><<<dim3(256, 1), 512, LDSZ, stream>>>(y_bf, HIDN, Wbuf, HIDN, HIDN, 32, FFDIM,
                                                    nullptr, nullptr, nullptr, g_bf, nullptr);
    conv_f32_bf16<<<CONV_FF, 256, 0, stream>>>(wd, Wbuf);
    gemm256<4><<<dim3(64, 4), 512, LDSZ, stream>>>(g_bf, FFDIM, Wbuf, FFDIM, 2048, 8, HIDN,
                                                   nullptr, nullptr, nullptr, part, nullptr);
    reduce4_add<<<4096, 256, 0, stream>>>(part, out);
}

// Round 7
// 449.630 us; speedup vs baseline: 2.6620x; 1.0023x over previous
//
#include <hip/hip_runtime.h>

#define HIDN 2048
#define NHEAD 16
#define HDIM 128
#define FFDIM 8192
#define SEQLEN 2048

typedef __attribute__((ext_vector_type(8))) __bf16 bf16x8;
typedef __attribute__((ext_vector_type(4))) float f32x4;
typedef __attribute__((ext_vector_type(4))) unsigned short u16x4;
typedef __attribute__((ext_vector_type(8))) unsigned short u16x8;

__device__ __forceinline__ unsigned short f2bfu(float f) {
    unsigned int u = __float_as_uint(f);
    unsigned int r = u + 0x7fffu + ((u >> 16) & 1u);
    return (unsigned short)(r >> 16);
}
__device__ __forceinline__ float bfu2f(unsigned short u) {
    return __uint_as_float(((unsigned int)u) << 16);
}

__device__ __forceinline__ void gload16(const void* g, void* l) {
    __builtin_amdgcn_global_load_lds(
        (const __attribute__((address_space(1))) unsigned int*)g,
        (__attribute__((address_space(3))) unsigned int*)l,
        16, 0, 0);
}

// ---------------- fp32 -> bf16 weight conversion ----------------
__global__ __launch_bounds__(256)
void conv_f32_bf16(const float* __restrict__ src, unsigned short* __restrict__ dst) {
    int i = blockIdx.x * 256 + threadIdx.x;
    float4 a = ((const float4*)src)[i * 2];
    float4 b = ((const float4*)src)[i * 2 + 1];
    u16x8 v;
    v[0] = f2bfu(a.x); v[1] = f2bfu(a.y); v[2] = f2bfu(a.z); v[3] = f2bfu(a.w);
    v[4] = f2bfu(b.x); v[5] = f2bfu(b.y); v[6] = f2bfu(b.z); v[7] = f2bfu(b.w);
    *(u16x8*)(dst + (size_t)i * 8) = v;
}

// 3 HIDNxHIDN matrices in one launch (each 1<<19 x8 elems)
__global__ __launch_bounds__(256)
void conv3_f32_bf16(const float* __restrict__ s0, const float* __restrict__ s1,
                    const float* __restrict__ s2, unsigned short* __restrict__ dst) {
    int i = blockIdx.x * 256 + threadIdx.x;
    int m = i >> 19;
    int li = i & ((1 << 19) - 1);
    const float* s = (m == 0) ? s0 : (m == 1) ? s1 : s2;
    float4 a = ((const float4*)s)[li * 2];
    float4 b = ((const float4*)s)[li * 2 + 1];
    u16x8 v;
    v[0] = f2bfu(a.x); v[1] = f2bfu(a.y); v[2] = f2bfu(a.z); v[3] = f2bfu(a.w);
    v[4] = f2bfu(b.x); v[5] = f2bfu(b.y); v[6] = f2bfu(b.z); v[7] = f2bfu(b.w);
    *(u16x8*)(dst + (size_t)i * 8) = v;
}

// ---------------- LayerNorm (fp32 in) -> bf16 out ----------------
__global__ __launch_bounds__(256)
void ln_bf16(const float* __restrict__ x, const float* __restrict__ w,
             const float* __restrict__ b, unsigned short* __restrict__ out) {
    const int row = blockIdx.x;
    const int tid = threadIdx.x;
    const float* xr = x + (size_t)row * HIDN;
    float4 v0 = ((const float4*)xr)[tid];
    float4 v1 = ((const float4*)xr)[tid + 256];
    float s = v0.x + v0.y + v0.z + v0.w + v1.x + v1.y + v1.z + v1.w;
    float q = v0.x*v0.x + v0.y*v0.y + v0.z*v0.z + v0.w*v0.w
            + v1.x*v1.x + v1.y*v1.y + v1.z*v1.z + v1.w*v1.w;
    for (int o = 32; o > 0; o >>= 1) {
        s += __shfl_down(s, o, 64);
        q += __shfl_down(q, o, 64);
    }
    __shared__ float red[8];
    const int wid = tid >> 6;
    if ((tid & 63) == 0) { red[wid] = s; red[4 + wid] = q; }
    __syncthreads();
    float st = red[0] + red[1] + red[2] + red[3];
    float qt = red[4] + red[5] + red[6] + red[7];
    float mu = st * (1.0f / HIDN);
    float var = qt * (1.0f / HIDN) - mu * mu;
    float rs = rsqrtf(var + 1e-5f);
    unsigned short* orow = out + (size_t)row * HIDN;
    int i0 = tid * 4, i1 = (tid + 256) * 4;
    orow[i0 + 0] = f2bfu((v0.x - mu) * rs * w[i0 + 0] + b[i0 + 0]);
    orow[i0 + 1] = f2bfu((v0.y - mu) * rs * w[i0 + 1] + b[i0 + 1]);
    orow[i0 + 2] = f2bfu((v0.z - mu) * rs * w[i0 + 2] + b[i0 + 2]);
    orow[i0 + 3] = f2bfu((v0.w - mu) * rs * w[i0 + 3] + b[i0 + 3]);
    orow[i1 + 0] = f2bfu((v1.x - mu) * rs * w[i1 + 0] + b[i1 + 0]);
    orow[i1 + 1] = f2bfu((v1.y - mu) * rs * w[i1 + 1] + b[i1 + 1]);
    orow[i1 + 2] = f2bfu((v1.z - mu) * rs * w[i1 + 2] + b[i1 + 2]);
    orow[i1 + 3] = f2bfu((v1.w - mu) * rs * w[i1 + 3] + b[i1 + 3]);
}

// ---------------- RoPE in-place on qk buffer [S][4096] ----------------
__global__ __launch_bounds__(256)
void rope_kernel(unsigned short* __restrict__ qk, const int* __restrict__ tsl) {
    int id = blockIdx.x * 256 + threadIdx.x;
    int p  = id & 63;
    int hh = (id >> 6) & 31;
    int s  = id >> 11;
    int off = tsl[0] - SEQLEN;
    float inv = exp2f((float)p * -0.20762050593f);
    float ang = (float)(s + off) * inv;
    float c, sn;
    __sincosf(ang, &sn, &c);
    size_t base = (size_t)s * 4096 + hh * 128 + p;
    float x1 = bfu2f(qk[base]);
    float x2 = bfu2f(qk[base + 64]);
    qk[base]      = f2bfu(x1 * c - x2 * sn);
    qk[base + 64] = f2bfu(x2 * c + x1 * sn);
}

// ================= 256x256 GEMM, register-pipelined 8-phase: C = A(bf16) * B^T(bf16) =========
// EPI 0 (QKV):  col<4096 -> qk[row*4096+col]+bias; else vt[(col-4096)*SEQ+row]+bv
// EPI 1 (BF):   outB[row*ldc+col] = bf16(acc)
// EPI 3 (SILU): outB[row*ldc+col] = bf16(silu(prev)*acc) in-place
// EPI 4 (PART): outB[ky*2048*2048 + row*ldc+col] = bf16(acc)   (split-K partial)
#define BAR __builtin_amdgcn_s_barrier()
#define VM4 asm volatile("s_waitcnt vmcnt(4)" ::: "memory")
#define VM0 asm volatile("s_waitcnt vmcnt(0)" ::: "memory")
#define LGK4 do { asm volatile("s_waitcnt lgkmcnt(4)" ::: "memory"); \
                  __builtin_amdgcn_sched_barrier(0); } while (0)
#define LGK0 do { asm volatile("s_waitcnt lgkmcnt(0)" ::: "memory"); \
                  __builtin_amdgcn_sched_barrier(0); } while (0)

#define STAGE_A(tile, h) { const int k0_ = k_start + (tile) * 64;                      \
  _Pragma("unroll") for (int i_ = 0; i_ < 2; ++i_) {                                   \
    int d_ = (h) * 16384 + i_ * 8192 + tid * 16;                                       \
    int r_ = d_ >> 7;                                                                  \
    int cb_ = (d_ & 127) ^ ((r_ & 7) << 4);                                            \
    gload16((const char*)Ab + ((size_t)(brow + r_) * lda + k0_) * 2 + cb_,             \
            smem + ((tile) & 1) * 65536 + (h) * 16384 + i_ * 8192 + w * 1024); } }

#define STAGE_B(tile, h) { const int k0_ = k_start + (tile) * 64;                      \
  _Pragma("unroll") for (int i_ = 0; i_ < 2; ++i_) {                                   \
    int d_ = (h) * 16384 + i_ * 8192 + tid * 16;                                       \
    int r_ = d_ >> 7;                                                                  \
    int cb_ = (d_ & 127) ^ ((r_ & 7) << 4);                                            \
    gload16((const char*)Bb + ((size_t)(bcol + r_) * ldb + k0_) * 2 + cb_,             \
            smem + ((tile) & 1) * 65536 + 32768 + (h) * 16384 + i_ * 8192 + w * 1024); } }

#define LDB(BO)                                                                        \
  _Pragma("unroll") for (int n_ = 0; n_ < 4; ++n_)                                     \
  _Pragma("unroll") for (int kk_ = 0; kk_ < 2; ++kk_)                                  \
    bF[n_][kk_] = *(const bf16x8*)(smem + (BO) + bbase + n_ * 2048 + colb[kk_]);

#define LDA_SET(BO, MP, SET)                                                           \
  _Pragma("unroll") for (int dm_ = 0; dm_ < 2; ++dm_)                                  \
  _Pragma("unroll") for (int kk_ = 0; kk_ < 2; ++kk_)                                  \
    SET[dm_][kk_] = *(const bf16x8*)(smem + (BO) + abase + ((MP) * 2 + dm_) * 2048 + colb[kk_]);

#define MM_SET(SET, MP)                                                                \
  __builtin_amdgcn_s_setprio(1);                                                       \
  _Pragma("unroll") for (int dm_ = 0; dm_ < 2; ++dm_)                                  \
  _Pragma("unroll") for (int n_ = 0; n_ < 4; ++n_)                                     \
  _Pragma("unroll") for (int kk_ = 0; kk_ < 2; ++kk_)                                  \
    acc[(MP) * 2 + dm_][n_] = __builtin_amdgcn_mfma_f32_16x16x32_bf16(                 \
        SET[dm_][kk_], bF[n_][kk_], acc[(MP) * 2 + dm_][n_], 0, 0, 0);                 \
  __builtin_amdgcn_s_setprio(0);

template<int EPI>
__global__ __launch_bounds__(512, 1)
void gemm256(const unsigned short* __restrict__ Ab, int lda,
             const unsigned short* __restrict__ Bb, int ldb,
             int k_len, int nbx, int ldc,
             const float* __restrict__ bias0, const float* __restrict__ bias1,
             const float* __restrict__ bias2,
             unsigned short* __restrict__ outB, unsigned short* __restrict__ outV) {
    extern __shared__ char smem[];   // 131072 bytes
    const int tid = threadIdx.x;
    const int w = tid >> 6, lane = tid & 63;
    const int lr = lane & 15, lg = lane >> 4;
    const int wrow = (w >> 2) * 128;
    const int wc = w & 3;

    // XCD column-stripe chunking: per-XCD B footprint = (nbx/8)*256 N-rows (L2-resident)
    const int cpx = nbx >> 3;
    const int xcd = blockIdx.x & 7;
    const int loc = blockIdx.x >> 3;
    const int bx = xcd * cpx + loc % cpx;
    const int by = loc / cpx;
    const int brow = by * 256, bcol = bx * 256;
    const int k_start = blockIdx.y * k_len;

    const int xorv = (lr & 7) << 4;
    int colb[2];
    colb[0] = (lg * 16) ^ xorv;
    colb[1] = (64 + lg * 16) ^ xorv;
    const int abase = (wrow + lr) * 128;
    const int bbase = 32768 + (wc * 64 + lr) * 128;

    f32x4 acc[8][4];
#pragma unroll
    for (int m = 0; m < 8; ++m)
#pragma unroll
        for (int n = 0; n < 4; ++n) acc[m][n] = (f32x4){0.f, 0.f, 0.f, 0.f};

    bf16x8 bF[4][2], aFa[2][2], aFb[2][2];

    const int NT = k_len >> 6;
    const int NIT = NT >> 1;

    // prologue: tile0 A+B, tile1 B; drain all but B1; preload tile0 fragments' first set
    STAGE_A(0, 0); STAGE_A(0, 1); STAGE_B(0, 0); STAGE_B(0, 1);
    STAGE_B(1, 0); STAGE_B(1, 1);
    VM4; BAR;
    LDB(0); LDA_SET(0, 0, aFa);

    for (int it = 0; it < NIT; ++it) {
        const int T = 2 * it;
        const bool s2 = (T + 2) < NT, s3 = (T + 3) < NT;
        // ---- tile T (buf0): reads pipelined one phase ahead ----
        STAGE_A(T + 1, 0); LDA_SET(0, 1, aFb); LGK4; MM_SET(aFa, 0);
        STAGE_A(T + 1, 1); LDA_SET(0, 2, aFa); LGK4; MM_SET(aFb, 1);
        BAR;
        if (s2) STAGE_B(T + 2, 0);
        LDA_SET(0, 3, aFb); LGK4; MM_SET(aFa, 2);
        if (s2) STAGE_B(T + 2, 1);
        LGK0; MM_SET(aFb, 3);          // consume bF(buf0) BEFORE overwriting it
        if (s2) { VM4; } else { VM0; }
        BAR;
        LDB(65536); LDA_SET(65536, 0, aFa);
        // ---- tile T+1 (buf1) ----
        if (s2) STAGE_A(T + 2, 0);
        LDA_SET(65536, 1, aFb); LGK4; MM_SET(aFa, 0);
        if (s2) STAGE_A(T + 2, 1);
        LDA_SET(65536, 2, aFa); LGK4; MM_SET(aFb, 1);
        BAR;
        if (s3) STAGE_B(T + 3, 0);
        LDA_SET(65536, 3, aFb); LGK4; MM_SET(aFa, 2);
        if (s3) STAGE_B(T + 3, 1);
        LGK0; MM_SET(aFb, 3);
        if (s3) { VM4; } else { VM0; }
        BAR;
        LDB(0); LDA_SET(0, 0, aFa);    // next iteration's tile (stale on last iter; unused)
    }

    // ======== LDS-staged epilogue (per-wave 16KB slice; all barriers passed) ========
    char* sw = smem + w * 16384;
    const bool vblk = (EPI == 0) && (bcol >= 4096);

    if (!vblk) {
        // stage row-major [128 r][64 c] bf16, byte-swizzled ^((r&7)<<4)
#pragma unroll
        for (int n = 0; n < 4; ++n) {
            const int col = bcol + wc * 64 + n * 16 + lr;
            float bv = 0.f;
            if (EPI == 0) bv = (col < 2048) ? bias0[col] : bias1[col - 2048];
#pragma unroll
            for (int m = 0; m < 8; ++m)
#pragma unroll
                for (int j = 0; j < 4; ++j) {
                    const int r = m * 16 + lg * 4 + j;
                    const int cb = ((n * 16 + lr) * 2) ^ ((r & 7) << 4);
                    *(unsigned short*)(sw + r * 128 + cb) = f2bfu(acc[m][n][j] + bv);
                }
        }
        // readback: 16 iters x (8 rows x 8 lanes x 16B)
        const int rl = lane >> 3, cl = lane & 7;
#pragma unroll
        for (int it2 = 0; it2 < 16; ++it2) {
            const int r = it2 * 8 + rl;
            const int cb = (cl * 16) ^ ((r & 7) << 4);
            u16x8 val = *(const u16x8*)(sw + r * 128 + cb);
            const int gr = brow + wrow + r;
            const int gcol = bcol + wc * 64 + cl * 8;
            if (EPI == 0) {
                *(u16x8*)(outB + (size_t)gr * 4096 + gcol) = val;
            } else if (EPI == 1) {
                *(u16x8*)(outB + (size_t)gr * ldc + gcol) = val;
            } else if (EPI == 3) {
                unsigned short* gp = outB + (size_t)gr * ldc + gcol;
                u16x8 gv = *(const u16x8*)gp;
                u16x8 ov;
#pragma unroll
                for (int e = 0; e < 8; ++e) {
                    float g = bfu2f(gv[e]);
                    float uu = bfu2f(val[e]);
                    ov[e] = f2bfu(g / (1.0f + __expf(-g)) * uu);
                }
                *(u16x8*)gp = ov;
            } else {
                *(u16x8*)(outB + (size_t)blockIdx.y * 4194304 + (size_t)gr * ldc + gcol) = val;
            }
        }
    } else {
        // V block: stage TRANSPOSED [64 c][128 r] bf16, byte-swizzled ^((c&7)<<4)
#pragma unroll
        for (int n = 0; n < 4; ++n) {
            const int c = n * 16 + lr;
            const float bv = bias2[bcol - 4096 + wc * 64 + c];
            const int cx = (c & 7) << 4;
#pragma unroll
            for (int m = 0; m < 8; ++m) {
                const int r0 = m * 16 + lg * 4;
                u16x4 pk;
#pragma unroll
                for (int j = 0; j < 4; ++j) pk[j] = f2bfu(acc[m][n][j] + bv);
                *(u16x4*)(sw + c * 256 + ((r0 * 2) ^ cx)) = pk;
            }
        }
        // readback: 16 iters x (4 cols x 16 lanes x 16B)
        const int cg = lane >> 4, rl2 = lane & 15;
#pragma unroll
        for (int it2 = 0; it2 < 16; ++it2) {
            const int c = it2 * 4 + cg;
            const int rb = (rl2 * 16) ^ ((c & 7) << 4);
            u16x8 val = *(const u16x8*)(sw + c * 256 + rb);
            const int d = bcol - 4096 + wc * 64 + c;
            *(u16x8*)(outV + (size_t)d * SEQLEN + brow + wrow + rl2 * 8) = val;
        }
    }
}

// ---------------- split-K reduce: out += sum of 4 bf16 partials ----------------
__global__ __launch_bounds__(256)
void reduce4_add(const unsigned short* __restrict__ part, float* __restrict__ out) {
    int i = blockIdx.x * 256 + threadIdx.x;
    float4 o = ((const float4*)out)[i];
#pragma unroll
    for (int sk = 0; sk < 4; ++sk) {
        u16x4 p = ((const u16x4*)(part + (size_t)sk * 4194304))[i];
        o.x += bfu2f(p[0]); o.y += bfu2f(p[1]); o.z += bfu2f(p[2]); o.w += bfu2f(p[3]);
    }
    ((float4*)out)[i] = o;
}

// ---------------- WO reduce: out = hidden + bias + sum of 4 partials ----------------
__global__ __launch_bounds__(256)
void reduce4_wo(const unsigned short* __restrict__ part, const float* __restrict__ h,
                const float* __restrict__ bias, float* __restrict__ out) {
    int i = blockIdx.x * 256 + threadIdx.x;
    float4 o = ((const float4*)h)[i];
    int col = (i & 511) * 4;
    o.x += bias[col]; o.y += bias[col + 1]; o.z += bias[col + 2]; o.w += bias[col + 3];
#pragma unroll
    for (int sk = 0; sk < 4; ++sk) {
        u16x4 p = ((const u16x4*)(part + (size_t)sk * 4194304))[i];
        o.x += bfu2f(p[0]); o.y += bfu2f(p[1]); o.z += bfu2f(p[2]); o.w += bfu2f(p[3]);
    }
    ((float4*)out)[i] = o;
}

// ---------------- Flash attention: 4 waves/block, QBLK=64, KVBLK=64, defer-max ----------------
#define PST 72
__global__ __launch_bounds__(256)
void attn_kernel(const unsigned short* __restrict__ QK, const unsigned short* __restrict__ VT,
                 unsigned short* __restrict__ O) {
    __shared__ __align__(16) unsigned short Ks[2][64 * 128];   // swz ^((row&7)<<4)
    __shared__ __align__(16) unsigned short Vs[2][128 * 64];   // swz ^((d&7)<<4)
    __shared__ __align__(16) unsigned short Ps[4][16 * PST];
    const int tid = threadIdx.x;
    const int lane = tid & 63;
    const int w = tid >> 6;
    const int lr = lane & 15, lg = lane >> 4;

    const int id = blockIdx.x;
    const int pair = id & 7;
    const int j0 = id >> 3;
    const int h = pair * 2 + (j0 & 1);
    const int qb = 31 - (j0 >> 1);
    const int q0 = qb * 64;
    const int qw = q0 + w * 16;

    const unsigned short* Qb = QK + (size_t)qw * 4096 + h * 128;
    const unsigned short* Kb = QK + 2048 + h * 128;
    const unsigned short* Vb = VT + (size_t)(h * 128) * SEQLEN;

    bf16x8 qa[4];
#pragma unroll
    for (int c = 0; c < 4; ++c)
        qa[c] = *(const bf16x8*)(Qb + (size_t)lr * 4096 + c * 32 + lg * 8);

    int krow[4], kcb[4], vrow[4], vcb[4];
#pragma unroll
    for (int ch = 0; ch < 4; ++ch) {
        int d = ch * 4096 + w * 1024 + lane * 16;
        krow[ch] = d >> 8;
        kcb[ch]  = (d & 255) ^ ((krow[ch] & 7) << 4);
        vrow[ch] = d >> 7;
        vcb[ch]  = (d & 127) ^ ((vrow[ch] & 7) << 4);
    }

    f32x4 acc[8];
#pragma unroll
    for (int dt = 0; dt < 8; ++dt) acc[dt] = (f32x4){0.f, 0.f, 0.f, 0.f};
    float mrow[4] = {-INFINITY, -INFINITY, -INFINITY, -INFINITY};
    float lrow[4] = {0.f, 0.f, 0.f, 0.f};

    const float sc = 0.08838834764831845f;
    const int ntile = qb + 1;

#pragma unroll
    for (int ch = 0; ch < 4; ++ch) {
        gload16(Kb + (size_t)krow[ch] * 4096 + (kcb[ch] >> 1),
                (char*)&Ks[0][0] + ch * 4096 + w * 1024);
        gload16(Vb + (size_t)vrow[ch] * SEQLEN + (vcb[ch] >> 1),
                (char*)&Vs[0][0] + ch * 4096 + w * 1024);
    }
    __syncthreads();

    for (int tt = 0; tt < ntile; ++tt) {
        const int cur = tt & 1;
        const int t0 = tt * 64;
        if (tt + 1 < ntile) {
            const int t1 = t0 + 64;
#pragma unroll
            for (int ch = 0; ch < 4; ++ch) {
                gload16(Kb + (size_t)(t1 + krow[ch]) * 4096 + (kcb[ch] >> 1),
                        (char*)&Ks[cur ^ 1][0] + ch * 4096 + w * 1024);
                gload16(Vb + (size_t)vrow[ch] * SEQLEN + t1 + (vcb[ch] >> 1),
                        (char*)&Vs[cur ^ 1][0] + ch * 4096 + w * 1024);
            }
        }
        f32x4 s[4];
#pragma unroll
        for (int th = 0; th < 4; ++th) s[th] = (f32x4){0.f, 0.f, 0.f, 0.f};
        __builtin_amdgcn_s_setprio(1);
#pragma unroll
        for (int th = 0; th < 4; ++th) {
            const int row = th * 16 + lr;
#pragma unroll
            for (int c = 0; c < 4; ++c) {
                bf16x8 kb = *(const bf16x8*)((char*)&Ks[cur][0] + row * 256 +
                                             ((c * 64 + lg * 16) ^ ((lr & 7) << 4)));
                s[th] = __builtin_amdgcn_mfma_f32_16x16x32_bf16(qa[c], kb, s[th], 0, 0, 0);
            }
        }
        __builtin_amdgcn_s_setprio(0);
#pragma unroll
        for (int th = 0; th < 4; ++th) {
            int tg = t0 + th * 16 + lr;
#pragma unroll
            for (int jj = 0; jj < 4; ++jj) {
                int qg = qw + lg * 4 + jj;
                s[th][jj] = s[th][jj] * sc + (tg <= qg ? 0.f : -1e9f);
            }
        }
        float mt[4];
#pragma unroll
        for (int jj = 0; jj < 4; ++jj)
            mt[jj] = fmaxf(fmaxf(s[0][jj], s[1][jj]), fmaxf(s[2][jj], s[3][jj]));
#pragma unroll
        for (int o = 8; o > 0; o >>= 1)
#pragma unroll
            for (int jj = 0; jj < 4; ++jj) mt[jj] = fmaxf(mt[jj], __shfl_xor(mt[jj], o, 16));
        bool need = false;
#pragma unroll
        for (int jj = 0; jj < 4; ++jj) need = need || (mt[jj] > mrow[jj] + 4.0f);
        if (__any(need)) {
#pragma unroll
            for (int jj = 0; jj < 4; ++jj) {
                float mn = fmaxf(mrow[jj], mt[jj]);
                float a = __expf(mrow[jj] - mn);
                mrow[jj] = mn;
                lrow[jj] *= a;
#pragma unroll
                for (int dt = 0; dt < 8; ++dt) acc[dt][jj] *= a;
            }
        }
        float ps[4] = {0.f, 0.f, 0.f, 0.f};
#pragma unroll
        for (int th = 0; th < 4; ++th)
#pragma unroll
            for (int jj = 0; jj < 4; ++jj) {
                float p = __expf(s[th][jj] - mrow[jj]);
                s[th][jj] = p;
                ps[jj] += p;
            }
#pragma unroll
        for (int o = 8; o > 0; o >>= 1)
#pragma unroll
            for (int jj = 0; jj < 4; ++jj) ps[jj] += __shfl_xor(ps[jj], o, 16);
#pragma unroll
        for (int jj = 0; jj < 4; ++jj) lrow[jj] += ps[jj];
#pragma unroll
        for (int th = 0; th < 4; ++th)
#pragma unroll
            for (int jj = 0; jj < 4; ++jj)
                Ps[w][(lg * 4 + jj) * PST + th * 16 + lr] = f2bfu(s[th][jj]);
        bf16x8 pa[2];
#pragma unroll
        for (int ks = 0; ks < 2; ++ks)
            pa[ks] = *(const bf16x8*)&Ps[w][lr * PST + ks * 32 + lg * 8];
        __builtin_amdgcn_s_setprio(1);
#pragma unroll
        for (int dt = 0; dt < 8; ++dt) {
            const int d = dt * 16 + lr;
#pragma unroll
            for (int ks = 0; ks < 2; ++ks) {
                bf16x8 vb = *(const bf16x8*)((char*)&Vs[cur][0] + d * 128 +
                                             ((ks * 64 + lg * 16) ^ ((lr & 7) << 4)));
                acc[dt] = __builtin_amdgcn_mfma_f32_16x16x32_bf16(pa[ks], vb, acc[dt], 0, 0, 0);
            }
        }
        __builtin_amdgcn_s_setprio(0);
        __syncthreads();
    }
    float invl[4];
#pragma unroll
    for (int jj = 0; jj < 4; ++jj) invl[jj] = 1.0f / lrow[jj];
#pragma unroll
    for (int dt = 0; dt < 8; ++dt)
#pragma unroll
        for (int jj = 0; jj < 4; ++jj)
            O[(size_t)(qw + lg * 4 + jj) * HIDN + h * HDIM + dt * 16 + lr] = f2bfu(acc[dt][jj] * invl[jj]);
}

extern "C" void kernel_launch(void* const* d_in, const int* in_sizes, int n_in,
                              void* d_out, int out_size, void* d_ws, size_t ws_size,
                              hipStream_t stream) {
    const float* hidden = (const float*)d_in[0];
    const float* ln1w = (const float*)d_in[2];
    const float* ln1b = (const float*)d_in[3];
    const float* ln2w = (const float*)d_in[4];
    const float* ln2b = (const float*)d_in[5];
    const float* wq = (const float*)d_in[6];
    const float* bq = (const float*)d_in[7];
    const float* wk = (const float*)d_in[8];
    const float* bk = (const float*)d_in[9];
    const float* wv = (const float*)d_in[10];
    const float* bv = (const float*)d_in[11];
    const float* wo = (const float*)d_in[12];
    const float* bo = (const float*)d_in[13];
    const float* wg = (const float*)d_in[14];
    const float* wu = (const float*)d_in[15];
    const float* wd = (const float*)d_in[16];
    const int* tsl = (const int*)d_in[17];
    float* out = (float*)d_out;

    char* ws = (char*)d_ws;
    const size_t MB = 1024 * 1024;
    unsigned short* Wbuf = (unsigned short*)(ws);            // 32 MiB weight staging
    unsigned short* qk   = (unsigned short*)(ws + 32 * MB);  // 16 MiB [2048][4096]
    unsigned short* vt   = (unsigned short*)(ws + 48 * MB);  // 8 MiB [2048 d][2048 t]
    unsigned short* x_bf = (unsigned short*)(ws + 56 * MB);  // 8 MiB; attn out reuses
    unsigned short* g_bf = (unsigned short*)(ws + 64 * MB);  // 32 MiB; WO partials reuse
    unsigned short* part = qk;                               // 32 MiB for down partials
    unsigned short* y_bf = vt;                               // ln2 out reuses vt

    const int HID2 = HIDN * HIDN;
    const int CONV_HID = HID2 / 8 / 256;
    const int CONV_FF  = FFDIM * HIDN / 8 / 256;
    const size_t LDSZ = 131072;

    // ---- QKV ----
    conv3_f32_bf16<<<3 * CONV_HID, 256, 0, stream>>>(wq, wk, wv, Wbuf);
    ln_bf16<<<SEQLEN, 256, 0, stream>>>(hidden, ln1w, ln1b, x_bf);
    gemm256<0><<<dim3(192, 1), 512, LDSZ, stream>>>(x_bf, HIDN, Wbuf, HIDN, HIDN, 24, 0,
                                                    bq, bk, bv, qk, vt);
    rope_kernel<<<SEQLEN * 32 * 64 / 256, 256, 0, stream>>>(qk, tsl);
    attn_kernel<<<512, 256, 0, stream>>>(qk, vt, x_bf);

    // ---- WO + residual (split-K=4, partials in g_bf) ----
    conv_f32_bf16<<<CONV_HID, 256, 0, stream>>>(wo, Wbuf);
    gemm256<4><<<dim3(64, 4), 512, LDSZ, stream>>>(x_bf, HIDN, Wbuf, HIDN, 512, 8, HIDN,
                                                   nullptr, nullptr, nullptr, g_bf, nullptr);
    reduce4_wo<<<4096, 256, 0, stream>>>(g_bf, hidden, bo, out);

    // ---- FFN ----
    ln_bf16<<<SEQLEN, 256, 0, stream>>>(out, ln2w, ln2b, y_bf);
    conv_f32_bf16<<<CONV_FF, 256, 0, stream>>>(wg, Wbuf);
    gemm256<1><<<dim3(256, 1), 512, LDSZ, stream>>>(y_bf, HIDN, Wbuf, HIDN, HIDN, 32, FFDIM,
                                                    nullptr, nullptr, nullptr, g_bf, nullptr);
    conv_f32_bf16<<<CONV_FF, 256, 0, stream>>>(wu, Wbuf);
    gemm256<3><<<dim3(256, 1), 512, LDSZ, stream>>>(y_bf, HIDN, Wbuf, HIDN, HIDN, 32, FFDIM,
                                                    nullptr, nullptr, nullptr, g_bf, nullptr);
    conv_f32_bf16<<<CONV_FF, 256, 0, stream>>>(wd, Wbuf);
    gemm256<4><<<dim3(64, 4), 512, LDSZ, stream>>>(g_bf, FFDIM, Wbuf, FFDIM, 2048, 8, HIDN,
                                                   nullptr, nullptr, nullptr, part, nullptr);
    reduce4_add<<<4096, 256, 0, stream>>>(part, out);
}

// Round 8
// 442.204 us; speedup vs baseline: 2.7067x; 1.0168x over previous
//
#include <hip/hip_runtime.h>

#define HIDN 2048
#define NHEAD 16
#define HDIM 128
#define FFDIM 8192
#define SEQLEN 2048

typedef __attribute__((ext_vector_type(8))) __bf16 bf16x8;
typedef __attribute__((ext_vector_type(4))) float f32x4;
typedef __attribute__((ext_vector_type(4))) unsigned short u16x4;
typedef __attribute__((ext_vector_type(8))) unsigned short u16x8;

__device__ __forceinline__ unsigned short f2bfu(float f) {
    unsigned int u = __float_as_uint(f);
    unsigned int r = u + 0x7fffu + ((u >> 16) & 1u);
    return (unsigned short)(r >> 16);
}
__device__ __forceinline__ float bfu2f(unsigned short u) {
    return __uint_as_float(((unsigned int)u) << 16);
}

__device__ __forceinline__ void gload16(const void* g, void* l) {
    __builtin_amdgcn_global_load_lds(
        (const __attribute__((address_space(1))) unsigned int*)g,
        (__attribute__((address_space(3))) unsigned int*)l,
        16, 0, 0);
}

// ---------------- fp32 -> bf16 weight conversion ----------------
__global__ __launch_bounds__(256)
void conv_f32_bf16(const float* __restrict__ src, unsigned short* __restrict__ dst) {
    int i = blockIdx.x * 256 + threadIdx.x;
    float4 a = ((const float4*)src)[i * 2];
    float4 b = ((const float4*)src)[i * 2 + 1];
    u16x8 v;
    v[0] = f2bfu(a.x); v[1] = f2bfu(a.y); v[2] = f2bfu(a.z); v[3] = f2bfu(a.w);
    v[4] = f2bfu(b.x); v[5] = f2bfu(b.y); v[6] = f2bfu(b.z); v[7] = f2bfu(b.w);
    *(u16x8*)(dst + (size_t)i * 8) = v;
}

// 3 HIDNxHIDN matrices in one launch (each 1<<19 x8 elems)
__global__ __launch_bounds__(256)
void conv3_f32_bf16(const float* __restrict__ s0, const float* __restrict__ s1,
                    const float* __restrict__ s2, unsigned short* __restrict__ dst) {
    int i = blockIdx.x * 256 + threadIdx.x;
    int m = i >> 19;
    int li = i & ((1 << 19) - 1);
    const float* s = (m == 0) ? s0 : (m == 1) ? s1 : s2;
    float4 a = ((const float4*)s)[li * 2];
    float4 b = ((const float4*)s)[li * 2 + 1];
    u16x8 v;
    v[0] = f2bfu(a.x); v[1] = f2bfu(a.y); v[2] = f2bfu(a.z); v[3] = f2bfu(a.w);
    v[4] = f2bfu(b.x); v[5] = f2bfu(b.y); v[6] = f2bfu(b.z); v[7] = f2bfu(b.w);
    *(u16x8*)(dst + (size_t)i * 8) = v;
}

// ---------------- LayerNorm (fp32 in) -> bf16 out ----------------
__global__ __launch_bounds__(256)
void ln_bf16(const float* __restrict__ x, const float* __restrict__ w,
             const float* __restrict__ b, unsigned short* __restrict__ out) {
    const int row = blockIdx.x;
    const int tid = threadIdx.x;
    const float* xr = x + (size_t)row * HIDN;
    float4 v0 = ((const float4*)xr)[tid];
    float4 v1 = ((const float4*)xr)[tid + 256];
    float s = v0.x + v0.y + v0.z + v0.w + v1.x + v1.y + v1.z + v1.w;
    float q = v0.x*v0.x + v0.y*v0.y + v0.z*v0.z + v0.w*v0.w
            + v1.x*v1.x + v1.y*v1.y + v1.z*v1.z + v1.w*v1.w;
    for (int o = 32; o > 0; o >>= 1) {
        s += __shfl_down(s, o, 64);
        q += __shfl_down(q, o, 64);
    }
    __shared__ float red[8];
    const int wid = tid >> 6;
    if ((tid & 63) == 0) { red[wid] = s; red[4 + wid] = q; }
    __syncthreads();
    float st = red[0] + red[1] + red[2] + red[3];
    float qt = red[4] + red[5] + red[6] + red[7];
    float mu = st * (1.0f / HIDN);
    float var = qt * (1.0f / HIDN) - mu * mu;
    float rs = rsqrtf(var + 1e-5f);
    unsigned short* orow = out + (size_t)row * HIDN;
    int i0 = tid * 4, i1 = (tid + 256) * 4;
    orow[i0 + 0] = f2bfu((v0.x - mu) * rs * w[i0 + 0] + b[i0 + 0]);
    orow[i0 + 1] = f2bfu((v0.y - mu) * rs * w[i0 + 1] + b[i0 + 1]);
    orow[i0 + 2] = f2bfu((v0.z - mu) * rs * w[i0 + 2] + b[i0 + 2]);
    orow[i0 + 3] = f2bfu((v0.w - mu) * rs * w[i0 + 3] + b[i0 + 3]);
    orow[i1 + 0] = f2bfu((v1.x - mu) * rs * w[i1 + 0] + b[i1 + 0]);
    orow[i1 + 1] = f2bfu((v1.y - mu) * rs * w[i1 + 1] + b[i1 + 1]);
    orow[i1 + 2] = f2bfu((v1.z - mu) * rs * w[i1 + 2] + b[i1 + 2]);
    orow[i1 + 3] = f2bfu((v1.w - mu) * rs * w[i1 + 3] + b[i1 + 3]);
}

// ---------------- WO combine + residual + LN2, one block per row ----------------
__global__ __launch_bounds__(256)
void wo_ln(const unsigned short* __restrict__ part, const float* __restrict__ h,
           const float* __restrict__ bo, const float* __restrict__ w,
           const float* __restrict__ b, float* __restrict__ out,
           unsigned short* __restrict__ ybf) {
    const int row = blockIdx.x;
    const int tid = threadIdx.x;
    const int c0 = tid * 4, c1 = (tid + 256) * 4;
    float4 o0 = ((const float4*)(h + (size_t)row * HIDN))[tid];
    float4 o1 = ((const float4*)(h + (size_t)row * HIDN))[tid + 256];
    o0.x += bo[c0]; o0.y += bo[c0 + 1]; o0.z += bo[c0 + 2]; o0.w += bo[c0 + 3];
    o1.x += bo[c1]; o1.y += bo[c1 + 1]; o1.z += bo[c1 + 2]; o1.w += bo[c1 + 3];
#pragma unroll
    for (int sk = 0; sk < 4; ++sk) {
        const unsigned short* pr = part + (size_t)sk * 4194304 + (size_t)row * HIDN;
        u16x4 p0 = *(const u16x4*)(pr + c0);
        u16x4 p1 = *(const u16x4*)(pr + c1);
        o0.x += bfu2f(p0[0]); o0.y += bfu2f(p0[1]); o0.z += bfu2f(p0[2]); o0.w += bfu2f(p0[3]);
        o1.x += bfu2f(p1[0]); o1.y += bfu2f(p1[1]); o1.z += bfu2f(p1[2]); o1.w += bfu2f(p1[3]);
    }
    ((float4*)(out + (size_t)row * HIDN))[tid] = o0;
    ((float4*)(out + (size_t)row * HIDN))[tid + 256] = o1;
    float s = o0.x + o0.y + o0.z + o0.w + o1.x + o1.y + o1.z + o1.w;
    float q = o0.x*o0.x + o0.y*o0.y + o0.z*o0.z + o0.w*o0.w
            + o1.x*o1.x + o1.y*o1.y + o1.z*o1.z + o1.w*o1.w;
    for (int o = 32; o > 0; o >>= 1) {
        s += __shfl_down(s, o, 64);
        q += __shfl_down(q, o, 64);
    }
    __shared__ float red[8];
    const int wid = tid >> 6;
    if ((tid & 63) == 0) { red[wid] = s; red[4 + wid] = q; }
    __syncthreads();
    float st = red[0] + red[1] + red[2] + red[3];
    float qt = red[4] + red[5] + red[6] + red[7];
    float mu = st * (1.0f / HIDN);
    float var = qt * (1.0f / HIDN) - mu * mu;
    float rs = rsqrtf(var + 1e-5f);
    unsigned short* yr = ybf + (size_t)row * HIDN;
    yr[c0 + 0] = f2bfu((o0.x - mu) * rs * w[c0 + 0] + b[c0 + 0]);
    yr[c0 + 1] = f2bfu((o0.y - mu) * rs * w[c0 + 1] + b[c0 + 1]);
    yr[c0 + 2] = f2bfu((o0.z - mu) * rs * w[c0 + 2] + b[c0 + 2]);
    yr[c0 + 3] = f2bfu((o0.w - mu) * rs * w[c0 + 3] + b[c0 + 3]);
    yr[c1 + 0] = f2bfu((o1.x - mu) * rs * w[c1 + 0] + b[c1 + 0]);
    yr[c1 + 1] = f2bfu((o1.y - mu) * rs * w[c1 + 1] + b[c1 + 1]);
    yr[c1 + 2] = f2bfu((o1.z - mu) * rs * w[c1 + 2] + b[c1 + 2]);
    yr[c1 + 3] = f2bfu((o1.w - mu) * rs * w[c1 + 3] + b[c1 + 3]);
}

// ---------------- RoPE in-place on qk buffer [S][4096] ----------------
__global__ __launch_bounds__(256)
void rope_kernel(unsigned short* __restrict__ qk, const int* __restrict__ tsl) {
    int id = blockIdx.x * 256 + threadIdx.x;
    int p  = id & 63;
    int hh = (id >> 6) & 31;
    int s  = id >> 11;
    int off = tsl[0] - SEQLEN;
    float inv = exp2f((float)p * -0.20762050593f);
    float ang = (float)(s + off) * inv;
    float c, sn;
    __sincosf(ang, &sn, &c);
    size_t base = (size_t)s * 4096 + hh * 128 + p;
    float x1 = bfu2f(qk[base]);
    float x2 = bfu2f(qk[base + 64]);
    qk[base]      = f2bfu(x1 * c - x2 * sn);
    qk[base + 64] = f2bfu(x2 * c + x1 * sn);
}

// ================= 256x256 GEMM, register-pipelined 8-phase: C = A(bf16) * B^T(bf16) =========
#define BAR __builtin_amdgcn_s_barrier()
#define VM4 asm volatile("s_waitcnt vmcnt(4)" ::: "memory")
#define VM0 asm volatile("s_waitcnt vmcnt(0)" ::: "memory")
#define LGK4 do { asm volatile("s_waitcnt lgkmcnt(4)" ::: "memory"); \
                  __builtin_amdgcn_sched_barrier(0); } while (0)
#define LGK0 do { asm volatile("s_waitcnt lgkmcnt(0)" ::: "memory"); \
                  __builtin_amdgcn_sched_barrier(0); } while (0)

#define STAGE_A(tile, h) { const int k0_ = k_start + (tile) * 64;                      \
  _Pragma("unroll") for (int i_ = 0; i_ < 2; ++i_) {                                   \
    int d_ = (h) * 16384 + i_ * 8192 + tid * 16;                                       \
    int r_ = d_ >> 7;                                                                  \
    int cb_ = (d_ & 127) ^ ((r_ & 7) << 4);                                            \
    gload16((const char*)Ab + ((size_t)(brow + r_) * lda + k0_) * 2 + cb_,             \
            smem + ((tile) & 1) * 65536 + (h) * 16384 + i_ * 8192 + w * 1024); } }

#define STAGE_B(tile, h) { const int k0_ = k_start + (tile) * 64;                      \
  _Pragma("unroll") for (int i_ = 0; i_ < 2; ++i_) {                                   \
    int d_ = (h) * 16384 + i_ * 8192 + tid * 16;                                       \
    int r_ = d_ >> 7;                                                                  \
    int cb_ = (d_ & 127) ^ ((r_ & 7) << 4);                                            \
    gload16((const char*)Bb + ((size_t)(bcol + r_) * ldb + k0_) * 2 + cb_,             \
            smem + ((tile) & 1) * 65536 + 32768 + (h) * 16384 + i_ * 8192 + w * 1024); } }

#define LDB(BO)                                                                        \
  _Pragma("unroll") for (int n_ = 0; n_ < 4; ++n_)                                     \
  _Pragma("unroll") for (int kk_ = 0; kk_ < 2; ++kk_)                                  \
    bF[n_][kk_] = *(const bf16x8*)(smem + (BO) + bbase + n_ * 2048 + colb[kk_]);

#define LDA_SET(BO, MP, SET)                                                           \
  _Pragma("unroll") for (int dm_ = 0; dm_ < 2; ++dm_)                                  \
  _Pragma("unroll") for (int kk_ = 0; kk_ < 2; ++kk_)                                  \
    SET[dm_][kk_] = *(const bf16x8*)(smem + (BO) + abase + ((MP) * 2 + dm_) * 2048 + colb[kk_]);

#define MM_SET(SET, MP)                                                                \
  __builtin_amdgcn_s_setprio(1);                                                       \
  _Pragma("unroll") for (int dm_ = 0; dm_ < 2; ++dm_)                                  \
  _Pragma("unroll") for (int n_ = 0; n_ < 4; ++n_)                                     \
  _Pragma("unroll") for (int kk_ = 0; kk_ < 2; ++kk_)                                  \
    acc[(MP) * 2 + dm_][n_] = __builtin_amdgcn_mfma_f32_16x16x32_bf16(                 \
        SET[dm_][kk_], bF[n_][kk_], acc[(MP) * 2 + dm_][n_], 0, 0, 0);                 \
  __builtin_amdgcn_s_setprio(0);

template<int EPI>
__global__ __launch_bounds__(512, 1)
void gemm256(const unsigned short* __restrict__ Ab, int lda,
             const unsigned short* __restrict__ Bb, int ldb,
             int k_len, int nbx, int ldc,
             const float* __restrict__ bias0, const float* __restrict__ bias1,
             const float* __restrict__ bias2,
             unsigned short* __restrict__ outB, unsigned short* __restrict__ outV) {
    extern __shared__ char smem[];   // 131072 bytes
    const int tid = threadIdx.x;
    const int w = tid >> 6, lane = tid & 63;
    const int lr = lane & 15, lg = lane >> 4;
    const int wrow = (w >> 2) * 128;
    const int wc = w & 3;

    const int cpx = nbx >> 3;
    const int xcd = blockIdx.x & 7;
    const int loc = blockIdx.x >> 3;
    const int bx = xcd * cpx + loc % cpx;
    const int by = loc / cpx;
    const int brow = by * 256, bcol = bx * 256;
    const int k_start = blockIdx.y * k_len;

    const int xorv = (lr & 7) << 4;
    int colb[2];
    colb[0] = (lg * 16) ^ xorv;
    colb[1] = (64 + lg * 16) ^ xorv;
    const int abase = (wrow + lr) * 128;
    const int bbase = 32768 + (wc * 64 + lr) * 128;

    f32x4 acc[8][4];
#pragma unroll
    for (int m = 0; m < 8; ++m)
#pragma unroll
        for (int n = 0; n < 4; ++n) acc[m][n] = (f32x4){0.f, 0.f, 0.f, 0.f};

    bf16x8 bF[4][2], aFa[2][2], aFb[2][2];

    const int NT = k_len >> 6;
    const int NIT = NT >> 1;

    STAGE_A(0, 0); STAGE_A(0, 1); STAGE_B(0, 0); STAGE_B(0, 1);
    STAGE_B(1, 0); STAGE_B(1, 1);
    VM4; BAR;
    LDB(0); LDA_SET(0, 0, aFa);

    for (int it = 0; it < NIT; ++it) {
        const int T = 2 * it;
        const bool s2 = (T + 2) < NT, s3 = (T + 3) < NT;
        STAGE_A(T + 1, 0); LDA_SET(0, 1, aFb); LGK4; MM_SET(aFa, 0);
        STAGE_A(T + 1, 1); LDA_SET(0, 2, aFa); LGK4; MM_SET(aFb, 1);
        BAR;
        if (s2) STAGE_B(T + 2, 0);
        LDA_SET(0, 3, aFb); LGK4; MM_SET(aFa, 2);
        if (s2) STAGE_B(T + 2, 1);
        LGK0; MM_SET(aFb, 3);
        if (s2) { VM4; } else { VM0; }
        BAR;
        LDB(65536); LDA_SET(65536, 0, aFa);
        if (s2) STAGE_A(T + 2, 0);
        LDA_SET(65536, 1, aFb); LGK4; MM_SET(aFa, 0);
        if (s2) STAGE_A(T + 2, 1);
        LDA_SET(65536, 2, aFa); LGK4; MM_SET(aFb, 1);
        BAR;
        if (s3) STAGE_B(T + 3, 0);
        LDA_SET(65536, 3, aFb); LGK4; MM_SET(aFa, 2);
        if (s3) STAGE_B(T + 3, 1);
        LGK0; MM_SET(aFb, 3);
        if (s3) { VM4; } else { VM0; }
        BAR;
        LDB(0); LDA_SET(0, 0, aFa);
    }

    // ======== LDS-staged epilogue ========
    char* sw = smem + w * 16384;
    const bool vblk = (EPI == 0) && (bcol >= 4096);

    if (!vblk) {
#pragma unroll
        for (int n = 0; n < 4; ++n) {
            const int col = bcol + wc * 64 + n * 16 + lr;
            float bv = 0.f;
            if (EPI == 0) bv = (col < 2048) ? bias0[col] : bias1[col - 2048];
#pragma unroll
            for (int m = 0; m < 8; ++m)
#pragma unroll
                for (int j = 0; j < 4; ++j) {
                    const int r = m * 16 + lg * 4 + j;
                    const int cb = ((n * 16 + lr) * 2) ^ ((r & 7) << 4);
                    *(unsigned short*)(sw + r * 128 + cb) = f2bfu(acc[m][n][j] + bv);
                }
        }
        const int rl = lane >> 3, cl = lane & 7;
#pragma unroll
        for (int it2 = 0; it2 < 16; ++it2) {
            const int r = it2 * 8 + rl;
            const int cb = (cl * 16) ^ ((r & 7) << 4);
            u16x8 val = *(const u16x8*)(sw + r * 128 + cb);
            const int gr = brow + wrow + r;
            const int gcol = bcol + wc * 64 + cl * 8;
            if (EPI == 0) {
                *(u16x8*)(outB + (size_t)gr * 4096 + gcol) = val;
            } else if (EPI == 1) {
                *(u16x8*)(outB + (size_t)gr * ldc + gcol) = val;
            } else if (EPI == 3) {
                unsigned short* gp = outB + (size_t)gr * ldc + gcol;
                u16x8 gv = *(const u16x8*)gp;
                u16x8 ov;
#pragma unroll
                for (int e = 0; e < 8; ++e) {
                    float g = bfu2f(gv[e]);
                    float uu = bfu2f(val[e]);
                    ov[e] = f2bfu(g / (1.0f + __expf(-g)) * uu);
                }
                *(u16x8*)gp = ov;
            } else {
                *(u16x8*)(outB + (size_t)blockIdx.y * 4194304 + (size_t)gr * ldc + gcol) = val;
            }
        }
    } else {
#pragma unroll
        for (int n = 0; n < 4; ++n) {
            const int c = n * 16 + lr;
            const float bv = bias2[bcol - 4096 + wc * 64 + c];
            const int cx = (c & 7) << 4;
#pragma unroll
            for (int m = 0; m < 8; ++m) {
                const int r0 = m * 16 + lg * 4;
                u16x4 pk;
#pragma unroll
                for (int j = 0; j < 4; ++j) pk[j] = f2bfu(acc[m][n][j] + bv);
                *(u16x4*)(sw + c * 256 + ((r0 * 2) ^ cx)) = pk;
            }
        }
        const int cg = lane >> 4, rl2 = lane & 15;
#pragma unroll
        for (int it2 = 0; it2 < 16; ++it2) {
            const int c = it2 * 4 + cg;
            const int rb = (rl2 * 16) ^ ((c & 7) << 4);
            u16x8 val = *(const u16x8*)(sw + c * 256 + rb);
            const int d = bcol - 4096 + wc * 64 + c;
            *(u16x8*)(outV + (size_t)d * SEQLEN + brow + wrow + rl2 * 8) = val;
        }
    }
}

// ---------------- split-K reduce: out += sum of 4 bf16 partials ----------------
__global__ __launch_bounds__(256)
void reduce4_add(const unsigned short* __restrict__ part, float* __restrict__ out) {
    int i = blockIdx.x * 256 + threadIdx.x;
    float4 o = ((const float4*)out)[i];
#pragma unroll
    for (int sk = 0; sk < 4; ++sk) {
        u16x4 p = ((const u16x4*)(part + (size_t)sk * 4194304))[i];
        o.x += bfu2f(p[0]); o.y += bfu2f(p[1]); o.z += bfu2f(p[2]); o.w += bfu2f(p[3]);
    }
    ((float4*)out)[i] = o;
}

// ---- Flash attention: 4 waves, QBLK=64, KVBLK=64, paired q-blocks (p, 31-p) ----
#define PST 72
__global__ __launch_bounds__(256)
void attn_kernel(const unsigned short* __restrict__ QK, const unsigned short* __restrict__ VT,
                 unsigned short* __restrict__ O) {
    __shared__ __align__(16) unsigned short Ks[2][64 * 128];   // swz ^((row&7)<<4)
    __shared__ __align__(16) unsigned short Vs[2][128 * 64];   // swz ^((d&7)<<4)
    __shared__ __align__(16) unsigned short Ps[4][16 * PST];
    const int tid = threadIdx.x;
    const int lane = tid & 63;
    const int w = tid >> 6;
    const int lr = lane & 15, lg = lane >> 4;

    // 256 blocks: id&7 -> XCD, two heads per XCD; p = id>>4 pairs {p, 31-p}
    const int id = blockIdx.x;
    const int h = ((id & 7) << 1) | ((id >> 3) & 1);
    const int p = id >> 4;

    const unsigned short* Kb = QK + 2048 + h * 128;
    const unsigned short* Vb = VT + (size_t)(h * 128) * SEQLEN;

    int krow[4], kcb[4], vrow[4], vcb[4];
#pragma unroll
    for (int ch = 0; ch < 4; ++ch) {
        int d = ch * 4096 + w * 1024 + lane * 16;
        krow[ch] = d >> 8;
        kcb[ch]  = (d & 255) ^ ((krow[ch] & 7) << 4);
        vrow[ch] = d >> 7;
        vcb[ch]  = (d & 127) ^ ((vrow[ch] & 7) << 4);
    }

    const float sc = 0.08838834764831845f;

#pragma unroll 1
    for (int seg = 0; seg < 2; ++seg) {
        const int qb = seg ? (31 - p) : p;
        const int qw = qb * 64 + w * 16;
        const unsigned short* Qb = QK + (size_t)qw * 4096 + h * 128;

        bf16x8 qa[4];
#pragma unroll
        for (int c = 0; c < 4; ++c)
            qa[c] = *(const bf16x8*)(Qb + (size_t)lr * 4096 + c * 32 + lg * 8);

        f32x4 acc[8];
#pragma unroll
        for (int dt = 0; dt < 8; ++dt) acc[dt] = (f32x4){0.f, 0.f, 0.f, 0.f};
        float mrow[4] = {-INFINITY, -INFINITY, -INFINITY, -INFINITY};
        float lrow[4] = {0.f, 0.f, 0.f, 0.f};
        const int ntile = qb + 1;

        // prologue: stage tile 0 into buffer 0
#pragma unroll
        for (int ch = 0; ch < 4; ++ch) {
            gload16(Kb + (size_t)krow[ch] * 4096 + (kcb[ch] >> 1),
                    (char*)&Ks[0][0] + ch * 4096 + w * 1024);
            gload16(Vb + (size_t)vrow[ch] * SEQLEN + (vcb[ch] >> 1),
                    (char*)&Vs[0][0] + ch * 4096 + w * 1024);
        }
        __syncthreads();

        for (int tt = 0; tt < ntile; ++tt) {
            const int cur = tt & 1;
            const int t0 = tt * 64;
            if (tt + 1 < ntile) {
                const int t1 = t0 + 64;
#pragma unroll
                for (int ch = 0; ch < 4; ++ch) {
                    gload16(Kb + (size_t)(t1 + krow[ch]) * 4096 + (kcb[ch] >> 1),
                            (char*)&Ks[cur ^ 1][0] + ch * 4096 + w * 1024);
                    gload16(Vb + (size_t)vrow[ch] * SEQLEN + t1 + (vcb[ch] >> 1),
                            (char*)&Vs[cur ^ 1][0] + ch * 4096 + w * 1024);
                }
            }
            f32x4 s[4];
#pragma unroll
            for (int th = 0; th < 4; ++th) s[th] = (f32x4){0.f, 0.f, 0.f, 0.f};
            __builtin_amdgcn_s_setprio(1);
#pragma unroll
            for (int th = 0; th < 4; ++th) {
                const int row = th * 16 + lr;
#pragma unroll
                for (int c = 0; c < 4; ++c) {
                    bf16x8 kb = *(const bf16x8*)((char*)&Ks[cur][0] + row * 256 +
                                                 ((c * 64 + lg * 16) ^ ((lr & 7) << 4)));
                    s[th] = __builtin_amdgcn_mfma_f32_16x16x32_bf16(qa[c], kb, s[th], 0, 0, 0);
                }
            }
            __builtin_amdgcn_s_setprio(0);
#pragma unroll
            for (int th = 0; th < 4; ++th) {
                int tg = t0 + th * 16 + lr;
#pragma unroll
                for (int jj = 0; jj < 4; ++jj) {
                    int qg = qw + lg * 4 + jj;
                    s[th][jj] = s[th][jj] * sc + (tg <= qg ? 0.f : -1e9f);
                }
            }
            float mt[4];
#pragma unroll
            for (int jj = 0; jj < 4; ++jj)
                mt[jj] = fmaxf(fmaxf(s[0][jj], s[1][jj]), fmaxf(s[2][jj], s[3][jj]));
#pragma unroll
            for (int o = 8; o > 0; o >>= 1)
#pragma unroll
                for (int jj = 0; jj < 4; ++jj) mt[jj] = fmaxf(mt[jj], __shfl_xor(mt[jj], o, 16));
            bool need = false;
#pragma unroll
            for (int jj = 0; jj < 4; ++jj) need = need || (mt[jj] > mrow[jj] + 4.0f);
            if (__any(need)) {
#pragma unroll
                for (int jj = 0; jj < 4; ++jj) {
                    float mn = fmaxf(mrow[jj], mt[jj]);
                    float a = __expf(mrow[jj] - mn);
                    mrow[jj] = mn;
                    lrow[jj] *= a;
#pragma unroll
                    for (int dt = 0; dt < 8; ++dt) acc[dt][jj] *= a;
                }
            }
            float ps[4] = {0.f, 0.f, 0.f, 0.f};
#pragma unroll
            for (int th = 0; th < 4; ++th)
#pragma unroll
                for (int jj = 0; jj < 4; ++jj) {
                    float pp = __expf(s[th][jj] - mrow[jj]);
                    s[th][jj] = pp;
                    ps[jj] += pp;
                }
#pragma unroll
            for (int o = 8; o > 0; o >>= 1)
#pragma unroll
                for (int jj = 0; jj < 4; ++jj) ps[jj] += __shfl_xor(ps[jj], o, 16);
#pragma unroll
            for (int jj = 0; jj < 4; ++jj) lrow[jj] += ps[jj];
#pragma unroll
            for (int th = 0; th < 4; ++th)
#pragma unroll
                for (int jj = 0; jj < 4; ++jj)
                    Ps[w][(lg * 4 + jj) * PST + th * 16 + lr] = f2bfu(s[th][jj]);
            bf16x8 pa[2];
#pragma unroll
            for (int ks = 0; ks < 2; ++ks)
                pa[ks] = *(const bf16x8*)&Ps[w][lr * PST + ks * 32 + lg * 8];
            __builtin_amdgcn_s_setprio(1);
#pragma unroll
            for (int dt = 0; dt < 8; ++dt) {
                const int d = dt * 16 + lr;
#pragma unroll
                for (int ks = 0; ks < 2; ++ks) {
                    bf16x8 vb = *(const bf16x8*)((char*)&Vs[cur][0] + d * 128 +
                                                 ((ks * 64 + lg * 16) ^ ((lr & 7) << 4)));
                    acc[dt] = __builtin_amdgcn_mfma_f32_16x16x32_bf16(pa[ks], vb, acc[dt], 0, 0, 0);
                }
            }
            __builtin_amdgcn_s_setprio(0);
            __syncthreads();
        }
        float invl[4];
#pragma unroll
        for (int jj = 0; jj < 4; ++jj) invl[jj] = 1.0f / lrow[jj];
#pragma unroll
        for (int dt = 0; dt < 8; ++dt)
#pragma unroll
            for (int jj = 0; jj < 4; ++jj)
                O[(size_t)(qw + lg * 4 + jj) * HIDN + h * HDIM + dt * 16 + lr] =
                    f2bfu(acc[dt][jj] * invl[jj]);
    }
}

extern "C" void kernel_launch(void* const* d_in, const int* in_sizes, int n_in,
                              void* d_out, int out_size, void* d_ws, size_t ws_size,
                              hipStream_t stream) {
    const float* hidden = (const float*)d_in[0];
    const float* ln1w = (const float*)d_in[2];
    const float* ln1b = (const float*)d_in[3];
    const float* ln2w = (const float*)d_in[4];
    const float* ln2b = (const float*)d_in[5];
    const float* wq = (const float*)d_in[6];
    const float* bq = (const float*)d_in[7];
    const float* wk = (const float*)d_in[8];
    const float* bk = (const float*)d_in[9];
    const float* wv = (const float*)d_in[10];
    const float* bv = (const float*)d_in[11];
    const float* wo = (const float*)d_in[12];
    const float* bo = (const float*)d_in[13];
    const float* wg = (const float*)d_in[14];
    const float* wu = (const float*)d_in[15];
    const float* wd = (const float*)d_in[16];
    const int* tsl = (const int*)d_in[17];
    float* out = (float*)d_out;

    char* ws = (char*)d_ws;
    const size_t MB = 1024 * 1024;
    unsigned short* Wbuf = (unsigned short*)(ws);            // 32 MiB weight staging
    unsigned short* qk   = (unsigned short*)(ws + 32 * MB);  // 16 MiB [2048][4096]
    unsigned short* vt   = (unsigned short*)(ws + 48 * MB);  // 8 MiB [2048 d][2048 t]
    unsigned short* x_bf = (unsigned short*)(ws + 56 * MB);  // 8 MiB; attn out reuses
    unsigned short* g_bf = (unsigned short*)(ws + 64 * MB);  // 32 MiB; WO partials reuse
    unsigned short* part = qk;                               // 32 MiB for down partials
    unsigned short* y_bf = vt;                               // ln2 out reuses vt

    const int HID2 = HIDN * HIDN;
    const int CONV_HID = HID2 / 8 / 256;
    const int CONV_FF  = FFDIM * HIDN / 8 / 256;
    const size_t LDSZ = 131072;

    // ---- QKV ----
    conv3_f32_bf16<<<3 * CONV_HID, 256, 0, stream>>>(wq, wk, wv, Wbuf);
    ln_bf16<<<SEQLEN, 256, 0, stream>>>(hidden, ln1w, ln1b, x_bf);
    gemm256<0><<<dim3(192, 1), 512, LDSZ, stream>>>(x_bf, HIDN, Wbuf, HIDN, HIDN, 24, 0,
                                                    bq, bk, bv, qk, vt);
    rope_kernel<<<SEQLEN * 32 * 64 / 256, 256, 0, stream>>>(qk, tsl);
    attn_kernel<<<256, 256, 0, stream>>>(qk, vt, x_bf);

    // ---- WO + residual + LN2 (split-K=4 partials in g_bf, combine fused with LN) ----
    conv_f32_bf16<<<CONV_HID, 256, 0, stream>>>(wo, Wbuf);
    gemm256<4><<<dim3(64, 4), 512, LDSZ, stream>>>(x_bf, HIDN, Wbuf, HIDN, 512, 8, HIDN,
                                                   nullptr, nullptr, nullptr, g_bf, nullptr);
    wo_ln<<<SEQLEN, 256, 0, stream>>>(g_bf, hidden, bo, ln2w, ln2b, out, y_bf);

    // ---- FFN ----
    conv_f32_bf16<<<CONV_FF, 256, 0, stream>>>(wg, Wbuf);
    gemm256<1><<<dim3(256, 1), 512, LDSZ, stream>>>(y_bf, HIDN, Wbuf, HIDN, HIDN, 32, FFDIM,
                                                    nullptr, nullptr, nullptr, g_bf, nullptr);
    conv_f32_bf16<<<CONV_FF, 256, 0, stream>>>(wu, Wbuf);
    gemm256<3><<<dim3(256, 1), 512, LDSZ, stream>>>(y_bf, HIDN, Wbuf, HIDN, HIDN, 32, FFDIM,
                                                    nullptr, nullptr, nullptr, g_bf, nullptr);
    conv_f32_bf16<<<CONV_FF, 256, 0, stream>>>(wd, Wbuf);
    gemm256<4><<<dim3(64, 4), 512, LDSZ, stream>>>(g_bf, FFDIM, Wbuf, FFDIM, 2048, 8, HIDN,
                                                   nullptr, nullptr, nullptr, part, nullptr);
    reduce4_add<<<4096, 256, 0, stream>>>(part, out);
}